// Round 2
// baseline (15400.935 us; speedup 1.0000x reference)
//
#include <hip/hip_runtime.h>
#include <hip/hip_bf16.h>
#include <math.h>

// ---- problem constants ----
#define LTOT 4161
#define BATCH 4
#define NROWS (BATCH*LTOT)      // 16644
#define MPAD 16768              // 131*128 (rows padded for 128-tile GEMM)
#define NPAD1 3456              // 3352 -> padded to 128 multiple
#define DM 768
#define DI 1536
#define DIP 3352
#define ZLD 3328                // stored columns of zx (z + xBC, dt cols handled in epilogue)
#define NH 24
#define HD 64
#define DS 128
#define EPSF 1e-5f

typedef __attribute__((ext_vector_type(8))) __bf16 bf16x8;
typedef __attribute__((ext_vector_type(4))) float f32x4;
typedef __attribute__((ext_vector_type(8))) short short8;
typedef unsigned short u16;

static __device__ __forceinline__ u16 f2bf(float f){
  unsigned u = __builtin_bit_cast(unsigned, f);
  u += 0x7FFFu + ((u >> 16) & 1u);          // RNE
  return (u16)(u >> 16);
}
static __device__ __forceinline__ float bf2f(u16 v){
  return __builtin_bit_cast(float, ((unsigned)v) << 16);
}
static __device__ __forceinline__ float siluf(float v){ return v / (1.f + expf(-v)); }

__device__ __forceinline__ float blockSum256(float v, float* sh){
  #pragma unroll
  for (int o = 32; o > 0; o >>= 1) v += __shfl_down(v, o);
  int w = threadIdx.x >> 6;
  if ((threadIdx.x & 63) == 0) sh[w] = v;
  __syncthreads();
  v = sh[0] + sh[1] + sh[2] + sh[3];
  __syncthreads();
  return v;
}

// ---- build x = LN0(concat(s0, h8, zm)) ----
__global__ __launch_bounds__(256)
void build_x_kernel(const float* __restrict__ im8, const float* __restrict__ frw,
                    const float* __restrict__ frb, const float* __restrict__ s0,
                    const float* __restrict__ suffix, const float* __restrict__ w,
                    const float* __restrict__ bb, float* __restrict__ x)
{
  int row = blockIdx.x;                 // 0..NROWS-1
  int b = row / LTOT, l = row % LTOT;
  int t = threadIdx.x;
  __shared__ float sh[4];
  float v[3];
  if (l == 0) {
    #pragma unroll
    for (int i = 0; i < 3; i++) v[i] = s0[t + i*256];
  } else if (l <= 64) {
    int p = l - 1;
    float r0 = im8[(b*64 + p)*3 + 0], r1 = im8[(b*64 + p)*3 + 1], r2 = im8[(b*64 + p)*3 + 2];
    #pragma unroll
    for (int i = 0; i < 3; i++) {
      int d = t + i*256;
      v[i] = r0*frw[d] + r1*frw[768 + d] + r2*frw[1536 + d] + frb[d];
    }
  } else {
    int j = l - 65;
    int p = ((j >> 9) << 3) | ((j & 63) >> 3);
    float r0 = im8[(b*64 + p)*3 + 0], r1 = im8[(b*64 + p)*3 + 1], r2 = im8[(b*64 + p)*3 + 2];
    #pragma unroll
    for (int i = 0; i < 3; i++) {
      int d = t + i*256;
      v[i] = r0*frw[d] + r1*frw[768 + d] + r2*frw[1536 + d] + frb[d] + suffix[(size_t)j*768 + d];
    }
  }
  float s = v[0] + v[1] + v[2];
  s = blockSum256(s, sh);
  float mu = s * (1.f/768.f);
  float q = 0;
  #pragma unroll
  for (int i = 0; i < 3; i++) { float d = v[i] - mu; q += d*d; }
  q = blockSum256(q, sh);
  float rs = rsqrtf(q * (1.f/768.f) + EPSF);
  float* xr = x + (size_t)row*DM;
  #pragma unroll
  for (int i = 0; i < 3; i++) {
    int d = t + i*256;
    xr[d] = (v[i] - mu)*rs*w[d] + bb[d];
  }
}

// ---- per-layer LN -> bf16 ----
__global__ __launch_bounds__(256)
void ln_bf16_kernel(const float* __restrict__ x, const float* __restrict__ w,
                    const float* __restrict__ bb, u16* __restrict__ out)
{
  int row = blockIdx.x;
  int t = threadIdx.x;
  __shared__ float sh[4];
  const float* xr = x + (size_t)row*DM;
  float v[3];
  #pragma unroll
  for (int i = 0; i < 3; i++) v[i] = xr[t + i*256];
  float s = v[0] + v[1] + v[2];
  s = blockSum256(s, sh);
  float mu = s * (1.f/768.f);
  float q = 0;
  #pragma unroll
  for (int i = 0; i < 3; i++) { float d = v[i] - mu; q += d*d; }
  q = blockSum256(q, sh);
  float rs = rsqrtf(q * (1.f/768.f) + EPSF);
  u16* orow = out + (size_t)row*DM;
  #pragma unroll
  for (int i = 0; i < 3; i++) {
    int d = t + i*256;
    orow[d] = f2bf((v[i] - mu)*rs*w[d] + bb[d]);
  }
}

// ---- transpose + f32->bf16 convert: in (K x N) -> out (Npad x K); grid(Npad/32, K/32) ----
__global__ __launch_bounds__(256)
void transp_bf16(const float* __restrict__ in, u16* __restrict__ out, int K, int N)
{
  __shared__ float tl[32][33];
  int tx = threadIdx.x & 31, ty = threadIdx.x >> 5;  // ty 0..7
  int n0 = blockIdx.x * 32, k0 = blockIdx.y * 32;
  #pragma unroll
  for (int r = 0; r < 4; r++) {
    int k = k0 + ty + r*8, n = n0 + tx;
    tl[ty + r*8][tx] = (n < N) ? in[(size_t)k*N + n] : 0.f;
  }
  __syncthreads();
  #pragma unroll
  for (int r = 0; r < 4; r++) {
    int n = n0 + ty + r*8, k = k0 + tx;
    out[(size_t)n*K + k] = f2bf(tl[tx][ty + r*8]);
  }
}

// ---- bf16 MFMA GEMM: C(M,N) = A(Mpad x K) * BT(Npad x K)^T
// MODE 0: store bf16 to zx (ld ZLD) for col<ZLD; cols [3328,3352) -> dt/da epilogue
// MODE 1: f32 residual add into x (ld 768)
template<int MODE>
__global__ __launch_bounds__(256)
void gemm_bf16(const u16* __restrict__ A, const u16* __restrict__ BT,
               void* __restrict__ Cout, const float* __restrict__ dtbias,
               const float* __restrict__ alog, float* __restrict__ dtO,
               float* __restrict__ daO, int K, int Mreal)
{
  __shared__ __align__(16) u16 As[128*40];
  __shared__ __align__(16) u16 Bs[128*40];
  const int t = threadIdx.x;
  const int bm = blockIdx.y, bn = blockIdx.x;
  const int lane = t & 63, wave = t >> 6;
  const int wr = wave >> 1, wc = wave & 1;
  const int r16 = lane & 15, kb = lane >> 4;

  f32x4 acc[4][4] = {};
  const int m = t >> 1, half = t & 1;
  const u16* gA = A + (size_t)(bm*128 + m)*K + half*16;
  const u16* gB = BT + (size_t)(bn*128 + m)*K + half*16;
  u16* wA = &As[m*40 + half*16];
  u16* wB = &Bs[m*40 + half*16];

  for (int kt = 0; kt < K; kt += 32) {
    short8 a0 = *(const short8*)(gA + kt);
    short8 a1 = *(const short8*)(gA + kt + 8);
    short8 b0 = *(const short8*)(gB + kt);
    short8 b1 = *(const short8*)(gB + kt + 8);
    *(short8*)(wA)     = a0; *(short8*)(wA + 8) = a1;
    *(short8*)(wB)     = b0; *(short8*)(wB + 8) = b1;
    __syncthreads();
    bf16x8 af[4], bfr[4];
    #pragma unroll
    for (int i = 0; i < 4; i++) af[i]  = *(const bf16x8*)&As[(wr*64 + i*16 + r16)*40 + kb*8];
    #pragma unroll
    for (int i = 0; i < 4; i++) bfr[i] = *(const bf16x8*)&Bs[(wc*64 + i*16 + r16)*40 + kb*8];
    #pragma unroll
    for (int i = 0; i < 4; i++)
      #pragma unroll
      for (int j = 0; j < 4; j++)
        acc[i][j] = __builtin_amdgcn_mfma_f32_16x16x32_bf16(af[i], bfr[j], acc[i][j], 0, 0, 0);
    __syncthreads();
  }
  const int rbase = bm*128 + wr*64, cbase = bn*128 + wc*64;
  #pragma unroll
  for (int i = 0; i < 4; i++) {
    #pragma unroll
    for (int j = 0; j < 4; j++) {
      int col = cbase + j*16 + r16;
      #pragma unroll
      for (int e = 0; e < 4; e++) {
        int row = rbase + i*16 + kb*4 + e;
        if (row < Mreal) {
          float v = acc[i][j][e];
          if (MODE == 0) {
            if (col < ZLD) {
              ((u16*)Cout)[(size_t)row*ZLD + col] = f2bf(v);
            } else if (col < DIP) {
              int hh = col - ZLD;
              float d = v + dtbias[hh];
              d = (d > 20.f) ? d : log1pf(expf(d));
              dtO[(size_t)row*NH + hh] = d;
              daO[(size_t)row*NH + hh] = expf(-d * expf(alog[hh]));
            }
          } else {
            ((float*)Cout)[(size_t)row*DM + col] += v;
          }
        }
      }
    }
  }
}

// ---- fused causal-conv(k=4)+silu + sequential SSM scan: one block per (b,h) ----
// zx row layout (bf16, ld ZLD): [0,1536) z | [1536,3072) x(conv in) | [3072,3200) B | [3200,3328) C
__global__ __launch_bounds__(256)
void scan_conv_kernel(const u16* __restrict__ zx, const float* __restrict__ dtb,
                      const float* __restrict__ dab, const float* __restrict__ cw,
                      const float* __restrict__ cb, const float* __restrict__ Dvec,
                      u16* __restrict__ y)
{
  const int b = blockIdx.x / NH, h = blockIdx.x % NH;
  const int t = threadIdx.x;
  const int p = t >> 2, nq = t & 3;
  __shared__ float ring[4][320];                 // [slot][ch]: ch<256 = B/C raw, 256..319 = x raw (this head)
  __shared__ __align__(16) float sBC[256];       // conv'd B (0..127) and C (128..255)
  __shared__ float sx[64];                       // conv'd x (this head)

  // conv weights: BC channel t -> conv channel 1536+t ; x channel t(<64) -> conv channel h*64+t
  float wbc[4], bbc, wx[4] = {0.f,0.f,0.f,0.f}, bx = 0.f;
  #pragma unroll
  for (int k = 0; k < 4; k++) wbc[k] = cw[(1536 + t)*4 + k];
  bbc = cb[1536 + t];
  if (t < 64) {
    #pragma unroll
    for (int k = 0; k < 4; k++) wx[k] = cw[(h*64 + t)*4 + k];
    bx = cb[h*64 + t];
  }
  float st[32];
  #pragma unroll
  for (int j = 0; j < 32; j++) st[j] = 0.f;
  const float dco = Dvec[h];

  const u16* zrow = zx + (size_t)(b*LTOT)*ZLD;
  const float* dtp = dtb + (size_t)(b*LTOT)*NH + h;
  const float* dap = dab + (size_t)(b*LTOT)*NH + h;
  u16* yp0 = y + (size_t)(b*LTOT)*DI + h*HD + p;

  // init ring: rows -3..-1 = 0, row 0 loaded
  #pragma unroll
  for (int s = 0; s < 4; s++) { ring[s][t] = 0.f; if (t < 64) ring[s][256 + t] = 0.f; }
  ring[0][t] = bf2f(zrow[3072 + t]);
  if (t < 64) ring[0][256 + t] = bf2f(zrow[1536 + h*HD + t]);
  // prefetch raw row 1 + dt/da rows 0,1
  u16 vb = zrow[(size_t)ZLD + 3072 + t];
  u16 vx = 0;
  if (t < 64) vx = zrow[(size_t)ZLD + 1536 + h*HD + t];
  float cdt = dtp[0], cda = dap[0];
  float ndt = dtp[NH], nda = dap[NH];
  __syncthreads();

  for (int l = 0; l < LTOT; ++l) {
    // conv for step l from ring (rows l-3..l live in slots (l+1+k)&3)
    float accb = bbc;
    #pragma unroll
    for (int k = 0; k < 4; k++) accb += wbc[k]*ring[(l + 1 + k) & 3][t];
    sBC[t] = siluf(accb);
    if (t < 64) {
      float accx = bx;
      #pragma unroll
      for (int k = 0; k < 4; k++) accx += wx[k]*ring[(l + 1 + k) & 3][256 + t];
      sx[t] = siluf(accx);
    }
    __syncthreads();
    // ring <- raw row l+1 (overwrites row l-3; conv above already consumed it)
    ring[(l + 1) & 3][t] = bf2f(vb);
    if (t < 64) ring[(l + 1) & 3][256 + t] = bf2f(vx);
    // prefetch raw row l+2 (clamped; clamped garbage is never consumed)
    {
      size_t rr = (size_t)((l + 2 < LTOT) ? (l + 2) : (LTOT - 1));
      vb = zrow[rr*ZLD + 3072 + t];
      if (t < 64) vx = zrow[rr*ZLD + 1536 + h*HD + t];
    }
    // state update + output
    float xv = sx[p];
    float co = cdt * xv;
    float yv = 0.f;
    const f32x4* Bp = (const f32x4*)&sBC[nq*32];
    const f32x4* Cp = (const f32x4*)&sBC[128 + nq*32];
    #pragma unroll
    for (int q = 0; q < 8; q++) {
      f32x4 bv = Bp[q], cv = Cp[q];
      #pragma unroll
      for (int e = 0; e < 4; e++) {
        float s = st[q*4 + e]*cda + co*bv[e];
        st[q*4 + e] = s;
        yv += s*cv[e];
      }
    }
    yv += __shfl_xor(yv, 1);
    yv += __shfl_xor(yv, 2);
    if (nq == 0) yp0[(size_t)l*DI] = f2bf(yv + dco*xv);
    // rotate dt/da, prefetch next
    cdt = ndt; cda = nda;
    {
      size_t rr = (size_t)((l + 2 < LTOT) ? (l + 2) : (LTOT - 1));
      ndt = dtp[rr*NH]; nda = dap[rr*NH];
    }
    __syncthreads();
  }
}

// ---- gate (in-place on y): y = rmsnorm(y * silu(z)) * gn_w ----
__global__ __launch_bounds__(256)
void gate_kernel(u16* __restrict__ ybuf, const u16* __restrict__ zx,
                 const float* __restrict__ gw)
{
  int row = blockIdx.x;
  int t = threadIdx.x;
  __shared__ float sh[4];
  float g[6]; float ss = 0.f;
  u16* yr = ybuf + (size_t)row*DI;
  const u16* zr = zx + (size_t)row*ZLD;
  #pragma unroll
  for (int i = 0; i < 6; i++) {
    int c = t + i*256;
    float z = bf2f(zr[c]);
    float yv = bf2f(yr[c]);
    float v = yv * siluf(z);
    g[i] = v; ss += v*v;
  }
  ss = blockSum256(ss, sh);
  float rs = rsqrtf(ss * (1.f/1536.f) + EPSF);
  #pragma unroll
  for (int i = 0; i < 6; i++) {
    int c = t + i*256;
    yr[c] = f2bf(g[i]*rs*gw[c]);
  }
}

// ---- head: y_hat = x[:, -4096:] @ to_rgb_w + b ; per-block squared-error partials ----
__global__ __launch_bounds__(256)
void head_kernel(const float* __restrict__ x, const float* __restrict__ tw,
                 const float* __restrict__ tb, const float* __restrict__ im64,
                 float* __restrict__ out, float* __restrict__ partial)
{
  int bj = blockIdx.x;                   // 0..B*4096-1
  int b = bj >> 12, j = bj & 4095;
  int row = b*LTOT + 65 + j;
  const float* xr = x + (size_t)row*DM;
  int t = threadIdx.x;
  float p0 = 0, p1 = 0, p2 = 0;
  for (int k = t; k < 768; k += 256) {
    float xv = xr[k];
    p0 += xv*tw[k*3 + 0]; p1 += xv*tw[k*3 + 1]; p2 += xv*tw[k*3 + 2];
  }
  __shared__ float sh[4];
  p0 = blockSum256(p0, sh);
  p1 = blockSum256(p1, sh);
  p2 = blockSum256(p2, sh);
  if (t == 0) {
    float y0 = p0 + tb[0], y1 = p1 + tb[1], y2 = p2 + tb[2];
    size_t o = (size_t)bj*3;
    out[o] = y0; out[o + 1] = y1; out[o + 2] = y2;
    float d0 = y0 - im64[o], d1 = y1 - im64[o + 1], d2 = y2 - im64[o + 2];
    partial[bj] = d0*d0 + d1*d1 + d2*d2;
  }
}

__global__ __launch_bounds__(256)
void loss_reduce(const float* __restrict__ partial, float* __restrict__ out)
{
  int t = threadIdx.x;
  float s = 0.f;
  for (int i = t; i < BATCH*4096; i += 256) s += partial[i];
  __shared__ float sh[4];
  s = blockSum256(s, sh);
  if (t == 0) out[49152] = s * (1.f/49152.f);
}

// ---- launcher ----
static inline size_t alignup(size_t v){ return (v + 255) & ~(size_t)255; }

extern "C" void kernel_launch(void* const* d_in, const int* in_sizes, int n_in,
                              void* d_out, int out_size, void* d_ws, size_t ws_size,
                              hipStream_t stream)
{
  const float* im8        = (const float*)d_in[0];
  const float* im64       = (const float*)d_in[1];
  const float* from_rgb_w = (const float*)d_in[2];
  const float* from_rgb_b = (const float*)d_in[3];
  const float* to_rgb_w   = (const float*)d_in[4];
  const float* to_rgb_b   = (const float*)d_in[5];
  const float* s0         = (const float*)d_in[6];
  const float* suffix     = (const float*)d_in[7];
  const float* norm0_w    = (const float*)d_in[8];
  const float* norm0_b    = (const float*)d_in[9];
  const float* ln_w       = (const float*)d_in[10];
  const float* ln_b       = (const float*)d_in[11];
  const float* in_proj_w  = (const float*)d_in[12];
  const float* conv_w     = (const float*)d_in[13];
  const float* conv_b     = (const float*)d_in[14];
  const float* dt_bias    = (const float*)d_in[15];
  const float* A_log      = (const float*)d_in[16];
  const float* Dvec       = (const float*)d_in[17];
  const float* gn_w       = (const float*)d_in[18];
  const float* out_proj_w = (const float*)d_in[19];

  char* w = (char*)d_ws;
  size_t off = 0;
  float* x     = (float*)(w + off); off = alignup(off + (size_t)NROWS*DM*4);    // 51.2 MB
  u16*   S1    = (u16*)  (w + off); off = alignup(off + (size_t)MPAD*DI*2);     // 51.5 MB (xn / y / yg)
  u16*   zx    = (u16*)  (w + off); off = alignup(off + (size_t)NROWS*ZLD*2);   // 110.8 MB
  u16*   wT    = (u16*)  (w + off); off = alignup(off + (size_t)NPAD1*DM*2);    // 5.3 MB (wT1 / wT2)
  float* dt    = (float*)(w + off); off = alignup(off + (size_t)NROWS*NH*4);    // 1.6 MB
  float* da    = (float*)(w + off); off = alignup(off + (size_t)NROWS*NH*4);    // 1.6 MB
  float* lpart = (float*)(w + off); off = alignup(off + (size_t)BATCH*4096*4);  // 64 KB
  // total ~222 MB

  build_x_kernel<<<NROWS, 256, 0, stream>>>(im8, from_rgb_w, from_rgb_b, s0, suffix,
                                            norm0_w, norm0_b, x);

  for (int i = 0; i < 4; i++) {
    ln_bf16_kernel<<<NROWS, 256, 0, stream>>>(x, ln_w + i*DM, ln_b + i*DM, S1);
    transp_bf16<<<dim3(NPAD1/32, DM/32), 256, 0, stream>>>(in_proj_w + (size_t)i*DM*DIP, wT, DM, DIP);
    gemm_bf16<0><<<dim3(NPAD1/128, MPAD/128), 256, 0, stream>>>(
        S1, wT, zx, dt_bias + i*NH, A_log + i*NH, dt, da, DM, NROWS);
    scan_conv_kernel<<<BATCH*NH, 256, 0, stream>>>(zx, dt, da, conv_w + (size_t)i*(DI+2*DS)*4,
                                                   conv_b + i*(DI+2*DS), Dvec + i*NH, S1);
    gate_kernel<<<NROWS, 256, 0, stream>>>(S1, zx, gn_w + i*DI);
    transp_bf16<<<dim3(DM/32, DI/32), 256, 0, stream>>>(out_proj_w + (size_t)i*DI*DM, wT, DI, DM);
    gemm_bf16<1><<<dim3(DM/128, MPAD/128), 256, 0, stream>>>(
        S1, wT, x, nullptr, nullptr, nullptr, nullptr, DI, NROWS);
  }

  head_kernel<<<BATCH*4096, 256, 0, stream>>>(x, to_rgb_w, to_rgb_b, im64, (float*)d_out, lpart);
  loss_reduce<<<1, 256, 0, stream>>>(lpart, (float*)d_out);
}

// Round 4
// 8126.700 us; speedup vs baseline: 1.8951x; 1.8951x over previous
//
#include <hip/hip_runtime.h>
#include <hip/hip_bf16.h>
#include <math.h>

// ---- problem constants ----
#define LTOT 4161
#define BATCH 4
#define NROWS (BATCH*LTOT)      // 16644
#define MPAD 16768              // rows padded for 128-tile GEMM grid
#define NPAD1 3456              // 3352 -> padded to 128 multiple
#define DM 768
#define DI 1536
#define DIP 3352
#define ZLD 3328                // stored columns of zx
#define NH 24
#define HD 64
#define DS 128
#define EPSF 1e-5f
#define CHK 128                 // SSD chunk length
#define NCH 33                  // ceil(4161/128)
#define LD 136                  // LDS row stride (u16)

typedef __attribute__((ext_vector_type(8))) __bf16 bf16x8;
typedef __attribute__((ext_vector_type(4))) float f32x4;
typedef __attribute__((ext_vector_type(8))) short short8;
typedef unsigned short u16;

static __device__ __forceinline__ u16 f2bf(float f){
  unsigned u = __builtin_bit_cast(unsigned, f);
  u += 0x7FFFu + ((u >> 16) & 1u);          // RNE
  return (u16)(u >> 16);
}
static __device__ __forceinline__ float bf2f(u16 v){
  return __builtin_bit_cast(float, ((unsigned)v) << 16);
}
static __device__ __forceinline__ float siluf(float v){ return v / (1.f + expf(-v)); }

__device__ __forceinline__ float blockSum256(float v, float* sh){
  #pragma unroll
  for (int o = 32; o > 0; o >>= 1) v += __shfl_down(v, o);
  int w = threadIdx.x >> 6;
  if ((threadIdx.x & 63) == 0) sh[w] = v;
  __syncthreads();
  v = sh[0] + sh[1] + sh[2] + sh[3];
  __syncthreads();
  return v;
}

// ---- build x = LN0(concat(s0, h8, zm)) ----
__global__ __launch_bounds__(256)
void build_x_kernel(const float* __restrict__ im8, const float* __restrict__ frw,
                    const float* __restrict__ frb, const float* __restrict__ s0,
                    const float* __restrict__ suffix, const float* __restrict__ w,
                    const float* __restrict__ bb, float* __restrict__ x)
{
  int row = blockIdx.x;
  int b = row / LTOT, l = row % LTOT;
  int t = threadIdx.x;
  __shared__ float sh[4];
  float v[3];
  if (l == 0) {
    #pragma unroll
    for (int i = 0; i < 3; i++) v[i] = s0[t + i*256];
  } else if (l <= 64) {
    int p = l - 1;
    float r0 = im8[(b*64 + p)*3 + 0], r1 = im8[(b*64 + p)*3 + 1], r2 = im8[(b*64 + p)*3 + 2];
    #pragma unroll
    for (int i = 0; i < 3; i++) {
      int d = t + i*256;
      v[i] = r0*frw[d] + r1*frw[768 + d] + r2*frw[1536 + d] + frb[d];
    }
  } else {
    int j = l - 65;
    int p = ((j >> 9) << 3) | ((j & 63) >> 3);
    float r0 = im8[(b*64 + p)*3 + 0], r1 = im8[(b*64 + p)*3 + 1], r2 = im8[(b*64 + p)*3 + 2];
    #pragma unroll
    for (int i = 0; i < 3; i++) {
      int d = t + i*256;
      v[i] = r0*frw[d] + r1*frw[768 + d] + r2*frw[1536 + d] + frb[d] + suffix[(size_t)j*768 + d];
    }
  }
  float s = v[0] + v[1] + v[2];
  s = blockSum256(s, sh);
  float mu = s * (1.f/768.f);
  float q = 0;
  #pragma unroll
  for (int i = 0; i < 3; i++) { float d = v[i] - mu; q += d*d; }
  q = blockSum256(q, sh);
  float rs = rsqrtf(q * (1.f/768.f) + EPSF);
  float* xr = x + (size_t)row*DM;
  #pragma unroll
  for (int i = 0; i < 3; i++) {
    int d = t + i*256;
    xr[d] = (v[i] - mu)*rs*w[d] + bb[d];
  }
}

// ---- per-row LN stats (mu, rstd) ----
__global__ __launch_bounds__(256)
void row_stats_kernel(const float* __restrict__ x, float* __restrict__ murs)
{
  int row = blockIdx.x;
  int t = threadIdx.x;
  __shared__ float sh[4];
  const float* xr = x + (size_t)row*DM;
  float v[3];
  #pragma unroll
  for (int i = 0; i < 3; i++) v[i] = xr[t + i*256];
  float s = v[0] + v[1] + v[2];
  s = blockSum256(s, sh);
  float mu = s * (1.f/768.f);
  float q = 0;
  #pragma unroll
  for (int i = 0; i < 3; i++) { float d = v[i] - mu; q += d*d; }
  q = blockSum256(q, sh);
  float rs = rsqrtf(q * (1.f/768.f) + EPSF);
  if (t == 0) { murs[2*row] = mu; murs[2*row + 1] = rs; }
}

// ---- transpose + f32->bf16: in (K x N) -> out (Npad x K); grid(Npad/32, K/32) ----
__global__ __launch_bounds__(256)
void transp_bf16(const float* __restrict__ in, u16* __restrict__ out, int K, int N)
{
  __shared__ float tl[32][33];
  int tx = threadIdx.x & 31, ty = threadIdx.x >> 5;
  int n0 = blockIdx.x * 32, k0 = blockIdx.y * 32;
  #pragma unroll
  for (int r = 0; r < 4; r++) {
    int k = k0 + ty + r*8, n = n0 + tx;
    tl[ty + r*8][tx] = (n < N) ? in[(size_t)k*N + n] : 0.f;
  }
  __syncthreads();
  #pragma unroll
  for (int r = 0; r < 4; r++) {
    int n = n0 + ty + r*8, k = k0 + tx;
    out[(size_t)n*K + k] = f2bf(tl[tx][ty + r*8]);
  }
}

// ---- GEMM0: zx[.]= LN(x) @ Wi  with LN fused into A-staging; dt epilogue ----
// grid(NPAD1/128, MPAD/128)
__global__ __launch_bounds__(256)
void gemm_ln(const float* __restrict__ X, const float* __restrict__ murs,
             const float* __restrict__ lnw, const float* __restrict__ lnb,
             const u16* __restrict__ BT, u16* __restrict__ zxO,
             const float* __restrict__ dtbias, float* __restrict__ dtO)
{
  __shared__ __align__(16) u16 As[128*40];
  __shared__ __align__(16) u16 Bs[128*40];
  __shared__ float wl[DM], bl[DM], muS[128], rsS[128];
  const int t = threadIdx.x;
  const int bm = blockIdx.y, bn = blockIdx.x;
  const int lane = t & 63, wave = t >> 6;
  const int wr = wave >> 1, wc = wave & 1;
  const int r16 = lane & 15, kb = lane >> 4;

  for (int i = t; i < DM; i += 256) { wl[i] = lnw[i]; bl[i] = lnb[i]; }
  if (t < 128) {
    int r = bm*128 + t;
    float m = 0.f, rr = 0.f;
    if (r < NROWS) { m = murs[2*r]; rr = murs[2*r + 1]; }
    muS[t] = m; rsS[t] = rr;
  }
  __syncthreads();

  const int m = t >> 1, half = t & 1;
  const int grow = bm*128 + m;
  const bool valid = grow < NROWS;
  const float* gX = X + (size_t)grow*DM + half*16;
  const u16* gB = BT + (size_t)(bn*128 + m)*DM + half*16;
  u16* wA = &As[m*40 + half*16];
  u16* wB = &Bs[m*40 + half*16];
  const float mu = muS[m], rs = rsS[m];

  f32x4 acc[4][4] = {};
  for (int kt = 0; kt < DM; kt += 32) {
    short8 b0 = *(const short8*)(gB + kt);
    short8 b1 = *(const short8*)(gB + kt + 8);
    short8 a0 = {}, a1 = {};
    if (valid) {
      const float* xp = gX + kt;
      const int c0 = kt + half*16;
      #pragma unroll
      for (int j = 0; j < 8; j++) a0[j] = (short)f2bf((xp[j]     - mu)*rs*wl[c0 + j]     + bl[c0 + j]);
      #pragma unroll
      for (int j = 0; j < 8; j++) a1[j] = (short)f2bf((xp[8 + j] - mu)*rs*wl[c0 + 8 + j] + bl[c0 + 8 + j]);
    }
    *(short8*)(wA)     = a0; *(short8*)(wA + 8) = a1;
    *(short8*)(wB)     = b0; *(short8*)(wB + 8) = b1;
    __syncthreads();
    bf16x8 af[4], bfr[4];
    #pragma unroll
    for (int i = 0; i < 4; i++) af[i]  = *(const bf16x8*)&As[(wr*64 + i*16 + r16)*40 + kb*8];
    #pragma unroll
    for (int i = 0; i < 4; i++) bfr[i] = *(const bf16x8*)&Bs[(wc*64 + i*16 + r16)*40 + kb*8];
    #pragma unroll
    for (int i = 0; i < 4; i++)
      #pragma unroll
      for (int j = 0; j < 4; j++)
        acc[i][j] = __builtin_amdgcn_mfma_f32_16x16x32_bf16(af[i], bfr[j], acc[i][j], 0, 0, 0);
    __syncthreads();
  }
  const int rbase = bm*128 + wr*64, cbase = bn*128 + wc*64;
  #pragma unroll
  for (int i = 0; i < 4; i++) {
    #pragma unroll
    for (int j = 0; j < 4; j++) {
      int col = cbase + j*16 + r16;
      #pragma unroll
      for (int e = 0; e < 4; e++) {
        int row = rbase + i*16 + kb*4 + e;
        if (row < NROWS) {
          float v = acc[i][j][e];
          if (col < ZLD) {
            zxO[(size_t)row*ZLD + col] = f2bf(v);
          } else if (col < DIP) {
            int hh = col - ZLD;
            float d = v + dtbias[hh];
            d = (d > 20.f) ? d : log1pf(expf(d));
            dtO[(size_t)row*NH + hh] = d;
          }
        }
      }
    }
  }
}

// ---- GEMM1: x += gated(zx cols 0..1535) @ Wo ; A from zx with lda=ZLD ----
// grid(DM/128, MPAD/128)
__global__ __launch_bounds__(256)
void gemm_out(const u16* __restrict__ A, const u16* __restrict__ BT, float* __restrict__ X)
{
  __shared__ __align__(16) u16 As[128*40];
  __shared__ __align__(16) u16 Bs[128*40];
  const int t = threadIdx.x;
  const int bm = blockIdx.y, bn = blockIdx.x;
  const int lane = t & 63, wave = t >> 6;
  const int wr = wave >> 1, wc = wave & 1;
  const int r16 = lane & 15, kb = lane >> 4;

  const int m = t >> 1, half = t & 1;
  const int grow = bm*128 + m;
  const bool valid = grow < NROWS;
  const u16* gA = A + (size_t)grow*ZLD + half*16;
  const u16* gB = BT + (size_t)(bn*128 + m)*DI + half*16;
  u16* wA = &As[m*40 + half*16];
  u16* wB = &Bs[m*40 + half*16];

  f32x4 acc[4][4] = {};
  for (int kt = 0; kt < DI; kt += 32) {
    short8 b0 = *(const short8*)(gB + kt);
    short8 b1 = *(const short8*)(gB + kt + 8);
    short8 a0 = {}, a1 = {};
    if (valid) { a0 = *(const short8*)(gA + kt); a1 = *(const short8*)(gA + kt + 8); }
    *(short8*)(wA)     = a0; *(short8*)(wA + 8) = a1;
    *(short8*)(wB)     = b0; *(short8*)(wB + 8) = b1;
    __syncthreads();
    bf16x8 af[4], bfr[4];
    #pragma unroll
    for (int i = 0; i < 4; i++) af[i]  = *(const bf16x8*)&As[(wr*64 + i*16 + r16)*40 + kb*8];
    #pragma unroll
    for (int i = 0; i < 4; i++) bfr[i] = *(const bf16x8*)&Bs[(wc*64 + i*16 + r16)*40 + kb*8];
    #pragma unroll
    for (int i = 0; i < 4; i++)
      #pragma unroll
      for (int j = 0; j < 4; j++)
        acc[i][j] = __builtin_amdgcn_mfma_f32_16x16x32_bf16(af[i], bfr[j], acc[i][j], 0, 0, 0);
    __syncthreads();
  }
  const int rbase = bm*128 + wr*64, cbase = bn*128 + wc*64;
  #pragma unroll
  for (int i = 0; i < 4; i++) {
    #pragma unroll
    for (int j = 0; j < 4; j++) {
      int col = cbase + j*16 + r16;
      #pragma unroll
      for (int e = 0; e < 4; e++) {
        int row = rbase + i*16 + kb*4 + e;
        if (row < NROWS) X[(size_t)row*DM + col] += acc[i][j][e];
      }
    }
  }
}

// ======================= chunked SSD =======================
// zx row layout (bf16, ld ZLD): [0,1536) z | [1536,3072) x raw | [3072,3200) B raw | [3200,3328) C raw
// slab id = (b*NCH + c)*NH + h ; cstat[id][p(64)][n(128)] bf16 ; dtot[id] f32

// ---- K1: per-chunk state ----
__global__ __launch_bounds__(256)
void chunk_state_kernel(const u16* __restrict__ zx, const float* __restrict__ dtb,
                        const float* __restrict__ alog, const float* __restrict__ cw,
                        const float* __restrict__ cb, u16* __restrict__ cstat,
                        float* __restrict__ dtot)
{
  const int id = blockIdx.x;
  const int h = id % NH; const int c = (id / NH) % NCH; const int b = id / (NH*NCH);
  const int t = threadIdx.x;
  const int base = c*CHK;
  int rows = LTOT - base; if (rows > CHK) rows = CHK;

  __shared__ __align__(16) u16 BTs[128][LD];   // [n][j]
  __shared__ __align__(16) u16 xsT[64][LD];    // [p][j], scaled by w_j
  __shared__ float dtv[128];
  __shared__ float cs[128];

  const float aexp = expf(alog[h]);
  if (t < 128) {
    float dv = 0.f;
    if (t < rows) dv = dtb[(size_t)(b*LTOT + base + t)*NH + h];
    dtv[t] = dv; cs[t] = -dv * aexp;
  }
  __syncthreads();
  for (int off = 1; off < 128; off <<= 1) {
    float add = 0.f;
    if (t < 128 && t >= off) add = cs[t - off];
    __syncthreads();
    if (t < 128) cs[t] += add;
    __syncthreads();
  }
  if (t < 128) {
    int n = t;
    const u16* src = zx + (size_t)(b*LTOT)*ZLD + 3072 + n;
    float w0 = cw[(1536 + n)*4 + 0], w1 = cw[(1536 + n)*4 + 1];
    float w2 = cw[(1536 + n)*4 + 2], w3 = cw[(1536 + n)*4 + 3];
    float bias = cb[1536 + n];
    float r0 = (base >= 3) ? bf2f(src[(size_t)(base-3)*ZLD]) : 0.f;
    float r1 = (base >= 2) ? bf2f(src[(size_t)(base-2)*ZLD]) : 0.f;
    float r2 = (base >= 1) ? bf2f(src[(size_t)(base-1)*ZLD]) : 0.f;
    #pragma unroll 4
    for (int j = 0; j < CHK; j++) {
      float r3 = (base + j < LTOT) ? bf2f(src[(size_t)(base+j)*ZLD]) : 0.f;
      float o = bias + w0*r0 + w1*r1 + w2*r2 + w3*r3;
      BTs[n][j] = (j < rows) ? f2bf(siluf(o)) : (u16)0;
      r0 = r1; r1 = r2; r2 = r3;
    }
  } else if (t < 192) {
    int p = t - 128;
    const u16* src = zx + (size_t)(b*LTOT)*ZLD + 1536 + h*HD + p;
    float w0 = cw[(h*HD + p)*4 + 0], w1 = cw[(h*HD + p)*4 + 1];
    float w2 = cw[(h*HD + p)*4 + 2], w3 = cw[(h*HD + p)*4 + 3];
    float bias = cb[h*HD + p];
    float csl = cs[127];
    float r0 = (base >= 3) ? bf2f(src[(size_t)(base-3)*ZLD]) : 0.f;
    float r1 = (base >= 2) ? bf2f(src[(size_t)(base-2)*ZLD]) : 0.f;
    float r2 = (base >= 1) ? bf2f(src[(size_t)(base-1)*ZLD]) : 0.f;
    #pragma unroll 4
    for (int j = 0; j < CHK; j++) {
      float r3 = (base + j < LTOT) ? bf2f(src[(size_t)(base+j)*ZLD]) : 0.f;
      float o = bias + w0*r0 + w1*r1 + w2*r2 + w3*r3;
      float wj = expf(csl - cs[j]) * dtv[j];
      xsT[p][j] = (j < rows) ? f2bf(siluf(o) * wj) : (u16)0;
      r0 = r1; r1 = r2; r2 = r3;
    }
  }
  __syncthreads();

  const int lane = t & 63, wave = t >> 6;
  const int r16 = lane & 15, kb = lane >> 4;
  const int n0 = wave*32;
  f32x4 acc[4][2] = {};
  #pragma unroll
  for (int kt = 0; kt < 4; kt++) {
    bf16x8 af[4], bfr[2];
    #pragma unroll
    for (int m = 0; m < 4; m++) af[m] = *(const bf16x8*)&xsT[m*16 + r16][kt*32 + kb*8];
    #pragma unroll
    for (int nn = 0; nn < 2; nn++) bfr[nn] = *(const bf16x8*)&BTs[n0 + nn*16 + r16][kt*32 + kb*8];
    #pragma unroll
    for (int m = 0; m < 4; m++)
      #pragma unroll
      for (int nn = 0; nn < 2; nn++)
        acc[m][nn] = __builtin_amdgcn_mfma_f32_16x16x32_bf16(af[m], bfr[nn], acc[m][nn], 0, 0, 0);
  }
  u16* dst = cstat + (size_t)id*64*128;
  #pragma unroll
  for (int m = 0; m < 4; m++)
    #pragma unroll
    for (int nn = 0; nn < 2; nn++)
      #pragma unroll
      for (int e = 0; e < 4; e++) {
        int p = m*16 + kb*4 + e;
        int n = n0 + nn*16 + r16;
        dst[p*128 + n] = f2bf(acc[m][nn][e]);
      }
  if (t == 0) dtot[id] = expf(cs[127]);
}

// ---- K2: inter-chunk scan (in-place: slot <- state BEFORE that chunk) ----
__global__ __launch_bounds__(256)
void state_scan_kernel(u16* __restrict__ cstat, const float* __restrict__ dtot)
{
  const int b = blockIdx.x / NH, h = blockIdx.x % NH;
  const int t = threadIdx.x;
  float run[32];
  #pragma unroll
  for (int k = 0; k < 32; k++) run[k] = 0.f;
  for (int c = 0; c < NCH; ++c) {
    size_t id = (size_t)(b*NCH + c)*NH + h;
    u16* slab = cstat + id*8192 + t*32;
    float d = dtot[id];
    short8 in[4], out[4];
    #pragma unroll
    for (int q = 0; q < 4; q++) in[q] = *(const short8*)(slab + q*8);
    #pragma unroll
    for (int q = 0; q < 4; q++)
      #pragma unroll
      for (int k = 0; k < 8; k++) {
        int idx = q*8 + k;
        float csv = bf2f((u16)in[q][k]);
        out[q][k] = (short)f2bf(run[idx]);
        run[idx] = run[idx]*d + csv;
      }
    #pragma unroll
    for (int q = 0; q < 4; q++) *(short8*)(slab + q*8) = out[q];
  }
}

// ---- K3: per-chunk output; writes y*silu(z) over z-columns of zx ----
__global__ __launch_bounds__(256)
void chunk_output_kernel(u16* __restrict__ zx, const float* __restrict__ dtb,
                         const float* __restrict__ alog, const float* __restrict__ cw,
                         const float* __restrict__ cb, const float* __restrict__ Dvec,
                         const u16* __restrict__ cstat)
{
  const int id = blockIdx.x;
  const int h = id % NH; const int c = (id / NH) % NCH; const int b = id / (NH*NCH);
  const int t = threadIdx.x;
  const int base = c*CHK;
  int rows = LTOT - base; if (rows > CHK) rows = CHK;

  __shared__ __align__(16) u16 Cc[128][LD];    // [i][n]
  __shared__ __align__(16) u16 Bc[128][LD];    // [j][n] -> later P[i][j]
  __shared__ __align__(16) u16 xc[64][LD];     // [p][j]
  __shared__ __align__(16) u16 stT[64][LD];    // [p][n]
  __shared__ float dtv[128];
  __shared__ float cs[128];

  const float aexp = expf(alog[h]);
  if (t < 128) {
    float dv = 0.f;
    if (t < rows) dv = dtb[(size_t)(b*LTOT + base + t)*NH + h];
    dtv[t] = dv; cs[t] = -dv * aexp;
  }
  {
    const u16* slab = cstat + (size_t)id*8192;
    int p = t >> 2, nb = (t & 3)*32;
    #pragma unroll
    for (int q = 0; q < 4; q++) {
      short8 v = *(const short8*)(slab + p*128 + nb + q*8);
      *(short8*)&stT[p][nb + q*8] = v;
    }
  }
  __syncthreads();
  for (int off = 1; off < 128; off <<= 1) {
    float add = 0.f;
    if (t < 128 && t >= off) add = cs[t - off];
    __syncthreads();
    if (t < 128) cs[t] += add;
    __syncthreads();
  }
  {
    int isC = (t >= 128);
    int n = t & 127;
    int zcol = isC ? (3200 + n) : (3072 + n);
    int ccol = isC ? (1664 + n) : (1536 + n);
    const u16* src = zx + (size_t)(b*LTOT)*ZLD + zcol;
    float w0 = cw[ccol*4 + 0], w1 = cw[ccol*4 + 1], w2 = cw[ccol*4 + 2], w3 = cw[ccol*4 + 3];
    float bias = cb[ccol];
    float r0 = (base >= 3) ? bf2f(src[(size_t)(base-3)*ZLD]) : 0.f;
    float r1 = (base >= 2) ? bf2f(src[(size_t)(base-2)*ZLD]) : 0.f;
    float r2 = (base >= 1) ? bf2f(src[(size_t)(base-1)*ZLD]) : 0.f;
    #pragma unroll 4
    for (int j = 0; j < CHK; j++) {
      float r3 = (base + j < LTOT) ? bf2f(src[(size_t)(base+j)*ZLD]) : 0.f;
      float o = bias + w0*r0 + w1*r1 + w2*r2 + w3*r3;
      u16 val = (j < rows) ? f2bf(siluf(o)) : (u16)0;
      if (isC) Cc[j][n] = val; else Bc[j][n] = val;
      r0 = r1; r1 = r2; r2 = r3;
    }
  }
  if (t < 64) {
    int p = t;
    const u16* src = zx + (size_t)(b*LTOT)*ZLD + 1536 + h*HD + p;
    float w0 = cw[(h*HD + p)*4 + 0], w1 = cw[(h*HD + p)*4 + 1];
    float w2 = cw[(h*HD + p)*4 + 2], w3 = cw[(h*HD + p)*4 + 3];
    float bias = cb[h*HD + p];
    float r0 = (base >= 3) ? bf2f(src[(size_t)(base-3)*ZLD]) : 0.f;
    float r1 = (base >= 2) ? bf2f(src[(size_t)(base-2)*ZLD]) : 0.f;
    float r2 = (base >= 1) ? bf2f(src[(size_t)(base-1)*ZLD]) : 0.f;
    #pragma unroll 4
    for (int j = 0; j < CHK; j++) {
      float r3 = (base + j < LTOT) ? bf2f(src[(size_t)(base+j)*ZLD]) : 0.f;
      float o = bias + w0*r0 + w1*r1 + w2*r2 + w3*r3;
      xc[p][j] = (j < rows) ? f2bf(siluf(o)) : (u16)0;
      r0 = r1; r1 = r2; r2 = r3;
    }
  }
  __syncthreads();

  const int lane = t & 63, wave = t >> 6;
  const int r16 = lane & 15, kb = lane >> 4;

  // Phase A: S[i][j] = sum_n Cc[i][n]*Bc[j][n]; then P into Bc
  {
    const int wi = wave >> 1, wj = wave & 1;
    f32x4 acc[4][4] = {};
    #pragma unroll
    for (int kt = 0; kt < 4; kt++) {
      bf16x8 af[4], bfr[4];
      #pragma unroll
      for (int m = 0; m < 4; m++) af[m] = *(const bf16x8*)&Cc[wi*64 + m*16 + r16][kt*32 + kb*8];
      #pragma unroll
      for (int nj = 0; nj < 4; nj++) bfr[nj] = *(const bf16x8*)&Bc[wj*64 + nj*16 + r16][kt*32 + kb*8];
      #pragma unroll
      for (int m = 0; m < 4; m++)
        #pragma unroll
        for (int nj = 0; nj < 4; nj++)
          acc[m][nj] = __builtin_amdgcn_mfma_f32_16x16x32_bf16(af[m], bfr[nj], acc[m][nj], 0, 0, 0);
    }
    __syncthreads();
    #pragma unroll
    for (int m = 0; m < 4; m++)
      #pragma unroll
      for (int nj = 0; nj < 4; nj++)
        #pragma unroll
        for (int e = 0; e < 4; e++) {
          int i = wi*64 + m*16 + kb*4 + e;
          int j = wj*64 + nj*16 + r16;
          float f = 0.f;
          if (j <= i && i < rows) f = expf(cs[i] - cs[j]) * dtv[j];
          Bc[i][j] = f2bf(acc[m][nj][e] * f);
        }
  }
  __syncthreads();

  // Phase B: Y1 = P @ xc^T ; Phase C: Y2 = Cc @ stT^T ; write gated y over z
  {
    const int iq = wave;
    f32x4 accY[2][4] = {};
    #pragma unroll
    for (int kt = 0; kt < 4; kt++) {
      bf16x8 af[2], bfr[4];
      #pragma unroll
      for (int m = 0; m < 2; m++) af[m] = *(const bf16x8*)&Bc[iq*32 + m*16 + r16][kt*32 + kb*8];
      #pragma unroll
      for (int n = 0; n < 4; n++) bfr[n] = *(const bf16x8*)&xc[n*16 + r16][kt*32 + kb*8];
      #pragma unroll
      for (int m = 0; m < 2; m++)
        #pragma unroll
        for (int n = 0; n < 4; n++)
          accY[m][n] = __builtin_amdgcn_mfma_f32_16x16x32_bf16(af[m], bfr[n], accY[m][n], 0, 0, 0);
    }
    f32x4 accS[2][4] = {};
    #pragma unroll
    for (int kt = 0; kt < 4; kt++) {
      bf16x8 af[2], bfr[4];
      #pragma unroll
      for (int m = 0; m < 2; m++) af[m] = *(const bf16x8*)&Cc[iq*32 + m*16 + r16][kt*32 + kb*8];
      #pragma unroll
      for (int n = 0; n < 4; n++) bfr[n] = *(const bf16x8*)&stT[n*16 + r16][kt*32 + kb*8];
      #pragma unroll
      for (int m = 0; m < 2; m++)
        #pragma unroll
        for (int n = 0; n < 4; n++)
          accS[m][n] = __builtin_amdgcn_mfma_f32_16x16x32_bf16(af[m], bfr[n], accS[m][n], 0, 0, 0);
    }
    const float dcoef = Dvec[h];
    #pragma unroll
    for (int m = 0; m < 2; m++)
      #pragma unroll
      for (int e = 0; e < 4; e++) {
        int i = iq*32 + m*16 + kb*4 + e;
        if (i < rows) {
          float sc = expf(cs[i]);
          size_t orow = (size_t)(b*LTOT + base + i)*ZLD + h*HD;
          #pragma unroll
          for (int n = 0; n < 4; n++) {
            int p = n*16 + r16;
            float xv = bf2f(xc[p][i]);
            float yv = accY[m][n][e] + sc*accS[m][n][e] + dcoef*xv;
            float zval = bf2f(zx[orow + p]);
            zx[orow + p] = f2bf(yv * siluf(zval));
          }
        }
      }
  }
}

// ---- rmsnorm in place on zx cols [0,1536) ----
__global__ __launch_bounds__(256)
void gate_rms_kernel(u16* __restrict__ zx, const float* __restrict__ gw)
{
  int row = blockIdx.x;
  int t = threadIdx.x;
  __shared__ float sh[4];
  float g[6]; float ss = 0.f;
  u16* zr = zx + (size_t)row*ZLD;
  #pragma unroll
  for (int i = 0; i < 6; i++) {
    int c = t + i*256;
    g[i] = bf2f(zr[c]);
    ss += g[i]*g[i];
  }
  ss = blockSum256(ss, sh);
  float rs = rsqrtf(ss * (1.f/1536.f) + EPSF);
  #pragma unroll
  for (int i = 0; i < 6; i++) {
    int c = t + i*256;
    zr[c] = f2bf(g[i]*rs*gw[c]);
  }
}

// ---- head ----
__global__ __launch_bounds__(256)
void head_kernel(const float* __restrict__ x, const float* __restrict__ tw,
                 const float* __restrict__ tb, const float* __restrict__ im64,
                 float* __restrict__ out, float* __restrict__ partial)
{
  int bj = blockIdx.x;
  int b = bj >> 12, j = bj & 4095;
  int row = b*LTOT + 65 + j;
  const float* xr = x + (size_t)row*DM;
  int t = threadIdx.x;
  float p0 = 0, p1 = 0, p2 = 0;
  for (int k = t; k < 768; k += 256) {
    float xv = xr[k];
    p0 += xv*tw[k*3 + 0]; p1 += xv*tw[k*3 + 1]; p2 += xv*tw[k*3 + 2];
  }
  __shared__ float sh[4];
  p0 = blockSum256(p0, sh);
  p1 = blockSum256(p1, sh);
  p2 = blockSum256(p2, sh);
  if (t == 0) {
    float y0 = p0 + tb[0], y1 = p1 + tb[1], y2 = p2 + tb[2];
    size_t o = (size_t)bj*3;
    out[o] = y0; out[o + 1] = y1; out[o + 2] = y2;
    float d0 = y0 - im64[o], d1 = y1 - im64[o + 1], d2 = y2 - im64[o + 2];
    partial[bj] = d0*d0 + d1*d1 + d2*d2;
  }
}

__global__ __launch_bounds__(256)
void loss_reduce(const float* __restrict__ partial, float* __restrict__ out)
{
  int t = threadIdx.x;
  float s = 0.f;
  for (int i = t; i < BATCH*4096; i += 256) s += partial[i];
  __shared__ float sh[4];
  s = blockSum256(s, sh);
  if (t == 0) out[49152] = s * (1.f/49152.f);
}

// ---- launcher ----
static inline size_t alignup(size_t v){ return (v + 255) & ~(size_t)255; }

extern "C" void kernel_launch(void* const* d_in, const int* in_sizes, int n_in,
                              void* d_out, int out_size, void* d_ws, size_t ws_size,
                              hipStream_t stream)
{
  const float* im8        = (const float*)d_in[0];
  const float* im64       = (const float*)d_in[1];
  const float* from_rgb_w = (const float*)d_in[2];
  const float* from_rgb_b = (const float*)d_in[3];
  const float* to_rgb_w   = (const float*)d_in[4];
  const float* to_rgb_b   = (const float*)d_in[5];
  const float* s0         = (const float*)d_in[6];
  const float* suffix     = (const float*)d_in[7];
  const float* norm0_w    = (const float*)d_in[8];
  const float* norm0_b    = (const float*)d_in[9];
  const float* ln_w       = (const float*)d_in[10];
  const float* ln_b       = (const float*)d_in[11];
  const float* in_proj_w  = (const float*)d_in[12];
  const float* conv_w     = (const float*)d_in[13];
  const float* conv_b     = (const float*)d_in[14];
  const float* dt_bias    = (const float*)d_in[15];
  const float* A_log      = (const float*)d_in[16];
  const float* Dvec       = (const float*)d_in[17];
  const float* gn_w       = (const float*)d_in[18];
  const float* out_proj_w = (const float*)d_in[19];

  char* w = (char*)d_ws;
  size_t off = 0;
  float* x     = (float*)(w + off); off = alignup(off + (size_t)NROWS*DM*4);        // 51.1 MB
  u16*   zx    = (u16*)  (w + off); off = alignup(off + (size_t)NROWS*ZLD*2);       // 110.8 MB
  u16*   scr   = (u16*)  (w + off); off = alignup(off + (size_t)BATCH*NCH*NH*64*128*2); // 51.9 MB (wT / cstat alias)
  float* dt    = (float*)(w + off); off = alignup(off + (size_t)NROWS*NH*4);        // 1.6 MB
  float* murs  = (float*)(w + off); off = alignup(off + (size_t)NROWS*2*4);         // 133 KB
  float* dtot  = (float*)(w + off); off = alignup(off + (size_t)BATCH*NCH*NH*4);    // 12.7 KB
  float* lpart = (float*)(w + off); off = alignup(off + (size_t)BATCH*4096*4);      // 64 KB
  // total ~215.8 MB (< 222 MB known-good)
  u16* wT    = scr;
  u16* cstat = scr;

  build_x_kernel<<<NROWS, 256, 0, stream>>>(im8, from_rgb_w, from_rgb_b, s0, suffix,
                                            norm0_w, norm0_b, x);

  const int NBLK = BATCH*NCH*NH;   // 3168
  for (int i = 0; i < 4; i++) {
    row_stats_kernel<<<NROWS, 256, 0, stream>>>(x, murs);
    transp_bf16<<<dim3(NPAD1/32, DM/32), 256, 0, stream>>>(in_proj_w + (size_t)i*DM*DIP, wT, DM, DIP);
    gemm_ln<<<dim3(NPAD1/128, MPAD/128), 256, 0, stream>>>(
        x, murs, ln_w + i*DM, ln_b + i*DM, wT, zx, dt_bias + i*NH, dt);
    chunk_state_kernel<<<NBLK, 256, 0, stream>>>(zx, dt, A_log + i*NH,
        conv_w + (size_t)i*(DI+2*DS)*4, conv_b + i*(DI+2*DS), cstat, dtot);
    state_scan_kernel<<<BATCH*NH, 256, 0, stream>>>(cstat, dtot);
    chunk_output_kernel<<<NBLK, 256, 0, stream>>>(zx, dt, A_log + i*NH,
        conv_w + (size_t)i*(DI+2*DS)*4, conv_b + i*(DI+2*DS), Dvec + i*NH, cstat);
    gate_rms_kernel<<<NROWS, 256, 0, stream>>>(zx, gn_w + i*DI);
    transp_bf16<<<dim3(DM/32, DI/32), 256, 0, stream>>>(out_proj_w + (size_t)i*DI*DM, wT, DI, DM);
    gemm_out<<<dim3(DM/128, MPAD/128), 256, 0, stream>>>(zx, wT, x);
  }

  head_kernel<<<BATCH*4096, 256, 0, stream>>>(x, to_rgb_w, to_rgb_b, im64, (float*)d_out, lpart);
  loss_reduce<<<1, 256, 0, stream>>>(lpart, (float*)d_out);
}

// Round 5
// 4498.439 us; speedup vs baseline: 3.4236x; 1.8066x over previous
//
#include <hip/hip_runtime.h>
#include <hip/hip_bf16.h>
#include <math.h>

// ---- problem constants ----
#define LTOT 4161
#define BATCH 4
#define NROWS (BATCH*LTOT)      // 16644
#define MPAD 16768              // rows padded for 128-tile GEMM grid
#define NPAD1 3456              // 3352 -> padded to 128 multiple
#define DM 768
#define DI 1536
#define DIP 3352
#define ZLD 3328                // stored columns of zx
#define NH 24
#define HD 64
#define DS 128
#define EPSF 1e-5f
#define CHK 128                 // SSD chunk length
#define NCH 33                  // ceil(4161/128)
#define LDF 136                 // LDS row stride (u16) for 128-wide tiles
#define XLD 72                  // LDS row stride (u16) for raw-x staging (16B-aligned rows)

typedef __attribute__((ext_vector_type(8))) __bf16 bf16x8;
typedef __attribute__((ext_vector_type(4))) float f32x4;
typedef __attribute__((ext_vector_type(8))) short short8;
typedef __attribute__((ext_vector_type(4))) unsigned int u32x4;
typedef unsigned short u16;
typedef unsigned int u32;

static __device__ __forceinline__ u16 f2bf(float f){
  unsigned u = __builtin_bit_cast(unsigned, f);
  u += 0x7FFFu + ((u >> 16) & 1u);          // RNE
  return (u16)(u >> 16);
}
static __device__ __forceinline__ float bf2f(u16 v){
  return __builtin_bit_cast(float, ((unsigned)v) << 16);
}
static __device__ __forceinline__ float siluf(float v){ return v / (1.f + expf(-v)); }

__device__ __forceinline__ float blockSum256(float v, float* sh){
  #pragma unroll
  for (int o = 32; o > 0; o >>= 1) v += __shfl_down(v, o);
  int w = threadIdx.x >> 6;
  if ((threadIdx.x & 63) == 0) sh[w] = v;
  __syncthreads();
  v = sh[0] + sh[1] + sh[2] + sh[3];
  __syncthreads();
  return v;
}

// ---- build x = LN0(concat(s0, h8, zm)) ----
__global__ __launch_bounds__(256)
void build_x_kernel(const float* __restrict__ im8, const float* __restrict__ frw,
                    const float* __restrict__ frb, const float* __restrict__ s0,
                    const float* __restrict__ suffix, const float* __restrict__ w,
                    const float* __restrict__ bb, float* __restrict__ x)
{
  int row = blockIdx.x;
  int b = row / LTOT, l = row % LTOT;
  int t = threadIdx.x;
  __shared__ float sh[4];
  float v[3];
  if (l == 0) {
    #pragma unroll
    for (int i = 0; i < 3; i++) v[i] = s0[t + i*256];
  } else if (l <= 64) {
    int p = l - 1;
    float r0 = im8[(b*64 + p)*3 + 0], r1 = im8[(b*64 + p)*3 + 1], r2 = im8[(b*64 + p)*3 + 2];
    #pragma unroll
    for (int i = 0; i < 3; i++) {
      int d = t + i*256;
      v[i] = r0*frw[d] + r1*frw[768 + d] + r2*frw[1536 + d] + frb[d];
    }
  } else {
    int j = l - 65;
    int p = ((j >> 9) << 3) | ((j & 63) >> 3);
    float r0 = im8[(b*64 + p)*3 + 0], r1 = im8[(b*64 + p)*3 + 1], r2 = im8[(b*64 + p)*3 + 2];
    #pragma unroll
    for (int i = 0; i < 3; i++) {
      int d = t + i*256;
      v[i] = r0*frw[d] + r1*frw[768 + d] + r2*frw[1536 + d] + frb[d] + suffix[(size_t)j*768 + d];
    }
  }
  float s = v[0] + v[1] + v[2];
  s = blockSum256(s, sh);
  float mu = s * (1.f/768.f);
  float q = 0;
  #pragma unroll
  for (int i = 0; i < 3; i++) { float d = v[i] - mu; q += d*d; }
  q = blockSum256(q, sh);
  float rs = rsqrtf(q * (1.f/768.f) + EPSF);
  float* xr = x + (size_t)row*DM;
  #pragma unroll
  for (int i = 0; i < 3; i++) {
    int d = t + i*256;
    xr[d] = (v[i] - mu)*rs*w[d] + bb[d];
  }
}

// ---- per-row LN stats (mu, rstd) ----
__global__ __launch_bounds__(256)
void row_stats_kernel(const float* __restrict__ x, float* __restrict__ murs)
{
  int row = blockIdx.x;
  int t = threadIdx.x;
  __shared__ float sh[4];
  const float* xr = x + (size_t)row*DM;
  float v[3];
  #pragma unroll
  for (int i = 0; i < 3; i++) v[i] = xr[t + i*256];
  float s = v[0] + v[1] + v[2];
  s = blockSum256(s, sh);
  float mu = s * (1.f/768.f);
  float q = 0;
  #pragma unroll
  for (int i = 0; i < 3; i++) { float d = v[i] - mu; q += d*d; }
  q = blockSum256(q, sh);
  float rs = rsqrtf(q * (1.f/768.f) + EPSF);
  if (t == 0) { murs[2*row] = mu; murs[2*row + 1] = rs; }
}

// ---- transpose + f32->bf16: in (K x N) -> out (Npad x K); grid(Npad/32, K/32) ----
__global__ __launch_bounds__(256)
void transp_bf16(const float* __restrict__ in, u16* __restrict__ out, int K, int N)
{
  __shared__ float tl[32][33];
  int tx = threadIdx.x & 31, ty = threadIdx.x >> 5;
  int n0 = blockIdx.x * 32, k0 = blockIdx.y * 32;
  #pragma unroll
  for (int r = 0; r < 4; r++) {
    int k = k0 + ty + r*8, n = n0 + tx;
    tl[ty + r*8][tx] = (n < N) ? in[(size_t)k*N + n] : 0.f;
  }
  __syncthreads();
  #pragma unroll
  for (int r = 0; r < 4; r++) {
    int n = n0 + ty + r*8, k = k0 + tx;
    out[(size_t)n*K + k] = f2bf(tl[tx][ty + r*8]);
  }
}

// ---- GEMM0: zx[.]= LN(x) @ Wi  with LN fused into A-staging; dt epilogue ----
__global__ __launch_bounds__(256)
void gemm_ln(const float* __restrict__ X, const float* __restrict__ murs,
             const float* __restrict__ lnw, const float* __restrict__ lnb,
             const u16* __restrict__ BT, u16* __restrict__ zxO,
             const float* __restrict__ dtbias, float* __restrict__ dtO)
{
  __shared__ __align__(16) u16 As[128*40];
  __shared__ __align__(16) u16 Bs[128*40];
  __shared__ float wl[DM], bl[DM], muS[128], rsS[128];
  const int t = threadIdx.x;
  const int bm = blockIdx.y, bn = blockIdx.x;
  const int lane = t & 63, wave = t >> 6;
  const int wr = wave >> 1, wc = wave & 1;
  const int r16 = lane & 15, kb = lane >> 4;

  for (int i = t; i < DM; i += 256) { wl[i] = lnw[i]; bl[i] = lnb[i]; }
  if (t < 128) {
    int r = bm*128 + t;
    float m = 0.f, rr = 0.f;
    if (r < NROWS) { m = murs[2*r]; rr = murs[2*r + 1]; }
    muS[t] = m; rsS[t] = rr;
  }
  __syncthreads();

  const int m = t >> 1, half = t & 1;
  const int grow = bm*128 + m;
  const bool valid = grow < NROWS;
  const float* gX = X + (size_t)grow*DM + half*16;
  const u16* gB = BT + (size_t)(bn*128 + m)*DM + half*16;
  u16* wA = &As[m*40 + half*16];
  u16* wB = &Bs[m*40 + half*16];
  const float mu = muS[m], rs = rsS[m];

  f32x4 acc[4][4] = {};
  for (int kt = 0; kt < DM; kt += 32) {
    short8 b0 = *(const short8*)(gB + kt);
    short8 b1 = *(const short8*)(gB + kt + 8);
    short8 a0 = {}, a1 = {};
    if (valid) {
      const float* xp = gX + kt;
      const int c0 = kt + half*16;
      #pragma unroll
      for (int j = 0; j < 8; j++) a0[j] = (short)f2bf((xp[j]     - mu)*rs*wl[c0 + j]     + bl[c0 + j]);
      #pragma unroll
      for (int j = 0; j < 8; j++) a1[j] = (short)f2bf((xp[8 + j] - mu)*rs*wl[c0 + 8 + j] + bl[c0 + 8 + j]);
    }
    *(short8*)(wA)     = a0; *(short8*)(wA + 8) = a1;
    *(short8*)(wB)     = b0; *(short8*)(wB + 8) = b1;
    __syncthreads();
    bf16x8 af[4], bfr[4];
    #pragma unroll
    for (int i = 0; i < 4; i++) af[i]  = *(const bf16x8*)&As[(wr*64 + i*16 + r16)*40 + kb*8];
    #pragma unroll
    for (int i = 0; i < 4; i++) bfr[i] = *(const bf16x8*)&Bs[(wc*64 + i*16 + r16)*40 + kb*8];
    #pragma unroll
    for (int i = 0; i < 4; i++)
      #pragma unroll
      for (int j = 0; j < 4; j++)
        acc[i][j] = __builtin_amdgcn_mfma_f32_16x16x32_bf16(af[i], bfr[j], acc[i][j], 0, 0, 0);
    __syncthreads();
  }
  const int rbase = bm*128 + wr*64, cbase = bn*128 + wc*64;
  #pragma unroll
  for (int i = 0; i < 4; i++) {
    #pragma unroll
    for (int j = 0; j < 4; j++) {
      int col = cbase + j*16 + r16;
      #pragma unroll
      for (int e = 0; e < 4; e++) {
        int row = rbase + i*16 + kb*4 + e;
        if (row < NROWS) {
          float v = acc[i][j][e];
          if (col < ZLD) {
            zxO[(size_t)row*ZLD + col] = f2bf(v);
          } else if (col < DIP) {
            int hh = col - ZLD;
            float d = v + dtbias[hh];
            d = (d > 20.f) ? d : log1pf(expf(d));
            dtO[(size_t)row*NH + hh] = d;
          }
        }
      }
    }
  }
}

// ---- GEMM1: x += gated(zx cols 0..1535) @ Wo ; A from zx with lda=ZLD ----
__global__ __launch_bounds__(256)
void gemm_out(const u16* __restrict__ A, const u16* __restrict__ BT, float* __restrict__ X)
{
  __shared__ __align__(16) u16 As[128*40];
  __shared__ __align__(16) u16 Bs[128*40];
  const int t = threadIdx.x;
  const int bm = blockIdx.y, bn = blockIdx.x;
  const int lane = t & 63, wave = t >> 6;
  const int wr = wave >> 1, wc = wave & 1;
  const int r16 = lane & 15, kb = lane >> 4;

  const int m = t >> 1, half = t & 1;
  const int grow = bm*128 + m;
  const bool valid = grow < NROWS;
  const u16* gA = A + (size_t)grow*ZLD + half*16;
  const u16* gB = BT + (size_t)(bn*128 + m)*DI + half*16;
  u16* wA = &As[m*40 + half*16];
  u16* wB = &Bs[m*40 + half*16];

  f32x4 acc[4][4] = {};
  for (int kt = 0; kt < DI; kt += 32) {
    short8 b0 = *(const short8*)(gB + kt);
    short8 b1 = *(const short8*)(gB + kt + 8);
    short8 a0 = {}, a1 = {};
    if (valid) { a0 = *(const short8*)(gA + kt); a1 = *(const short8*)(gA + kt + 8); }
    *(short8*)(wA)     = a0; *(short8*)(wA + 8) = a1;
    *(short8*)(wB)     = b0; *(short8*)(wB + 8) = b1;
    __syncthreads();
    bf16x8 af[4], bfr[4];
    #pragma unroll
    for (int i = 0; i < 4; i++) af[i]  = *(const bf16x8*)&As[(wr*64 + i*16 + r16)*40 + kb*8];
    #pragma unroll
    for (int i = 0; i < 4; i++) bfr[i] = *(const bf16x8*)&Bs[(wc*64 + i*16 + r16)*40 + kb*8];
    #pragma unroll
    for (int i = 0; i < 4; i++)
      #pragma unroll
      for (int j = 0; j < 4; j++)
        acc[i][j] = __builtin_amdgcn_mfma_f32_16x16x32_bf16(af[i], bfr[j], acc[i][j], 0, 0, 0);
    __syncthreads();
  }
  const int rbase = bm*128 + wr*64, cbase = bn*128 + wc*64;
  #pragma unroll
  for (int i = 0; i < 4; i++) {
    #pragma unroll
    for (int j = 0; j < 4; j++) {
      int col = cbase + j*16 + r16;
      #pragma unroll
      for (int e = 0; e < 4; e++) {
        int row = rbase + i*16 + kb*4 + e;
        if (row < NROWS) X[(size_t)row*DM + col] += acc[i][j][e];
      }
    }
  }
}

// ======================= chunked SSD =======================
// zx row layout (bf16, ld ZLD): [0,1536) z | [1536,3072) x raw | [3072,3200) B raw | [3200,3328) C raw
// slab id = (b*NCH + c)*NH + h ; cstat[id][p(64)][n(128)] bf16 ; dtot[id] f32
// Raw tiles staged with +3 row shift: LDS row r  <->  global row base-3+r (r in [0,131))

// ---- K1: per-chunk state ----
__global__ __launch_bounds__(256)
void chunk_state_kernel(const u16* __restrict__ zx, const float* __restrict__ dtb,
                        const float* __restrict__ alog, const float* __restrict__ cw,
                        const float* __restrict__ cb, u16* __restrict__ cstat,
                        float* __restrict__ dtot)
{
  const int id = blockIdx.x;
  const int h = id % NH; const int c = (id / NH) % NCH; const int b = id / (NH*NCH);
  const int t = threadIdx.x;
  const int base = c*CHK;
  int rows = LTOT - base; if (rows > CHK) rows = CHK;

  __shared__ __align__(16) u16 Bbuf[132*LDF];   // raw B [131][.] -> BTs[n][j]
  __shared__ __align__(16) u16 xbuf[131*XLD + 8]; // raw x [131][XLD] -> xsT[64][LDF]
  __shared__ float dtv[128];
  __shared__ float cs[128];
  __shared__ float wjs[128];

  const u16* zb = zx + (size_t)(b*LTOT)*ZLD;
  const float aexp = expf(alog[h]);
  if (t < 128) {
    float dv = 0.f;
    if (t < rows) dv = dtb[(size_t)(b*LTOT + base + t)*NH + h];
    dtv[t] = dv; cs[t] = -dv * aexp;
  }
  // stage raw B (cols 3072..3199): 16 rows/round
  #pragma unroll
  for (int rg = 0; rg < 9; rg++) {
    int r = rg*16 + (t >> 4);
    int seg = t & 15;
    if (r < 131) {
      int g = base - 3 + r;
      short8 v = {};
      if (g >= 0 && g < LTOT) v = *(const short8*)(zb + (size_t)g*ZLD + 3072 + seg*8);
      *(short8*)&Bbuf[r*LDF + seg*8] = v;
    }
  }
  // stage raw x (this head's 64 cols): 32 rows/round
  #pragma unroll
  for (int rg = 0; rg < 5; rg++) {
    int r = rg*32 + (t >> 3);
    int seg = t & 7;
    if (r < 131) {
      int g = base - 3 + r;
      short8 v = {};
      if (g >= 0 && g < LTOT) v = *(const short8*)(zb + (size_t)g*ZLD + 1536 + h*HD + seg*8);
      *(short8*)&xbuf[r*XLD + seg*8] = v;
    }
  }
  __syncthreads();
  // prefix sum of dtA
  for (int off = 1; off < 128; off <<= 1) {
    float add = 0.f;
    if (t < 128 && t >= off) add = cs[t - off];
    __syncthreads();
    if (t < 128) cs[t] += add;
    __syncthreads();
  }
  if (t < 128) wjs[t] = expf(cs[127] - cs[t]) * dtv[t];
  __syncthreads();

  // B conv -> regs (64 outputs, packed)
  const int n_ = t & 127, jh = t >> 7;
  u32 pkB[32];
  {
    const int ch = 1536 + n_;
    float w0 = cw[ch*4+0], w1 = cw[ch*4+1], w2 = cw[ch*4+2], w3 = cw[ch*4+3];
    float bias = cb[ch];
    const int rb = jh*64;
    float r0 = bf2f(Bbuf[(rb+0)*LDF + n_]);
    float r1 = bf2f(Bbuf[(rb+1)*LDF + n_]);
    float r2 = bf2f(Bbuf[(rb+2)*LDF + n_]);
    #pragma unroll
    for (int k2 = 0; k2 < 32; k2++) {
      float r3 = bf2f(Bbuf[(rb + 2*k2 + 3)*LDF + n_]);
      float o0 = bias + w0*r0 + w1*r1 + w2*r2 + w3*r3;
      float r4 = bf2f(Bbuf[(rb + 2*k2 + 4)*LDF + n_]);
      float o1 = bias + w0*r1 + w1*r2 + w2*r3 + w3*r4;
      pkB[k2] = (u32)f2bf(siluf(o0)) | ((u32)f2bf(siluf(o1)) << 16);
      r0 = r2; r1 = r3; r2 = r4;
    }
  }
  // x conv -> regs (32 outputs, scaled by wjs)
  const int p_ = t & 63, jq = t >> 6;
  u32 pkx[16];
  {
    const int ch = h*HD + p_;
    float w0 = cw[ch*4+0], w1 = cw[ch*4+1], w2 = cw[ch*4+2], w3 = cw[ch*4+3];
    float bias = cb[ch];
    const int rb = jq*32;
    float r0 = bf2f(xbuf[(rb+0)*XLD + p_]);
    float r1 = bf2f(xbuf[(rb+1)*XLD + p_]);
    float r2 = bf2f(xbuf[(rb+2)*XLD + p_]);
    #pragma unroll
    for (int k2 = 0; k2 < 16; k2++) {
      float r3 = bf2f(xbuf[(rb + 2*k2 + 3)*XLD + p_]);
      float o0 = bias + w0*r0 + w1*r1 + w2*r2 + w3*r3;
      float r4 = bf2f(xbuf[(rb + 2*k2 + 4)*XLD + p_]);
      float o1 = bias + w0*r1 + w1*r2 + w2*r3 + w3*r4;
      float s0 = siluf(o0) * wjs[rb + 2*k2];
      float s1 = siluf(o1) * wjs[rb + 2*k2 + 1];
      pkx[k2] = (u32)f2bf(s0) | ((u32)f2bf(s1) << 16);
      r0 = r2; r1 = r3; r2 = r4;
    }
  }
  __syncthreads();   // all raw reads done
  // write BTs[n][j] and xsT[p][j]
  #pragma unroll
  for (int q = 0; q < 8; q++) {
    u32x4 v; v[0] = pkB[q*4]; v[1] = pkB[q*4+1]; v[2] = pkB[q*4+2]; v[3] = pkB[q*4+3];
    *(u32x4*)&Bbuf[n_*LDF + jh*64 + q*8] = v;
  }
  #pragma unroll
  for (int q = 0; q < 4; q++) {
    u32x4 v; v[0] = pkx[q*4]; v[1] = pkx[q*4+1]; v[2] = pkx[q*4+2]; v[3] = pkx[q*4+3];
    *(u32x4*)&xbuf[p_*LDF + jq*32 + q*8] = v;
  }
  __syncthreads();

  // chunk_state[p][n] = sum_j xsT[p][j] * BTs[n][j]
  const int lane = t & 63, wave = t >> 6;
  const int r16 = lane & 15, kb = lane >> 4;
  const int n0 = wave*32;
  f32x4 acc[4][2] = {};
  #pragma unroll
  for (int kt = 0; kt < 4; kt++) {
    bf16x8 af[4], bfr[2];
    #pragma unroll
    for (int m = 0; m < 4; m++) af[m] = *(const bf16x8*)&xbuf[(m*16 + r16)*LDF + kt*32 + kb*8];
    #pragma unroll
    for (int nn = 0; nn < 2; nn++) bfr[nn] = *(const bf16x8*)&Bbuf[(n0 + nn*16 + r16)*LDF + kt*32 + kb*8];
    #pragma unroll
    for (int m = 0; m < 4; m++)
      #pragma unroll
      for (int nn = 0; nn < 2; nn++)
        acc[m][nn] = __builtin_amdgcn_mfma_f32_16x16x32_bf16(af[m], bfr[nn], acc[m][nn], 0, 0, 0);
  }
  u16* dst = cstat + (size_t)id*64*128;
  #pragma unroll
  for (int m = 0; m < 4; m++)
    #pragma unroll
    for (int nn = 0; nn < 2; nn++)
      #pragma unroll
      for (int e = 0; e < 4; e++) {
        int p = m*16 + kb*4 + e;
        int n = n0 + nn*16 + r16;
        dst[p*128 + n] = f2bf(acc[m][nn][e]);
      }
  if (t == 0) dtot[id] = expf(cs[127]);
}

// ---- K2: inter-chunk scan (in-place: slot <- state BEFORE that chunk) ----
__global__ __launch_bounds__(256)
void state_scan_kernel(u16* __restrict__ cstat, const float* __restrict__ dtot)
{
  const int b = blockIdx.x / NH, h = blockIdx.x % NH;
  const int t = threadIdx.x;
  float run[32];
  #pragma unroll
  for (int k = 0; k < 32; k++) run[k] = 0.f;
  size_t id0 = (size_t)(b*NCH)*NH + h;
  short8 cur[4];
  {
    const u16* s0 = cstat + id0*8192 + t*32;
    #pragma unroll
    for (int q = 0; q < 4; q++) cur[q] = *(const short8*)(s0 + q*8);
  }
  float d = dtot[id0];
  for (int c = 0; c < NCH; ++c) {
    size_t id = (size_t)(b*NCH + c)*NH + h;
    u16* slab = cstat + id*8192 + t*32;
    short8 nxt[4] = {}; float nd = 0.f;
    if (c + 1 < NCH) {
      const u16* sn = slab + (size_t)NH*8192;
      #pragma unroll
      for (int q = 0; q < 4; q++) nxt[q] = *(const short8*)(sn + q*8);
      nd = dtot[id + NH];
    }
    short8 out[4];
    #pragma unroll
    for (int q = 0; q < 4; q++)
      #pragma unroll
      for (int k = 0; k < 8; k++) {
        int idx = q*8 + k;
        float csv = bf2f((u16)cur[q][k]);
        out[q][k] = (short)f2bf(run[idx]);
        run[idx] = run[idx]*d + csv;
      }
    #pragma unroll
    for (int q = 0; q < 4; q++) *(short8*)(slab + q*8) = out[q];
    #pragma unroll
    for (int q = 0; q < 4; q++) cur[q] = nxt[q];
    d = nd;
  }
}

// ---- K3: per-chunk output; writes y*silu(z) over z-columns of zx ----
__global__ __launch_bounds__(256)
void chunk_output_kernel(u16* __restrict__ zx, const float* __restrict__ dtb,
                         const float* __restrict__ alog, const float* __restrict__ cw,
                         const float* __restrict__ cb, const float* __restrict__ Dvec,
                         const u16* __restrict__ cstat)
{
  const int id = blockIdx.x;
  const int h = id % NH; const int c = (id / NH) % NCH; const int b = id / (NH*NCH);
  const int t = threadIdx.x;
  const int base = c*CHK;
  int rows = LTOT - base; if (rows > CHK) rows = CHK;

  __shared__ __align__(16) u16 Bc[132*LDF];     // raw B(+3 shift) -> conv'd B rows 0..127 -> P[i][j]
  __shared__ __align__(16) u16 Cc[132*LDF];     // raw C -> conv'd C rows 0..127
  __shared__ __align__(16) u16 stT[64*LDF];     // state_before [p][n]
  __shared__ __align__(16) u16 xbuf[131*XLD + 8]; // raw x [131][XLD] -> xc[64][LDF]
  __shared__ float dtv[128];
  __shared__ float cs[128];

  const u16* zb = zx + (size_t)(b*LTOT)*ZLD;
  const float aexp = expf(alog[h]);
  if (t < 128) {
    float dv = 0.f;
    if (t < rows) dv = dtb[(size_t)(b*LTOT + base + t)*NH + h];
    dtv[t] = dv; cs[t] = -dv * aexp;
  }
  // stage state_before
  {
    const u16* slab = cstat + (size_t)id*8192;
    int p = t >> 2, nb = (t & 3)*32;
    #pragma unroll
    for (int q = 0; q < 4; q++)
      *(short8*)&stT[p*LDF + nb + q*8] = *(const short8*)(slab + p*128 + nb + q*8);
  }
  // stage raw B/C (cols 3072..3327): 8 rows/round
  #pragma unroll
  for (int rg = 0; rg < 17; rg++) {
    int r = rg*8 + (t >> 5);
    int seg = t & 31;
    if (r < 131) {
      int g = base - 3 + r;
      short8 v = {};
      if (g >= 0 && g < LTOT) v = *(const short8*)(zb + (size_t)g*ZLD + 3072 + seg*8);
      if (seg < 16) *(short8*)&Bc[r*LDF + seg*8] = v;
      else          *(short8*)&Cc[r*LDF + (seg - 16)*8] = v;
    }
  }
  // stage raw x
  #pragma unroll
  for (int rg = 0; rg < 5; rg++) {
    int r = rg*32 + (t >> 3);
    int seg = t & 7;
    if (r < 131) {
      int g = base - 3 + r;
      short8 v = {};
      if (g >= 0 && g < LTOT) v = *(const short8*)(zb + (size_t)g*ZLD + 1536 + h*HD + seg*8);
      *(short8*)&xbuf[r*XLD + seg*8] = v;
    }
  }
  __syncthreads();
  // prefix sum of dtA
  for (int off = 1; off < 128; off <<= 1) {
    float add = 0.f;
    if (t < 128 && t >= off) add = cs[t - off];
    __syncthreads();
    if (t < 128) cs[t] += add;
    __syncthreads();
  }

  // x conv -> regs (transpose to xc[p][j])
  const int p_ = t & 63, jq = t >> 6;
  u32 pkx[16];
  {
    const int ch = h*HD + p_;
    float w0 = cw[ch*4+0], w1 = cw[ch*4+1], w2 = cw[ch*4+2], w3 = cw[ch*4+3];
    float bias = cb[ch];
    const int rb = jq*32;
    float r0 = bf2f(xbuf[(rb+0)*XLD + p_]);
    float r1 = bf2f(xbuf[(rb+1)*XLD + p_]);
    float r2 = bf2f(xbuf[(rb+2)*XLD + p_]);
    #pragma unroll
    for (int k2 = 0; k2 < 16; k2++) {
      float r3 = bf2f(xbuf[(rb + 2*k2 + 3)*XLD + p_]);
      float o0 = bias + w0*r0 + w1*r1 + w2*r2 + w3*r3;
      float r4 = bf2f(xbuf[(rb + 2*k2 + 4)*XLD + p_]);
      float o1 = bias + w0*r1 + w1*r2 + w2*r3 + w3*r4;
      int j0 = rb + 2*k2;
      u32 lo = (j0     < rows) ? (u32)f2bf(siluf(o0)) : 0u;
      u32 hi = (j0 + 1 < rows) ? (u32)f2bf(siluf(o1)) : 0u;
      pkx[k2] = lo | (hi << 16);
      r0 = r2; r1 = r3; r2 = r4;
    }
  }
  // B/C halo + initial rolling preloads (pre-barrier: rows rbase+64..66 are the cross-thread hazard)
  const int n_ = t & 127, jh = t >> 7;
  const int rbase = jh*64;
  float hB0 = bf2f(Bc[(rbase+64)*LDF + n_]);
  float hB1 = bf2f(Bc[(rbase+65)*LDF + n_]);
  float hB2 = bf2f(Bc[(rbase+66)*LDF + n_]);
  float hC0 = bf2f(Cc[(rbase+64)*LDF + n_]);
  float hC1 = bf2f(Cc[(rbase+65)*LDF + n_]);
  float hC2 = bf2f(Cc[(rbase+66)*LDF + n_]);
  float rB0 = bf2f(Bc[(rbase+0)*LDF + n_]);
  float rB1 = bf2f(Bc[(rbase+1)*LDF + n_]);
  float rB2 = bf2f(Bc[(rbase+2)*LDF + n_]);
  float rC0 = bf2f(Cc[(rbase+0)*LDF + n_]);
  float rC1 = bf2f(Cc[(rbase+1)*LDF + n_]);
  float rC2 = bf2f(Cc[(rbase+2)*LDF + n_]);
  __syncthreads();
  // in-place conv B (reads row j+3 before self writes row j; cross-half hazards preloaded)
  {
    const int ch = 1536 + n_;
    float w0 = cw[ch*4+0], w1 = cw[ch*4+1], w2 = cw[ch*4+2], w3 = cw[ch*4+3];
    float bias = cb[ch];
    float r0 = rB0, r1 = rB1, r2 = rB2;
    #pragma unroll
    for (int j = 0; j < 64; j++) {
      float r3 = (j < 61) ? bf2f(Bc[(rbase + j + 3)*LDF + n_])
                          : (j == 61 ? hB0 : (j == 62 ? hB1 : hB2));
      float o = bias + w0*r0 + w1*r1 + w2*r2 + w3*r3;
      Bc[(rbase + j)*LDF + n_] = f2bf(siluf(o));
      r0 = r1; r1 = r2; r2 = r3;
    }
  }
  // in-place conv C
  {
    const int ch = 1664 + n_;
    float w0 = cw[ch*4+0], w1 = cw[ch*4+1], w2 = cw[ch*4+2], w3 = cw[ch*4+3];
    float bias = cb[ch];
    float r0 = rC0, r1 = rC1, r2 = rC2;
    #pragma unroll
    for (int j = 0; j < 64; j++) {
      float r3 = (j < 61) ? bf2f(Cc[(rbase + j + 3)*LDF + n_])
                          : (j == 61 ? hC0 : (j == 62 ? hC1 : hC2));
      float o = bias + w0*r0 + w1*r1 + w2*r2 + w3*r3;
      Cc[(rbase + j)*LDF + n_] = f2bf(siluf(o));
      r0 = r1; r1 = r2; r2 = r3;
    }
  }
  // write xc[p][j] over xbuf (raw x fully consumed pre-barrier)
  #pragma unroll
  for (int q = 0; q < 4; q++) {
    u32x4 v; v[0] = pkx[q*4]; v[1] = pkx[q*4+1]; v[2] = pkx[q*4+2]; v[3] = pkx[q*4+3];
    *(u32x4*)&xbuf[p_*LDF + jq*32 + q*8] = v;
  }
  __syncthreads();

  const int lane = t & 63, wave = t >> 6;
  const int r16 = lane & 15, kb = lane >> 4;

  // Phase A: S[i][j] = sum_n Cc[i][n]*Bc[j][n]; then P into Bc
  {
    const int wi = wave >> 1, wjn = wave & 1;
    f32x4 acc[4][4] = {};
    #pragma unroll
    for (int kt = 0; kt < 4; kt++) {
      bf16x8 af[4], bfr[4];
      #pragma unroll
      for (int m = 0; m < 4; m++) af[m] = *(const bf16x8*)&Cc[(wi*64 + m*16 + r16)*LDF + kt*32 + kb*8];
      #pragma unroll
      for (int nj = 0; nj < 4; nj++) bfr[nj] = *(const bf16x8*)&Bc[(wjn*64 + nj*16 + r16)*LDF + kt*32 + kb*8];
      #pragma unroll
      for (int m = 0; m < 4; m++)
        #pragma unroll
        for (int nj = 0; nj < 4; nj++)
          acc[m][nj] = __builtin_amdgcn_mfma_f32_16x16x32_bf16(af[m], bfr[nj], acc[m][nj], 0, 0, 0);
    }
    __syncthreads();   // all Bc reads done -> safe to overwrite with P
    #pragma unroll
    for (int m = 0; m < 4; m++)
      #pragma unroll
      for (int nj = 0; nj < 4; nj++)
        #pragma unroll
        for (int e = 0; e < 4; e++) {
          int i = wi*64 + m*16 + kb*4 + e;
          int j = wjn*64 + nj*16 + r16;
          float f = 0.f;
          if (j <= i && i < rows) f = expf(cs[i] - cs[j]) * dtv[j];
          Bc[i*LDF + j] = f2bf(acc[m][nj][e] * f);
        }
  }
  __syncthreads();

  // Phase B: Y1 = P @ xc^T ; Phase C: Y2 = Cc @ stT^T ; write gated y over z
  {
    const int iq = wave;
    f32x4 accY[2][4] = {};
    #pragma unroll
    for (int kt = 0; kt < 4; kt++) {
      bf16x8 af[2], bfr[4];
      #pragma unroll
      for (int m = 0; m < 2; m++) af[m] = *(const bf16x8*)&Bc[(iq*32 + m*16 + r16)*LDF + kt*32 + kb*8];
      #pragma unroll
      for (int n = 0; n < 4; n++) bfr[n] = *(const bf16x8*)&xbuf[(n*16 + r16)*LDF + kt*32 + kb*8];
      #pragma unroll
      for (int m = 0; m < 2; m++)
        #pragma unroll
        for (int n = 0; n < 4; n++)
          accY[m][n] = __builtin_amdgcn_mfma_f32_16x16x32_bf16(af[m], bfr[n], accY[m][n], 0, 0, 0);
    }
    f32x4 accS[2][4] = {};
    #pragma unroll
    for (int kt = 0; kt < 4; kt++) {
      bf16x8 af[2], bfr[4];
      #pragma unroll
      for (int m = 0; m < 2; m++) af[m] = *(const bf16x8*)&Cc[(iq*32 + m*16 + r16)*LDF + kt*32 + kb*8];
      #pragma unroll
      for (int n = 0; n < 4; n++) bfr[n] = *(const bf16x8*)&stT[(n*16 + r16)*LDF + kt*32 + kb*8];
      #pragma unroll
      for (int m = 0; m < 2; m++)
        #pragma unroll
        for (int n = 0; n < 4; n++)
          accS[m][n] = __builtin_amdgcn_mfma_f32_16x16x32_bf16(af[m], bfr[n], accS[m][n], 0, 0, 0);
    }
    const float dcoef = Dvec[h];
    #pragma unroll
    for (int m = 0; m < 2; m++)
      #pragma unroll
      for (int e = 0; e < 4; e++) {
        int i = iq*32 + m*16 + kb*4 + e;
        if (i < rows) {
          float sc = expf(cs[i]);
          size_t orow = (size_t)(b*LTOT + base + i)*ZLD + h*HD;
          #pragma unroll
          for (int n = 0; n < 4; n++) {
            int p = n*16 + r16;
            float xv = bf2f(xbuf[p*LDF + i]);
            float yv = accY[m][n][e] + sc*accS[m][n][e] + dcoef*xv;
            float zval = bf2f(zx[orow + p]);
            zx[orow + p] = f2bf(yv * siluf(zval));
          }
        }
      }
  }
}

// ---- rmsnorm in place on zx cols [0,1536) ----
__global__ __launch_bounds__(256)
void gate_rms_kernel(u16* __restrict__ zx, const float* __restrict__ gw)
{
  int row = blockIdx.x;
  int t = threadIdx.x;
  __shared__ float sh[4];
  float g[6]; float ss = 0.f;
  u16* zr = zx + (size_t)row*ZLD;
  #pragma unroll
  for (int i = 0; i < 6; i++) {
    int c = t + i*256;
    g[i] = bf2f(zr[c]);
    ss += g[i]*g[i];
  }
  ss = blockSum256(ss, sh);
  float rs = rsqrtf(ss * (1.f/1536.f) + EPSF);
  #pragma unroll
  for (int i = 0; i < 6; i++) {
    int c = t + i*256;
    zr[c] = f2bf(g[i]*rs*gw[c]);
  }
}

// ---- head ----
__global__ __launch_bounds__(256)
void head_kernel(const float* __restrict__ x, const float* __restrict__ tw,
                 const float* __restrict__ tb, const float* __restrict__ im64,
                 float* __restrict__ out, float* __restrict__ partial)
{
  int bj = blockIdx.x;
  int b = bj >> 12, j = bj & 4095;
  int row = b*LTOT + 65 + j;
  const float* xr = x + (size_t)row*DM;
  int t = threadIdx.x;
  float p0 = 0, p1 = 0, p2 = 0;
  for (int k = t; k < 768; k += 256) {
    float xv = xr[k];
    p0 += xv*tw[k*3 + 0]; p1 += xv*tw[k*3 + 1]; p2 += xv*tw[k*3 + 2];
  }
  __shared__ float sh[4];
  p0 = blockSum256(p0, sh);
  p1 = blockSum256(p1, sh);
  p2 = blockSum256(p2, sh);
  if (t == 0) {
    float y0 = p0 + tb[0], y1 = p1 + tb[1], y2 = p2 + tb[2];
    size_t o = (size_t)bj*3;
    out[o] = y0; out[o + 1] = y1; out[o + 2] = y2;
    float d0 = y0 - im64[o], d1 = y1 - im64[o + 1], d2 = y2 - im64[o + 2];
    partial[bj] = d0*d0 + d1*d1 + d2*d2;
  }
}

__global__ __launch_bounds__(256)
void loss_reduce(const float* __restrict__ partial, float* __restrict__ out)
{
  int t = threadIdx.x;
  float s = 0.f;
  for (int i = t; i < BATCH*4096; i += 256) s += partial[i];
  __shared__ float sh[4];
  s = blockSum256(s, sh);
  if (t == 0) out[49152] = s * (1.f/49152.f);
}

// ---- launcher ----
static inline size_t alignup(size_t v){ return (v + 255) & ~(size_t)255; }

extern "C" void kernel_launch(void* const* d_in, const int* in_sizes, int n_in,
                              void* d_out, int out_size, void* d_ws, size_t ws_size,
                              hipStream_t stream)
{
  const float* im8        = (const float*)d_in[0];
  const float* im64       = (const float*)d_in[1];
  const float* from_rgb_w = (const float*)d_in[2];
  const float* from_rgb_b = (const float*)d_in[3];
  const float* to_rgb_w   = (const float*)d_in[4];
  const float* to_rgb_b   = (const float*)d_in[5];
  const float* s0         = (const float*)d_in[6];
  const float* suffix     = (const float*)d_in[7];
  const float* norm0_w    = (const float*)d_in[8];
  const float* norm0_b    = (const float*)d_in[9];
  const float* ln_w       = (const float*)d_in[10];
  const float* ln_b       = (const float*)d_in[11];
  const float* in_proj_w  = (const float*)d_in[12];
  const float* conv_w     = (const float*)d_in[13];
  const float* conv_b     = (const float*)d_in[14];
  const float* dt_bias    = (const float*)d_in[15];
  const float* A_log      = (const float*)d_in[16];
  const float* Dvec       = (const float*)d_in[17];
  const float* gn_w       = (const float*)d_in[18];
  const float* out_proj_w = (const float*)d_in[19];

  char* w = (char*)d_ws;
  size_t off = 0;
  float* x     = (float*)(w + off); off = alignup(off + (size_t)NROWS*DM*4);        // 51.1 MB
  u16*   zx    = (u16*)  (w + off); off = alignup(off + (size_t)NROWS*ZLD*2);       // 110.8 MB
  u16*   scr   = (u16*)  (w + off); off = alignup(off + (size_t)BATCH*NCH*NH*64*128*2); // 51.9 MB (wT / cstat alias)
  float* dt    = (float*)(w + off); off = alignup(off + (size_t)NROWS*NH*4);        // 1.6 MB
  float* murs  = (float*)(w + off); off = alignup(off + (size_t)NROWS*2*4);         // 133 KB
  float* dtot  = (float*)(w + off); off = alignup(off + (size_t)BATCH*NCH*NH*4);    // 12.7 KB
  float* lpart = (float*)(w + off); off = alignup(off + (size_t)BATCH*4096*4);      // 64 KB
  // total ~215.8 MB
  u16* wT    = scr;
  u16* cstat = scr;

  build_x_kernel<<<NROWS, 256, 0, stream>>>(im8, from_rgb_w, from_rgb_b, s0, suffix,
                                            norm0_w, norm0_b, x);

  const int NBLK = BATCH*NCH*NH;   // 3168
  for (int i = 0; i < 4; i++) {
    row_stats_kernel<<<NROWS, 256, 0, stream>>>(x, murs);
    transp_bf16<<<dim3(NPAD1/32, DM/32), 256, 0, stream>>>(in_proj_w + (size_t)i*DM*DIP, wT, DM, DIP);
    gemm_ln<<<dim3(NPAD1/128, MPAD/128), 256, 0, stream>>>(
        x, murs, ln_w + i*DM, ln_b + i*DM, wT, zx, dt_bias + i*NH, dt);
    chunk_state_kernel<<<NBLK, 256, 0, stream>>>(zx, dt, A_log + i*NH,
        conv_w + (size_t)i*(DI+2*DS)*4, conv_b + i*(DI+2*DS), cstat, dtot);
    state_scan_kernel<<<BATCH*NH, 256, 0, stream>>>(cstat, dtot);
    chunk_output_kernel<<<NBLK, 256, 0, stream>>>(zx, dt, A_log + i*NH,
        conv_w + (size_t)i*(DI+2*DS)*4, conv_b + i*(DI+2*DS), Dvec + i*NH, cstat);
    gate_rms_kernel<<<NROWS, 256, 0, stream>>>(zx, gn_w + i*DI);
    transp_bf16<<<dim3(DM/32, DI/32), 256, 0, stream>>>(out_proj_w + (size_t)i*DI*DM, wT, DI, DM);
    gemm_out<<<dim3(DM/128, MPAD/128), 256, 0, stream>>>(zx, wT, x);
  }

  head_kernel<<<BATCH*4096, 256, 0, stream>>>(x, to_rgb_w, to_rgb_b, im64, (float*)d_out, lpart);
  loss_reduce<<<1, 256, 0, stream>>>(lpart, (float*)d_out);
}

// Round 6
// 3205.912 us; speedup vs baseline: 4.8039x; 1.4032x over previous
//
#include <hip/hip_runtime.h>
#include <hip/hip_bf16.h>
#include <math.h>

// ---- problem constants ----
#define LTOT 4161
#define BATCH 4
#define NROWS (BATCH*LTOT)      // 16644
#define MPAD 16768              // rows padded for 128-tile GEMM grid
#define NPAD1 3456              // 3352 -> padded to 128 multiple
#define DM 768
#define DI 1536
#define DIP 3352
#define ZLD 3328                // stored columns of zx
#define NH 24
#define HD 64
#define DS 128
#define EPSF 1e-5f
#define CHK 128                 // SSD chunk length
#define NCH 33                  // ceil(4161/128)
#define LDF 136                 // LDS row stride (u16) for 128-wide tiles
#define XLD 72                  // LDS row stride (u16) for raw-x staging

typedef __attribute__((ext_vector_type(8))) __bf16 bf16x8;
typedef __attribute__((ext_vector_type(4))) float f32x4;
typedef __attribute__((ext_vector_type(8))) short short8;
typedef __attribute__((ext_vector_type(4))) unsigned int u32x4;
typedef unsigned short u16;
typedef unsigned int u32;

static __device__ __forceinline__ u16 f2bf(float f){
  unsigned u = __builtin_bit_cast(unsigned, f);
  u += 0x7FFFu + ((u >> 16) & 1u);          // RNE
  return (u16)(u >> 16);
}
static __device__ __forceinline__ float bf2f(u16 v){
  return __builtin_bit_cast(float, ((unsigned)v) << 16);
}
static __device__ __forceinline__ float siluf(float v){ return v / (1.f + __expf(-v)); }

__device__ __forceinline__ float blockSum256(float v, float* sh){
  #pragma unroll
  for (int o = 32; o > 0; o >>= 1) v += __shfl_down(v, o);
  int w = threadIdx.x >> 6;
  if ((threadIdx.x & 63) == 0) sh[w] = v;
  __syncthreads();
  v = sh[0] + sh[1] + sh[2] + sh[3];
  __syncthreads();
  return v;
}

// ---- build x = LN0(concat(s0, h8, zm)) ----
__global__ __launch_bounds__(256)
void build_x_kernel(const float* __restrict__ im8, const float* __restrict__ frw,
                    const float* __restrict__ frb, const float* __restrict__ s0,
                    const float* __restrict__ suffix, const float* __restrict__ w,
                    const float* __restrict__ bb, float* __restrict__ x)
{
  int row = blockIdx.x;
  int b = row / LTOT, l = row % LTOT;
  int t = threadIdx.x;
  __shared__ float sh[4];
  float v[3];
  if (l == 0) {
    #pragma unroll
    for (int i = 0; i < 3; i++) v[i] = s0[t + i*256];
  } else if (l <= 64) {
    int p = l - 1;
    float r0 = im8[(b*64 + p)*3 + 0], r1 = im8[(b*64 + p)*3 + 1], r2 = im8[(b*64 + p)*3 + 2];
    #pragma unroll
    for (int i = 0; i < 3; i++) {
      int d = t + i*256;
      v[i] = r0*frw[d] + r1*frw[768 + d] + r2*frw[1536 + d] + frb[d];
    }
  } else {
    int j = l - 65;
    int p = ((j >> 9) << 3) | ((j & 63) >> 3);
    float r0 = im8[(b*64 + p)*3 + 0], r1 = im8[(b*64 + p)*3 + 1], r2 = im8[(b*64 + p)*3 + 2];
    #pragma unroll
    for (int i = 0; i < 3; i++) {
      int d = t + i*256;
      v[i] = r0*frw[d] + r1*frw[768 + d] + r2*frw[1536 + d] + frb[d] + suffix[(size_t)j*768 + d];
    }
  }
  float s = v[0] + v[1] + v[2];
  s = blockSum256(s, sh);
  float mu = s * (1.f/768.f);
  float q = 0;
  #pragma unroll
  for (int i = 0; i < 3; i++) { float d = v[i] - mu; q += d*d; }
  q = blockSum256(q, sh);
  float rs = rsqrtf(q * (1.f/768.f) + EPSF);
  float* xr = x + (size_t)row*DM;
  #pragma unroll
  for (int i = 0; i < 3; i++) {
    int d = t + i*256;
    xr[d] = (v[i] - mu)*rs*w[d] + bb[d];
  }
}

// ---- per-row LN stats (mu, rstd) ----
__global__ __launch_bounds__(256)
void row_stats_kernel(const float* __restrict__ x, float* __restrict__ murs)
{
  int row = blockIdx.x;
  int t = threadIdx.x;
  __shared__ float sh[4];
  const float* xr = x + (size_t)row*DM;
  float v[3];
  #pragma unroll
  for (int i = 0; i < 3; i++) v[i] = xr[t + i*256];
  float s = v[0] + v[1] + v[2];
  s = blockSum256(s, sh);
  float mu = s * (1.f/768.f);
  float q = 0;
  #pragma unroll
  for (int i = 0; i < 3; i++) { float d = v[i] - mu; q += d*d; }
  q = blockSum256(q, sh);
  float rs = rsqrtf(q * (1.f/768.f) + EPSF);
  if (t == 0) { murs[2*row] = mu; murs[2*row + 1] = rs; }
}

// ---- transpose + f32->bf16: in (K x N) -> out (Npad x K); grid(Npad/32, K/32) ----
__global__ __launch_bounds__(256)
void transp_bf16(const float* __restrict__ in, u16* __restrict__ out, int K, int N)
{
  __shared__ float tl[32][33];
  int tx = threadIdx.x & 31, ty = threadIdx.x >> 5;
  int n0 = blockIdx.x * 32, k0 = blockIdx.y * 32;
  #pragma unroll
  for (int r = 0; r < 4; r++) {
    int k = k0 + ty + r*8, n = n0 + tx;
    tl[ty + r*8][tx] = (n < N) ? in[(size_t)k*N + n] : 0.f;
  }
  __syncthreads();
  #pragma unroll
  for (int r = 0; r < 4; r++) {
    int n = n0 + ty + r*8, k = k0 + tx;
    out[(size_t)n*K + k] = f2bf(tl[tx][ty + r*8]);
  }
}

// ---- GEMM0: zx[.]= LN(x) @ Wi  with LN fused into A-staging; dt epilogue ----
__global__ __launch_bounds__(256)
void gemm_ln(const float* __restrict__ X, const float* __restrict__ murs,
             const float* __restrict__ lnw, const float* __restrict__ lnb,
             const u16* __restrict__ BT, u16* __restrict__ zxO,
             const float* __restrict__ dtbias, float* __restrict__ dtO)
{
  __shared__ __align__(16) u16 As[128*40];
  __shared__ __align__(16) u16 Bs[128*40];
  __shared__ float wl[DM], bl[DM], muS[128], rsS[128];
  const int t = threadIdx.x;
  const int bm = blockIdx.y, bn = blockIdx.x;
  const int lane = t & 63, wave = t >> 6;
  const int wr = wave >> 1, wc = wave & 1;
  const int r16 = lane & 15, kb = lane >> 4;

  for (int i = t; i < DM; i += 256) { wl[i] = lnw[i]; bl[i] = lnb[i]; }
  if (t < 128) {
    int r = bm*128 + t;
    float m = 0.f, rr = 0.f;
    if (r < NROWS) { m = murs[2*r]; rr = murs[2*r + 1]; }
    muS[t] = m; rsS[t] = rr;
  }
  __syncthreads();

  const int m = t >> 1, half = t & 1;
  const int grow = bm*128 + m;
  const bool valid = grow < NROWS;
  const float* gX = X + (size_t)grow*DM + half*16;
  const u16* gB = BT + (size_t)(bn*128 + m)*DM + half*16;
  u16* wA = &As[m*40 + half*16];
  u16* wB = &Bs[m*40 + half*16];
  const float mu = muS[m], rs = rsS[m];

  f32x4 acc[4][4] = {};
  for (int kt = 0; kt < DM; kt += 32) {
    short8 b0 = *(const short8*)(gB + kt);
    short8 b1 = *(const short8*)(gB + kt + 8);
    short8 a0 = {}, a1 = {};
    if (valid) {
      const float* xp = gX + kt;
      const int c0 = kt + half*16;
      #pragma unroll
      for (int j = 0; j < 8; j++) a0[j] = (short)f2bf((xp[j]     - mu)*rs*wl[c0 + j]     + bl[c0 + j]);
      #pragma unroll
      for (int j = 0; j < 8; j++) a1[j] = (short)f2bf((xp[8 + j] - mu)*rs*wl[c0 + 8 + j] + bl[c0 + 8 + j]);
    }
    *(short8*)(wA)     = a0; *(short8*)(wA + 8) = a1;
    *(short8*)(wB)     = b0; *(short8*)(wB + 8) = b1;
    __syncthreads();
    bf16x8 af[4], bfr[4];
    #pragma unroll
    for (int i = 0; i < 4; i++) af[i]  = *(const bf16x8*)&As[(wr*64 + i*16 + r16)*40 + kb*8];
    #pragma unroll
    for (int i = 0; i < 4; i++) bfr[i] = *(const bf16x8*)&Bs[(wc*64 + i*16 + r16)*40 + kb*8];
    #pragma unroll
    for (int i = 0; i < 4; i++)
      #pragma unroll
      for (int j = 0; j < 4; j++)
        acc[i][j] = __builtin_amdgcn_mfma_f32_16x16x32_bf16(af[i], bfr[j], acc[i][j], 0, 0, 0);
    __syncthreads();
  }
  const int rbase = bm*128 + wr*64, cbase = bn*128 + wc*64;
  #pragma unroll
  for (int i = 0; i < 4; i++) {
    #pragma unroll
    for (int j = 0; j < 4; j++) {
      int col = cbase + j*16 + r16;
      #pragma unroll
      for (int e = 0; e < 4; e++) {
        int row = rbase + i*16 + kb*4 + e;
        if (row < NROWS) {
          float v = acc[i][j][e];
          if (col < ZLD) {
            zxO[(size_t)row*ZLD + col] = f2bf(v);
          } else if (col < DIP) {
            int hh = col - ZLD;
            float d = v + dtbias[hh];
            d = (d > 20.f) ? d : log1pf(expf(d));
            dtO[(size_t)row*NH + hh] = d;
          }
        }
      }
    }
  }
}

// ---- GEMM1: x += gated(zx cols 0..1535) @ Wo ; A from zx with lda=ZLD ----
__global__ __launch_bounds__(256)
void gemm_out(const u16* __restrict__ A, const u16* __restrict__ BT, float* __restrict__ X)
{
  __shared__ __align__(16) u16 As[128*40];
  __shared__ __align__(16) u16 Bs[128*40];
  const int t = threadIdx.x;
  const int bm = blockIdx.y, bn = blockIdx.x;
  const int lane = t & 63, wave = t >> 6;
  const int wr = wave >> 1, wc = wave & 1;
  const int r16 = lane & 15, kb = lane >> 4;

  const int m = t >> 1, half = t & 1;
  const int grow = bm*128 + m;
  const bool valid = grow < NROWS;
  const u16* gA = A + (size_t)grow*ZLD + half*16;
  const u16* gB = BT + (size_t)(bn*128 + m)*DI + half*16;
  u16* wA = &As[m*40 + half*16];
  u16* wB = &Bs[m*40 + half*16];

  f32x4 acc[4][4] = {};
  for (int kt = 0; kt < DI; kt += 32) {
    short8 b0 = *(const short8*)(gB + kt);
    short8 b1 = *(const short8*)(gB + kt + 8);
    short8 a0 = {}, a1 = {};
    if (valid) { a0 = *(const short8*)(gA + kt); a1 = *(const short8*)(gA + kt + 8); }
    *(short8*)(wA)     = a0; *(short8*)(wA + 8) = a1;
    *(short8*)(wB)     = b0; *(short8*)(wB + 8) = b1;
    __syncthreads();
    bf16x8 af[4], bfr[4];
    #pragma unroll
    for (int i = 0; i < 4; i++) af[i]  = *(const bf16x8*)&As[(wr*64 + i*16 + r16)*40 + kb*8];
    #pragma unroll
    for (int i = 0; i < 4; i++) bfr[i] = *(const bf16x8*)&Bs[(wc*64 + i*16 + r16)*40 + kb*8];
    #pragma unroll
    for (int i = 0; i < 4; i++)
      #pragma unroll
      for (int j = 0; j < 4; j++)
        acc[i][j] = __builtin_amdgcn_mfma_f32_16x16x32_bf16(af[i], bfr[j], acc[i][j], 0, 0, 0);
    __syncthreads();
  }
  const int rbase = bm*128 + wr*64, cbase = bn*128 + wc*64;
  #pragma unroll
  for (int i = 0; i < 4; i++) {
    #pragma unroll
    for (int j = 0; j < 4; j++) {
      int col = cbase + j*16 + r16;
      #pragma unroll
      for (int e = 0; e < 4; e++) {
        int row = rbase + i*16 + kb*4 + e;
        if (row < NROWS) X[(size_t)row*DM + col] += acc[i][j][e];
      }
    }
  }
}

// ======================= chunked SSD =======================
// zx row layout (bf16, ld ZLD): [0,1536) z | [1536,3072) x raw | [3072,3200) B raw | [3200,3328) C raw
// slab id = (b*NCH + c)*NH + h ; cstat[id][p(64)][n(128)] bf16 ; dtot[id] f32
// Raw tiles staged with +3 row shift: LDS row r  <->  global row base-3+r (r in [0,131))

// ---- K1: per-chunk state (256 threads; ~55 KB LDS -> 2 blocks/CU) ----
__global__ __launch_bounds__(256)
void chunk_state_kernel(const u16* __restrict__ zx, const float* __restrict__ dtb,
                        const float* __restrict__ alog, const float* __restrict__ cw,
                        const float* __restrict__ cb, u16* __restrict__ cstat,
                        float* __restrict__ dtot)
{
  const int id = blockIdx.x;
  const int h = id % NH; const int c = (id / NH) % NCH; const int b = id / (NH*NCH);
  const int t = threadIdx.x;
  const int base = c*CHK;
  int rows = LTOT - base; if (rows > CHK) rows = CHK;

  __shared__ __align__(16) u16 Bbuf[132*LDF];
  __shared__ __align__(16) u16 xbuf[131*XLD + 8];
  __shared__ float dtv[128];
  __shared__ float cs[128];
  __shared__ float wjs[128];

  const u16* zb = zx + (size_t)(b*LTOT)*ZLD;
  const float aexp = __expf(alog[h]);
  if (t < 128) {
    float dv = 0.f;
    if (t < rows) dv = dtb[(size_t)(b*LTOT + base + t)*NH + h];
    dtv[t] = dv; cs[t] = -dv * aexp;
  }
  #pragma unroll
  for (int rg = 0; rg < 9; rg++) {
    int r = rg*16 + (t >> 4);
    int seg = t & 15;
    if (r < 131) {
      int g = base - 3 + r;
      short8 v = {};
      if (g >= 0 && g < LTOT) v = *(const short8*)(zb + (size_t)g*ZLD + 3072 + seg*8);
      *(short8*)&Bbuf[r*LDF + seg*8] = v;
    }
  }
  #pragma unroll
  for (int rg = 0; rg < 5; rg++) {
    int r = rg*32 + (t >> 3);
    int seg = t & 7;
    if (r < 131) {
      int g = base - 3 + r;
      short8 v = {};
      if (g >= 0 && g < LTOT) v = *(const short8*)(zb + (size_t)g*ZLD + 1536 + h*HD + seg*8);
      *(short8*)&xbuf[r*XLD + seg*8] = v;
    }
  }
  __syncthreads();
  for (int off = 1; off < 128; off <<= 1) {
    float add = 0.f;
    if (t < 128 && t >= off) add = cs[t - off];
    __syncthreads();
    if (t < 128) cs[t] += add;
    __syncthreads();
  }
  if (t < 128) wjs[t] = __expf(cs[127] - cs[t]) * dtv[t];
  __syncthreads();

  const int n_ = t & 127, jh = t >> 7;
  u32 pkB[32];
  {
    const int ch = 1536 + n_;
    float w0 = cw[ch*4+0], w1 = cw[ch*4+1], w2 = cw[ch*4+2], w3 = cw[ch*4+3];
    float bias = cb[ch];
    const int rb = jh*64;
    float r0 = bf2f(Bbuf[(rb+0)*LDF + n_]);
    float r1 = bf2f(Bbuf[(rb+1)*LDF + n_]);
    float r2 = bf2f(Bbuf[(rb+2)*LDF + n_]);
    #pragma unroll
    for (int k2 = 0; k2 < 32; k2++) {
      float r3 = bf2f(Bbuf[(rb + 2*k2 + 3)*LDF + n_]);
      float o0 = bias + w0*r0 + w1*r1 + w2*r2 + w3*r3;
      float r4 = bf2f(Bbuf[(rb + 2*k2 + 4)*LDF + n_]);
      float o1 = bias + w0*r1 + w1*r2 + w2*r3 + w3*r4;
      pkB[k2] = (u32)f2bf(siluf(o0)) | ((u32)f2bf(siluf(o1)) << 16);
      r0 = r2; r1 = r3; r2 = r4;
    }
  }
  const int p_ = t & 63, jq = t >> 6;
  u32 pkx[16];
  {
    const int ch = h*HD + p_;
    float w0 = cw[ch*4+0], w1 = cw[ch*4+1], w2 = cw[ch*4+2], w3 = cw[ch*4+3];
    float bias = cb[ch];
    const int rb = jq*32;
    float r0 = bf2f(xbuf[(rb+0)*XLD + p_]);
    float r1 = bf2f(xbuf[(rb+1)*XLD + p_]);
    float r2 = bf2f(xbuf[(rb+2)*XLD + p_]);
    #pragma unroll
    for (int k2 = 0; k2 < 16; k2++) {
      float r3 = bf2f(xbuf[(rb + 2*k2 + 3)*XLD + p_]);
      float o0 = bias + w0*r0 + w1*r1 + w2*r2 + w3*r3;
      float r4 = bf2f(xbuf[(rb + 2*k2 + 4)*XLD + p_]);
      float o1 = bias + w0*r1 + w1*r2 + w2*r3 + w3*r4;
      float s0 = siluf(o0) * wjs[rb + 2*k2];
      float s1 = siluf(o1) * wjs[rb + 2*k2 + 1];
      pkx[k2] = (u32)f2bf(s0) | ((u32)f2bf(s1) << 16);
      r0 = r2; r1 = r3; r2 = r4;
    }
  }
  __syncthreads();
  #pragma unroll
  for (int q = 0; q < 8; q++) {
    u32x4 v; v[0] = pkB[q*4]; v[1] = pkB[q*4+1]; v[2] = pkB[q*4+2]; v[3] = pkB[q*4+3];
    *(u32x4*)&Bbuf[n_*LDF + jh*64 + q*8] = v;
  }
  #pragma unroll
  for (int q = 0; q < 4; q++) {
    u32x4 v; v[0] = pkx[q*4]; v[1] = pkx[q*4+1]; v[2] = pkx[q*4+2]; v[3] = pkx[q*4+3];
    *(u32x4*)&xbuf[p_*LDF + jq*32 + q*8] = v;
  }
  __syncthreads();

  const int lane = t & 63, wave = t >> 6;
  const int r16 = lane & 15, kb = lane >> 4;
  const int n0 = wave*32;
  f32x4 acc[4][2] = {};
  #pragma unroll
  for (int kt = 0; kt < 4; kt++) {
    bf16x8 af[4], bfr[2];
    #pragma unroll
    for (int m = 0; m < 4; m++) af[m] = *(const bf16x8*)&xbuf[(m*16 + r16)*LDF + kt*32 + kb*8];
    #pragma unroll
    for (int nn = 0; nn < 2; nn++) bfr[nn] = *(const bf16x8*)&Bbuf[(n0 + nn*16 + r16)*LDF + kt*32 + kb*8];
    #pragma unroll
    for (int m = 0; m < 4; m++)
      #pragma unroll
      for (int nn = 0; nn < 2; nn++)
        acc[m][nn] = __builtin_amdgcn_mfma_f32_16x16x32_bf16(af[m], bfr[nn], acc[m][nn], 0, 0, 0);
  }
  u16* dst = cstat + (size_t)id*64*128;
  #pragma unroll
  for (int m = 0; m < 4; m++)
    #pragma unroll
    for (int nn = 0; nn < 2; nn++)
      #pragma unroll
      for (int e = 0; e < 4; e++) {
        int p = m*16 + kb*4 + e;
        int n = n0 + nn*16 + r16;
        dst[p*128 + n] = f2bf(acc[m][nn][e]);
      }
  if (t == 0) dtot[id] = __expf(cs[127]);
}

// ---- K2: inter-chunk scan (in-place: slot <- state BEFORE that chunk) ----
__global__ __launch_bounds__(256)
void state_scan_kernel(u16* __restrict__ cstat, const float* __restrict__ dtot)
{
  const int b = blockIdx.x / NH, h = blockIdx.x % NH;
  const int t = threadIdx.x;
  float run[32];
  #pragma unroll
  for (int k = 0; k < 32; k++) run[k] = 0.f;
  size_t id0 = (size_t)(b*NCH)*NH + h;
  short8 cur[4];
  {
    const u16* s0 = cstat + id0*8192 + t*32;
    #pragma unroll
    for (int q = 0; q < 4; q++) cur[q] = *(const short8*)(s0 + q*8);
  }
  float d = dtot[id0];
  for (int c = 0; c < NCH; ++c) {
    size_t id = (size_t)(b*NCH + c)*NH + h;
    u16* slab = cstat + id*8192 + t*32;
    short8 nxt[4] = {}; float nd = 0.f;
    if (c + 1 < NCH) {
      const u16* sn = slab + (size_t)NH*8192;
      #pragma unroll
      for (int q = 0; q < 4; q++) nxt[q] = *(const short8*)(sn + q*8);
      nd = dtot[id + NH];
    }
    short8 out[4];
    #pragma unroll
    for (int q = 0; q < 4; q++)
      #pragma unroll
      for (int k = 0; k < 8; k++) {
        int idx = q*8 + k;
        float csv = bf2f((u16)cur[q][k]);
        out[q][k] = (short)f2bf(run[idx]);
        run[idx] = run[idx]*d + csv;
      }
    #pragma unroll
    for (int q = 0; q < 4; q++) *(short8*)(slab + q*8) = out[q];
    #pragma unroll
    for (int q = 0; q < 4; q++) cur[q] = nxt[q];
    d = nd;
  }
}

// ---- K3: per-chunk output (512 threads / 8 waves); writes y*silu(z) over z-cols of zx ----
__global__ __launch_bounds__(512, 2)
void chunk_output_kernel(u16* __restrict__ zx, const float* __restrict__ dtb,
                         const float* __restrict__ alog, const float* __restrict__ cw,
                         const float* __restrict__ cb, const float* __restrict__ Dvec,
                         const u16* __restrict__ cstat)
{
  const int id = blockIdx.x;
  const int h = id % NH; const int c = (id / NH) % NCH; const int b = id / (NH*NCH);
  const int t = threadIdx.x;                 // 0..511
  const int base = c*CHK;
  int rows = LTOT - base; if (rows > CHK) rows = CHK;

  __shared__ __align__(16) u16 Bc[132*LDF];       // raw B(+3 shift) -> conv'd B -> P[i][j]
  __shared__ __align__(16) u16 Cc[132*LDF];       // raw C -> conv'd C
  __shared__ __align__(16) u16 stT[64*LDF];       // state_before [p][n]
  __shared__ __align__(16) u16 xbuf[131*XLD + 8]; // raw x -> xc[p][j]
  __shared__ float dtv[128];
  __shared__ float cs[128];

  const u16* zb = zx + (size_t)(b*LTOT)*ZLD;
  const float aexp = __expf(alog[h]);
  if (t < 128) {
    float dv = 0.f;
    if (t < rows) dv = dtb[(size_t)(b*LTOT + base + t)*NH + h];
    dtv[t] = dv; cs[t] = -dv * aexp;
  }
  // stage state_before: 512 threads, 2 x short8 each
  {
    const u16* slab = cstat + (size_t)id*8192;
    int p = t >> 3, nb = (t & 7)*16;
    *(short8*)&stT[p*LDF + nb]     = *(const short8*)(slab + p*128 + nb);
    *(short8*)&stT[p*LDF + nb + 8] = *(const short8*)(slab + p*128 + nb + 8);
  }
  // stage raw B/C: 16 rows/round
  #pragma unroll
  for (int rg = 0; rg < 9; rg++) {
    int r = rg*16 + (t >> 5);
    int seg = t & 31;
    if (r < 131) {
      int g = base - 3 + r;
      short8 v = {};
      if (g >= 0 && g < LTOT) v = *(const short8*)(zb + (size_t)g*ZLD + 3072 + seg*8);
      if (seg < 16) *(short8*)&Bc[r*LDF + seg*8] = v;
      else          *(short8*)&Cc[r*LDF + (seg - 16)*8] = v;
    }
  }
  // stage raw x: 64 rows/round
  #pragma unroll
  for (int rg = 0; rg < 3; rg++) {
    int r = rg*64 + (t >> 3);
    int seg = t & 7;
    if (r < 131) {
      int g = base - 3 + r;
      short8 v = {};
      if (g >= 0 && g < LTOT) v = *(const short8*)(zb + (size_t)g*ZLD + 1536 + h*HD + seg*8);
      *(short8*)&xbuf[r*XLD + seg*8] = v;
    }
  }
  __syncthreads();
  // prefix sum of dtA
  for (int off = 1; off < 128; off <<= 1) {
    float add = 0.f;
    if (t < 128 && t >= off) add = cs[t - off];
    __syncthreads();
    if (t < 128) cs[t] += add;
    __syncthreads();
  }

  // x conv -> regs (8 j-groups of 16)
  const int p_ = t & 63, jq = t >> 6;
  u32 pkx[8];
  {
    const int ch = h*HD + p_;
    float w0 = cw[ch*4+0], w1 = cw[ch*4+1], w2 = cw[ch*4+2], w3 = cw[ch*4+3];
    float bias = cb[ch];
    const int rb = jq*16;
    float r0 = bf2f(xbuf[(rb+0)*XLD + p_]);
    float r1 = bf2f(xbuf[(rb+1)*XLD + p_]);
    float r2 = bf2f(xbuf[(rb+2)*XLD + p_]);
    #pragma unroll
    for (int k2 = 0; k2 < 8; k2++) {
      float r3 = bf2f(xbuf[(rb + 2*k2 + 3)*XLD + p_]);
      float o0 = bias + w0*r0 + w1*r1 + w2*r2 + w3*r3;
      float r4 = bf2f(xbuf[(rb + 2*k2 + 4)*XLD + p_]);
      float o1 = bias + w0*r1 + w1*r2 + w2*r3 + w3*r4;
      int j0 = rb + 2*k2;
      u32 lo = (j0     < rows) ? (u32)f2bf(siluf(o0)) : 0u;
      u32 hi = (j0 + 1 < rows) ? (u32)f2bf(siluf(o1)) : 0u;
      pkx[k2] = lo | (hi << 16);
      r0 = r2; r1 = r3; r2 = r4;
    }
  }
  // B/C quarter halo + initial rolling preloads (cross-quarter hazard rows rbq+32..34)
  const int n_ = t & 127, qd = t >> 7;       // qd 0..3, rows [32qd, 32qd+32)
  const int rbq = qd*32;
  float hB0 = bf2f(Bc[(rbq+32)*LDF + n_]);
  float hB1 = bf2f(Bc[(rbq+33)*LDF + n_]);
  float hB2 = bf2f(Bc[(rbq+34)*LDF + n_]);
  float hC0 = bf2f(Cc[(rbq+32)*LDF + n_]);
  float hC1 = bf2f(Cc[(rbq+33)*LDF + n_]);
  float hC2 = bf2f(Cc[(rbq+34)*LDF + n_]);
  float rB0 = bf2f(Bc[(rbq+0)*LDF + n_]);
  float rB1 = bf2f(Bc[(rbq+1)*LDF + n_]);
  float rB2 = bf2f(Bc[(rbq+2)*LDF + n_]);
  float rC0 = bf2f(Cc[(rbq+0)*LDF + n_]);
  float rC1 = bf2f(Cc[(rbq+1)*LDF + n_]);
  float rC2 = bf2f(Cc[(rbq+2)*LDF + n_]);
  __syncthreads();   // all raw reads (x conv + preloads) complete
  // in-place conv B (32 iters; reads row j+3 before writing row j; column-private per thread)
  {
    const int ch = 1536 + n_;
    float w0 = cw[ch*4+0], w1 = cw[ch*4+1], w2 = cw[ch*4+2], w3 = cw[ch*4+3];
    float bias = cb[ch];
    float r0 = rB0, r1 = rB1, r2 = rB2;
    #pragma unroll
    for (int j = 0; j < 32; j++) {
      float r3 = (j < 29) ? bf2f(Bc[(rbq + j + 3)*LDF + n_])
                          : (j == 29 ? hB0 : (j == 30 ? hB1 : hB2));
      float o = bias + w0*r0 + w1*r1 + w2*r2 + w3*r3;
      Bc[(rbq + j)*LDF + n_] = f2bf(siluf(o));
      r0 = r1; r1 = r2; r2 = r3;
    }
  }
  // in-place conv C
  {
    const int ch = 1664 + n_;
    float w0 = cw[ch*4+0], w1 = cw[ch*4+1], w2 = cw[ch*4+2], w3 = cw[ch*4+3];
    float bias = cb[ch];
    float r0 = rC0, r1 = rC1, r2 = rC2;
    #pragma unroll
    for (int j = 0; j < 32; j++) {
      float r3 = (j < 29) ? bf2f(Cc[(rbq + j + 3)*LDF + n_])
                          : (j == 29 ? hC0 : (j == 30 ? hC1 : hC2));
      float o = bias + w0*r0 + w1*r1 + w2*r2 + w3*r3;
      Cc[(rbq + j)*LDF + n_] = f2bf(siluf(o));
      r0 = r1; r1 = r2; r2 = r3;
    }
  }
  // write xc[p][j] over xbuf (raw x fully consumed before the barrier above)
  {
    u32x4 v0; v0[0] = pkx[0]; v0[1] = pkx[1]; v0[2] = pkx[2]; v0[3] = pkx[3];
    u32x4 v1; v1[0] = pkx[4]; v1[1] = pkx[5]; v1[2] = pkx[6]; v1[3] = pkx[7];
    *(u32x4*)&xbuf[p_*LDF + jq*16]     = v0;
    *(u32x4*)&xbuf[p_*LDF + jq*16 + 8] = v1;
  }
  __syncthreads();

  const int lane = t & 63, wave = t >> 6;
  const int r16 = lane & 15, kb = lane >> 4;

  // Phase A: S[i][j] = sum_n Cc[i][n]*Bc[j][n]; 8 waves -> 64x32 tiles; then P into Bc
  {
    const int wi = wave >> 2, wjn = wave & 3;
    f32x4 acc[4][2] = {};
    #pragma unroll
    for (int kt = 0; kt < 4; kt++) {
      bf16x8 af[4], bfr[2];
      #pragma unroll
      for (int m = 0; m < 4; m++) af[m] = *(const bf16x8*)&Cc[(wi*64 + m*16 + r16)*LDF + kt*32 + kb*8];
      #pragma unroll
      for (int nj = 0; nj < 2; nj++) bfr[nj] = *(const bf16x8*)&Bc[(wjn*32 + nj*16 + r16)*LDF + kt*32 + kb*8];
      #pragma unroll
      for (int m = 0; m < 4; m++)
        #pragma unroll
        for (int nj = 0; nj < 2; nj++)
          acc[m][nj] = __builtin_amdgcn_mfma_f32_16x16x32_bf16(af[m], bfr[nj], acc[m][nj], 0, 0, 0);
    }
    __syncthreads();   // all conv'd-B reads done -> safe to overwrite with P
    #pragma unroll
    for (int m = 0; m < 4; m++)
      #pragma unroll
      for (int nj = 0; nj < 2; nj++)
        #pragma unroll
        for (int e = 0; e < 4; e++) {
          int i = wi*64 + m*16 + kb*4 + e;
          int j = wjn*32 + nj*16 + r16;
          float f = 0.f;
          if (j <= i && i < rows) f = __expf(cs[i] - cs[j]) * dtv[j];
          Bc[i*LDF + j] = f2bf(acc[m][nj][e] * f);
        }
  }
  __syncthreads();

  // Phase B: Y1 = P @ xc^T ; Phase C: Y2 = Cc @ stT^T ; 8 waves -> 16 rows each
  {
    const int iq = wave;
    f32x4 accY[4] = {};
    #pragma unroll
    for (int kt = 0; kt < 4; kt++) {
      bf16x8 af = *(const bf16x8*)&Bc[(iq*16 + r16)*LDF + kt*32 + kb*8];
      #pragma unroll
      for (int n = 0; n < 4; n++) {
        bf16x8 bfr = *(const bf16x8*)&xbuf[(n*16 + r16)*LDF + kt*32 + kb*8];
        accY[n] = __builtin_amdgcn_mfma_f32_16x16x32_bf16(af, bfr, accY[n], 0, 0, 0);
      }
    }
    f32x4 accS[4] = {};
    #pragma unroll
    for (int kt = 0; kt < 4; kt++) {
      bf16x8 af = *(const bf16x8*)&Cc[(iq*16 + r16)*LDF + kt*32 + kb*8];
      #pragma unroll
      for (int n = 0; n < 4; n++) {
        bf16x8 bfr = *(const bf16x8*)&stT[(n*16 + r16)*LDF + kt*32 + kb*8];
        accS[n] = __builtin_amdgcn_mfma_f32_16x16x32_bf16(af, bfr, accS[n], 0, 0, 0);
      }
    }
    const float dcoef = Dvec[h];
    #pragma unroll
    for (int e = 0; e < 4; e++) {
      int i = iq*16 + kb*4 + e;
      if (i < rows) {
        float sc = __expf(cs[i]);
        size_t orow = (size_t)(b*LTOT + base + i)*ZLD + h*HD;
        #pragma unroll
        for (int n = 0; n < 4; n++) {
          int p = n*16 + r16;
          float xv = bf2f(xbuf[p*LDF + i]);
          float yv = accY[n][e] + sc*accS[n][e] + dcoef*xv;
          float zval = bf2f(zx[orow + p]);
          zx[orow + p] = f2bf(yv * siluf(zval));
        }
      }
    }
  }
}

// ---- rmsnorm in place on zx cols [0,1536) ----
__global__ __launch_bounds__(256)
void gate_rms_kernel(u16* __restrict__ zx, const float* __restrict__ gw)
{
  int row = blockIdx.x;
  int t = threadIdx.x;
  __shared__ float sh[4];
  float g[6]; float ss = 0.f;
  u16* zr = zx + (size_t)row*ZLD;
  #pragma unroll
  for (int i = 0; i < 6; i++) {
    int c = t + i*256;
    g[i] = bf2f(zr[c]);
    ss += g[i]*g[i];
  }
  ss = blockSum256(ss, sh);
  float rs = rsqrtf(ss * (1.f/1536.f) + EPSF);
  #pragma unroll
  for (int i = 0; i < 6; i++) {
    int c = t + i*256;
    zr[c] = f2bf(g[i]*rs*gw[c]);
  }
}

// ---- head ----
__global__ __launch_bounds__(256)
void head_kernel(const float* __restrict__ x, const float* __restrict__ tw,
                 const float* __restrict__ tb, const float* __restrict__ im64,
                 float* __restrict__ out, float* __restrict__ partial)
{
  int bj = blockIdx.x;
  int b = bj >> 12, j = bj & 4095;
  int row = b*LTOT + 65 + j;
  const float* xr = x + (size_t)row*DM;
  int t = threadIdx.x;
  float p0 = 0, p1 = 0, p2 = 0;
  for (int k = t; k < 768; k += 256) {
    float xv = xr[k];
    p0 += xv*tw[k*3 + 0]; p1 += xv*tw[k*3 + 1]; p2 += xv*tw[k*3 + 2];
  }
  __shared__ float sh[4];
  p0 = blockSum256(p0, sh);
  p1 = blockSum256(p1, sh);
  p2 = blockSum256(p2, sh);
  if (t == 0) {
    float y0 = p0 + tb[0], y1 = p1 + tb[1], y2 = p2 + tb[2];
    size_t o = (size_t)bj*3;
    out[o] = y0; out[o + 1] = y1; out[o + 2] = y2;
    float d0 = y0 - im64[o], d1 = y1 - im64[o + 1], d2 = y2 - im64[o + 2];
    partial[bj] = d0*d0 + d1*d1 + d2*d2;
  }
}

__global__ __launch_bounds__(256)
void loss_reduce(const float* __restrict__ partial, float* __restrict__ out)
{
  int t = threadIdx.x;
  float s = 0.f;
  for (int i = t; i < BATCH*4096; i += 256) s += partial[i];
  __shared__ float sh[4];
  s = blockSum256(s, sh);
  if (t == 0) out[49152] = s * (1.f/49152.f);
}

// ---- launcher ----
static inline size_t alignup(size_t v){ return (v + 255) & ~(size_t)255; }

extern "C" void kernel_launch(void* const* d_in, const int* in_sizes, int n_in,
                              void* d_out, int out_size, void* d_ws, size_t ws_size,
                              hipStream_t stream)
{
  const float* im8        = (const float*)d_in[0];
  const float* im64       = (const float*)d_in[1];
  const float* from_rgb_w = (const float*)d_in[2];
  const float* from_rgb_b = (const float*)d_in[3];
  const float* to_rgb_w   = (const float*)d_in[4];
  const float* to_rgb_b   = (const float*)d_in[5];
  const float* s0         = (const float*)d_in[6];
  const float* suffix     = (const float*)d_in[7];
  const float* norm0_w    = (const float*)d_in[8];
  const float* norm0_b    = (const float*)d_in[9];
  const float* ln_w       = (const float*)d_in[10];
  const float* ln_b       = (const float*)d_in[11];
  const float* in_proj_w  = (const float*)d_in[12];
  const float* conv_w     = (const float*)d_in[13];
  const float* conv_b     = (const float*)d_in[14];
  const float* dt_bias    = (const float*)d_in[15];
  const float* A_log      = (const float*)d_in[16];
  const float* Dvec       = (const float*)d_in[17];
  const float* gn_w       = (const float*)d_in[18];
  const float* out_proj_w = (const float*)d_in[19];

  char* w = (char*)d_ws;
  size_t off = 0;
  float* x     = (float*)(w + off); off = alignup(off + (size_t)NROWS*DM*4);        // 51.1 MB
  u16*   zx    = (u16*)  (w + off); off = alignup(off + (size_t)NROWS*ZLD*2);       // 110.8 MB
  u16*   scr   = (u16*)  (w + off); off = alignup(off + (size_t)BATCH*NCH*NH*64*128*2); // 51.9 MB (wT / cstat alias)
  float* dt    = (float*)(w + off); off = alignup(off + (size_t)NROWS*NH*4);        // 1.6 MB
  float* murs  = (float*)(w + off); off = alignup(off + (size_t)NROWS*2*4);         // 133 KB
  float* dtot  = (float*)(w + off); off = alignup(off + (size_t)BATCH*NCH*NH*4);    // 12.7 KB
  float* lpart = (float*)(w + off); off = alignup(off + (size_t)BATCH*4096*4);      // 64 KB
  // total ~215.8 MB
  u16* wT    = scr;
  u16* cstat = scr;

  build_x_kernel<<<NROWS, 256, 0, stream>>>(im8, from_rgb_w, from_rgb_b, s0, suffix,
                                            norm0_w, norm0_b, x);

  const int NBLK = BATCH*NCH*NH;   // 3168
  for (int i = 0; i < 4; i++) {
    row_stats_kernel<<<NROWS, 256, 0, stream>>>(x, murs);
    transp_bf16<<<dim3(NPAD1/32, DM/32), 256, 0, stream>>>(in_proj_w + (size_t)i*DM*DIP, wT, DM, DIP);
    gemm_ln<<<dim3(NPAD1/128, MPAD/128), 256, 0, stream>>>(
        x, murs, ln_w + i*DM, ln_b + i*DM, wT, zx, dt_bias + i*NH, dt);
    chunk_state_kernel<<<NBLK, 256, 0, stream>>>(zx, dt, A_log + i*NH,
        conv_w + (size_t)i*(DI+2*DS)*4, conv_b + i*(DI+2*DS), cstat, dtot);
    state_scan_kernel<<<BATCH*NH, 256, 0, stream>>>(cstat, dtot);
    chunk_output_kernel<<<NBLK, 512, 0, stream>>>(zx, dt, A_log + i*NH,
        conv_w + (size_t)i*(DI+2*DS)*4, conv_b + i*(DI+2*DS), Dvec + i*NH, cstat);
    gate_rms_kernel<<<NROWS, 256, 0, stream>>>(zx, gn_w + i*DI);
    transp_bf16<<<dim3(DM/32, DI/32), 256, 0, stream>>>(out_proj_w + (size_t)i*DI*DM, wT, DI, DM);
    gemm_out<<<dim3(DM/128, MPAD/128), 256, 0, stream>>>(zx, wT, x);
  }

  head_kernel<<<BATCH*4096, 256, 0, stream>>>(x, to_rgb_w, to_rgb_b, im64, (float*)d_out, lpart);
  loss_reduce<<<1, 256, 0, stream>>>(lpart, (float*)d_out);
}

// Round 7
// 2722.446 us; speedup vs baseline: 5.6570x; 1.1776x over previous
//
#include <hip/hip_runtime.h>
#include <hip/hip_bf16.h>
#include <math.h>

// ---- problem constants ----
#define LTOT 4161
#define BATCH 4
#define NROWS (BATCH*LTOT)      // 16644
#define MPAD 16768              // rows padded for 128-tile GEMM grid
#define NPAD1 3456              // 3352 -> padded to 128 multiple
#define DM 768
#define DI 1536
#define DIP 3352
#define ZLD 3328                // stored columns of zx
#define NH 24
#define HD 64
#define DS 128
#define EPSF 1e-5f
#define CHK 128                 // SSD chunk length
#define NCH 33                  // ceil(4161/128)
#define LDF 136                 // LDS row stride (u16) for 128-wide tiles
#define XLD 72                  // LDS row stride (u16) for raw-x staging
#define RLD 264                 // LDS row stride (u16) for raw B/C staging in convBC

typedef __attribute__((ext_vector_type(8))) __bf16 bf16x8;
typedef __attribute__((ext_vector_type(4))) float f32x4;
typedef __attribute__((ext_vector_type(8))) short short8;
typedef __attribute__((ext_vector_type(4))) unsigned int u32x4;
typedef unsigned short u16;
typedef unsigned int u32;

static __device__ __forceinline__ u16 f2bf(float f){
  unsigned u = __builtin_bit_cast(unsigned, f);
  u += 0x7FFFu + ((u >> 16) & 1u);          // RNE
  return (u16)(u >> 16);
}
static __device__ __forceinline__ float bf2f(u16 v){
  return __builtin_bit_cast(float, ((unsigned)v) << 16);
}
static __device__ __forceinline__ float siluf(float v){ return v / (1.f + __expf(-v)); }

__device__ __forceinline__ float blockSum256(float v, float* sh){
  #pragma unroll
  for (int o = 32; o > 0; o >>= 1) v += __shfl_down(v, o);
  int w = threadIdx.x >> 6;
  if ((threadIdx.x & 63) == 0) sh[w] = v;
  __syncthreads();
  v = sh[0] + sh[1] + sh[2] + sh[3];
  __syncthreads();
  return v;
}

// ---- build x = LN0(concat(s0, h8, zm)) ----
__global__ __launch_bounds__(256)
void build_x_kernel(const float* __restrict__ im8, const float* __restrict__ frw,
                    const float* __restrict__ frb, const float* __restrict__ s0,
                    const float* __restrict__ suffix, const float* __restrict__ w,
                    const float* __restrict__ bb, float* __restrict__ x)
{
  int row = blockIdx.x;
  int b = row / LTOT, l = row % LTOT;
  int t = threadIdx.x;
  __shared__ float sh[4];
  float v[3];
  if (l == 0) {
    #pragma unroll
    for (int i = 0; i < 3; i++) v[i] = s0[t + i*256];
  } else if (l <= 64) {
    int p = l - 1;
    float r0 = im8[(b*64 + p)*3 + 0], r1 = im8[(b*64 + p)*3 + 1], r2 = im8[(b*64 + p)*3 + 2];
    #pragma unroll
    for (int i = 0; i < 3; i++) {
      int d = t + i*256;
      v[i] = r0*frw[d] + r1*frw[768 + d] + r2*frw[1536 + d] + frb[d];
    }
  } else {
    int j = l - 65;
    int p = ((j >> 9) << 3) | ((j & 63) >> 3);
    float r0 = im8[(b*64 + p)*3 + 0], r1 = im8[(b*64 + p)*3 + 1], r2 = im8[(b*64 + p)*3 + 2];
    #pragma unroll
    for (int i = 0; i < 3; i++) {
      int d = t + i*256;
      v[i] = r0*frw[d] + r1*frw[768 + d] + r2*frw[1536 + d] + frb[d] + suffix[(size_t)j*768 + d];
    }
  }
  float s = v[0] + v[1] + v[2];
  s = blockSum256(s, sh);
  float mu = s * (1.f/768.f);
  float q = 0;
  #pragma unroll
  for (int i = 0; i < 3; i++) { float d = v[i] - mu; q += d*d; }
  q = blockSum256(q, sh);
  float rs = rsqrtf(q * (1.f/768.f) + EPSF);
  float* xr = x + (size_t)row*DM;
  #pragma unroll
  for (int i = 0; i < 3; i++) {
    int d = t + i*256;
    xr[d] = (v[i] - mu)*rs*w[d] + bb[d];
  }
}

// ---- per-layer LN -> bf16 ----
__global__ __launch_bounds__(256)
void ln_bf16_kernel(const float* __restrict__ x, const float* __restrict__ w,
                    const float* __restrict__ bb, u16* __restrict__ out)
{
  int row = blockIdx.x;
  int t = threadIdx.x;
  __shared__ float sh[4];
  const float* xr = x + (size_t)row*DM;
  float v[3];
  #pragma unroll
  for (int i = 0; i < 3; i++) v[i] = xr[t + i*256];
  float s = v[0] + v[1] + v[2];
  s = blockSum256(s, sh);
  float mu = s * (1.f/768.f);
  float q = 0;
  #pragma unroll
  for (int i = 0; i < 3; i++) { float d = v[i] - mu; q += d*d; }
  q = blockSum256(q, sh);
  float rs = rsqrtf(q * (1.f/768.f) + EPSF);
  u16* orow = out + (size_t)row*DM;
  #pragma unroll
  for (int i = 0; i < 3; i++) {
    int d = t + i*256;
    orow[d] = f2bf((v[i] - mu)*rs*w[d] + bb[d]);
  }
}

// ---- transpose + f32->bf16: in (K x N) -> out (Npad x K); grid(Npad/32, K/32) ----
__global__ __launch_bounds__(256)
void transp_bf16(const float* __restrict__ in, u16* __restrict__ out, int K, int N)
{
  __shared__ float tl[32][33];
  int tx = threadIdx.x & 31, ty = threadIdx.x >> 5;
  int n0 = blockIdx.x * 32, k0 = blockIdx.y * 32;
  #pragma unroll
  for (int r = 0; r < 4; r++) {
    int k = k0 + ty + r*8, n = n0 + tx;
    tl[ty + r*8][tx] = (n < N) ? in[(size_t)k*N + n] : 0.f;
  }
  __syncthreads();
  #pragma unroll
  for (int r = 0; r < 4; r++) {
    int n = n0 + ty + r*8, k = k0 + tx;
    out[(size_t)n*K + k] = f2bf(tl[tx][ty + r*8]);
  }
}

// ---- GEMM0: zx = xn @ Wi (bf16 A, lda DM); dt epilogue ----
__global__ __launch_bounds__(256)
void gemm0(const u16* __restrict__ A, const u16* __restrict__ BT,
           u16* __restrict__ zxO, const float* __restrict__ dtbias,
           float* __restrict__ dtO)
{
  __shared__ __align__(16) u16 As[128*40];
  __shared__ __align__(16) u16 Bs[128*40];
  const int t = threadIdx.x;
  const int bm = blockIdx.y, bn = blockIdx.x;
  const int lane = t & 63, wave = t >> 6;
  const int wr = wave >> 1, wc = wave & 1;
  const int r16 = lane & 15, kb = lane >> 4;

  const int m = t >> 1, half = t & 1;
  const int grow = bm*128 + m;
  const bool valid = grow < NROWS;
  const u16* gA = A + (size_t)grow*DM + half*16;
  const u16* gB = BT + (size_t)(bn*128 + m)*DM + half*16;
  u16* wA = &As[m*40 + half*16];
  u16* wB = &Bs[m*40 + half*16];

  f32x4 acc[4][4] = {};
  for (int kt = 0; kt < DM; kt += 32) {
    short8 b0 = *(const short8*)(gB + kt);
    short8 b1 = *(const short8*)(gB + kt + 8);
    short8 a0 = {}, a1 = {};
    if (valid) { a0 = *(const short8*)(gA + kt); a1 = *(const short8*)(gA + kt + 8); }
    *(short8*)(wA)     = a0; *(short8*)(wA + 8) = a1;
    *(short8*)(wB)     = b0; *(short8*)(wB + 8) = b1;
    __syncthreads();
    bf16x8 af[4], bfr[4];
    #pragma unroll
    for (int i = 0; i < 4; i++) af[i]  = *(const bf16x8*)&As[(wr*64 + i*16 + r16)*40 + kb*8];
    #pragma unroll
    for (int i = 0; i < 4; i++) bfr[i] = *(const bf16x8*)&Bs[(wc*64 + i*16 + r16)*40 + kb*8];
    #pragma unroll
    for (int i = 0; i < 4; i++)
      #pragma unroll
      for (int j = 0; j < 4; j++)
        acc[i][j] = __builtin_amdgcn_mfma_f32_16x16x32_bf16(af[i], bfr[j], acc[i][j], 0, 0, 0);
    __syncthreads();
  }
  const int rbase = bm*128 + wr*64, cbase = bn*128 + wc*64;
  #pragma unroll
  for (int i = 0; i < 4; i++) {
    #pragma unroll
    for (int j = 0; j < 4; j++) {
      int col = cbase + j*16 + r16;
      #pragma unroll
      for (int e = 0; e < 4; e++) {
        int row = rbase + i*16 + kb*4 + e;
        if (row < NROWS) {
          float v = acc[i][j][e];
          if (col < ZLD) {
            zxO[(size_t)row*ZLD + col] = f2bf(v);
          } else if (col < DIP) {
            int hh = col - ZLD;
            float d = v + dtbias[hh];
            d = (d > 20.f) ? d : log1pf(expf(d));
            dtO[(size_t)row*NH + hh] = d;
          }
        }
      }
    }
  }
}

// ---- GEMM1: x += gated(zx cols 0..1535) @ Wo ; A from zx with lda=ZLD ----
__global__ __launch_bounds__(256)
void gemm_out(const u16* __restrict__ A, const u16* __restrict__ BT, float* __restrict__ X)
{
  __shared__ __align__(16) u16 As[128*40];
  __shared__ __align__(16) u16 Bs[128*40];
  const int t = threadIdx.x;
  const int bm = blockIdx.y, bn = blockIdx.x;
  const int lane = t & 63, wave = t >> 6;
  const int wr = wave >> 1, wc = wave & 1;
  const int r16 = lane & 15, kb = lane >> 4;

  const int m = t >> 1, half = t & 1;
  const int grow = bm*128 + m;
  const bool valid = grow < NROWS;
  const u16* gA = A + (size_t)grow*ZLD + half*16;
  const u16* gB = BT + (size_t)(bn*128 + m)*DI + half*16;
  u16* wA = &As[m*40 + half*16];
  u16* wB = &Bs[m*40 + half*16];

  f32x4 acc[4][4] = {};
  for (int kt = 0; kt < DI; kt += 32) {
    short8 b0 = *(const short8*)(gB + kt);
    short8 b1 = *(const short8*)(gB + kt + 8);
    short8 a0 = {}, a1 = {};
    if (valid) { a0 = *(const short8*)(gA + kt); a1 = *(const short8*)(gA + kt + 8); }
    *(short8*)(wA)     = a0; *(short8*)(wA + 8) = a1;
    *(short8*)(wB)     = b0; *(short8*)(wB + 8) = b1;
    __syncthreads();
    bf16x8 af[4], bfr[4];
    #pragma unroll
    for (int i = 0; i < 4; i++) af[i]  = *(const bf16x8*)&As[(wr*64 + i*16 + r16)*40 + kb*8];
    #pragma unroll
    for (int i = 0; i < 4; i++) bfr[i] = *(const bf16x8*)&Bs[(wc*64 + i*16 + r16)*40 + kb*8];
    #pragma unroll
    for (int i = 0; i < 4; i++)
      #pragma unroll
      for (int j = 0; j < 4; j++)
        acc[i][j] = __builtin_amdgcn_mfma_f32_16x16x32_bf16(af[i], bfr[j], acc[i][j], 0, 0, 0);
    __syncthreads();
  }
  const int rbase = bm*128 + wr*64, cbase = bn*128 + wc*64;
  #pragma unroll
  for (int i = 0; i < 4; i++) {
    #pragma unroll
    for (int j = 0; j < 4; j++) {
      int col = cbase + j*16 + r16;
      #pragma unroll
      for (int e = 0; e < 4; e++) {
        int row = rbase + i*16 + kb*4 + e;
        if (row < NROWS) X[(size_t)row*DM + col] += acc[i][j][e];
      }
    }
  }
}

// ======================= chunked SSD =======================
// zx row layout (bf16, ld ZLD): [0,1536) z | [1536,3072) x raw | [3072,3200) B raw | [3200,3328) C raw
// Bcv/Ccv[(b*LTOT + l)*128 + n] : conv'd+silu'd B/C (head-independent, computed once)
// BcvT[(b*NCH + c)*16384 + n*128 + j] : conv'd B transposed per chunk (for K1 MFMA operand)
// cstat[id][p][n] bf16, id = (b*NCH + c)*NH + h ; dtot[id] f32

// ---- conv B/C once per (b,chunk): 132 blocks ----
__global__ __launch_bounds__(256)
void convBC_kernel(const u16* __restrict__ zx, const float* __restrict__ cw,
                   const float* __restrict__ cb, u16* __restrict__ Bcv,
                   u16* __restrict__ Ccv, u16* __restrict__ BcvT)
{
  const int bc = blockIdx.x;              // 0..BATCH*NCH-1
  const int b = bc / NCH, c = bc % NCH;
  const int t = threadIdx.x;
  const int base = c*CHK;
  __shared__ __align__(16) u16 raw[131*RLD + 8];  // [r][ch 0..255] (+3 row shift)
  __shared__ __align__(16) u16 Bt[128*LDF];       // conv'd B [j][n]
  __shared__ __align__(16) u16 Ct[128*LDF];       // conv'd C [j][n]
  const u16* zb = zx + (size_t)(b*LTOT)*ZLD;

  // stage raw 131 rows x 256 ch
  #pragma unroll
  for (int rg = 0; rg < 17; rg++) {
    int idx = rg*256 + t;
    int r = idx >> 5, seg = idx & 31;
    if (r < 131) {
      int g = base - 3 + r;
      short8 v = {};
      if (g >= 0 && g < LTOT) v = *(const short8*)(zb + (size_t)g*ZLD + 3072 + seg*8);
      *(short8*)&raw[r*RLD + seg*8] = v;
    }
  }
  __syncthreads();
  // conv channel t serially over 128 rows
  {
    const int isC = t >> 7, n = t & 127;
    const int ch = 1536 + t;
    float w0 = cw[ch*4+0], w1 = cw[ch*4+1], w2 = cw[ch*4+2], w3 = cw[ch*4+3];
    float bias = cb[ch];
    float r0 = bf2f(raw[0*RLD + t]);
    float r1 = bf2f(raw[1*RLD + t]);
    float r2 = bf2f(raw[2*RLD + t]);
    u16* dstT = isC ? Ct : Bt;
    #pragma unroll 4
    for (int j = 0; j < 128; j++) {
      float r3 = bf2f(raw[(j + 3)*RLD + t]);
      float o = bias + w0*r0 + w1*r1 + w2*r2 + w3*r3;
      dstT[j*LDF + n] = f2bf(siluf(o));
      r0 = r1; r1 = r2; r2 = r3;
    }
  }
  __syncthreads();
  // write Bcv/Ccv [l][n] coalesced
  #pragma unroll
  for (int rg = 0; rg < 16; rg++) {
    int idx = rg*256 + t;
    int r = idx >> 5, seg = idx & 31;
    int g = base + r;
    if (g < LTOT) {
      size_t orow = (size_t)(b*LTOT + g)*128;
      if (seg < 16) *(short8*)(Bcv + orow + seg*8)        = *(const short8*)&Bt[r*LDF + seg*8];
      else          *(short8*)(Ccv + orow + (seg - 16)*8) = *(const short8*)&Ct[r*LDF + (seg - 16)*8];
    }
  }
  // write BcvT [n][j] (transposed read from Bt)
  u16* bT = BcvT + (size_t)bc*16384;
  #pragma unroll
  for (int rg = 0; rg < 8; rg++) {
    int idx = rg*256 + t;
    int n = idx >> 4, js = (idx & 15)*8;
    short8 v;
    #pragma unroll
    for (int k = 0; k < 8; k++) v[k] = (short)Bt[(js + k)*LDF + n];
    *(short8*)(bT + n*128 + js) = v;
  }
}

// ---- K1: per-chunk state (256 threads; ~55 KB LDS) ----
__global__ __launch_bounds__(256)
void chunk_state_kernel(const u16* __restrict__ zx, const float* __restrict__ dtb,
                        const float* __restrict__ alog, const float* __restrict__ cw,
                        const float* __restrict__ cb, const u16* __restrict__ BcvT,
                        u16* __restrict__ cstat, float* __restrict__ dtot)
{
  const int id = blockIdx.x;
  const int h = id % NH; const int c = (id / NH) % NCH; const int b = id / (NH*NCH);
  const int t = threadIdx.x;
  const int base = c*CHK;
  int rows = LTOT - base; if (rows > CHK) rows = CHK;

  __shared__ __align__(16) u16 Bbuf[128*LDF];      // BTs[n][j]
  __shared__ __align__(16) u16 xbuf[131*XLD + 8];  // raw x -> xsT[p][j]
  __shared__ float dtv[128];
  __shared__ float cs[128];
  __shared__ float wjs[128];

  const u16* zb = zx + (size_t)(b*LTOT)*ZLD;
  const float aexp = __expf(alog[h]);
  if (t < 128) {
    float dv = 0.f;
    if (t < rows) dv = dtb[(size_t)(b*LTOT + base + t)*NH + h];
    dtv[t] = dv; cs[t] = -dv * aexp;
  }
  // stage conv'd B^T
  {
    const u16* bT = BcvT + (size_t)(b*NCH + c)*16384;
    #pragma unroll
    for (int rg = 0; rg < 8; rg++) {
      int idx = rg*256 + t;
      int n = idx >> 4, js = (idx & 15)*8;
      *(short8*)&Bbuf[n*LDF + js] = *(const short8*)(bT + n*128 + js);
    }
  }
  // stage raw x
  #pragma unroll
  for (int rg = 0; rg < 5; rg++) {
    int r = rg*32 + (t >> 3);
    int seg = t & 7;
    if (r < 131) {
      int g = base - 3 + r;
      short8 v = {};
      if (g >= 0 && g < LTOT) v = *(const short8*)(zb + (size_t)g*ZLD + 1536 + h*HD + seg*8);
      *(short8*)&xbuf[r*XLD + seg*8] = v;
    }
  }
  __syncthreads();
  for (int off = 1; off < 128; off <<= 1) {
    float add = 0.f;
    if (t < 128 && t >= off) add = cs[t - off];
    __syncthreads();
    if (t < 128) cs[t] += add;
    __syncthreads();
  }
  if (t < 128) wjs[t] = __expf(cs[127] - cs[t]) * dtv[t];
  __syncthreads();

  // x conv -> regs (scaled by wjs)
  const int p_ = t & 63, jq = t >> 6;
  u32 pkx[16];
  {
    const int ch = h*HD + p_;
    float w0 = cw[ch*4+0], w1 = cw[ch*4+1], w2 = cw[ch*4+2], w3 = cw[ch*4+3];
    float bias = cb[ch];
    const int rb = jq*32;
    float r0 = bf2f(xbuf[(rb+0)*XLD + p_]);
    float r1 = bf2f(xbuf[(rb+1)*XLD + p_]);
    float r2 = bf2f(xbuf[(rb+2)*XLD + p_]);
    #pragma unroll
    for (int k2 = 0; k2 < 16; k2++) {
      float r3 = bf2f(xbuf[(rb + 2*k2 + 3)*XLD + p_]);
      float o0 = bias + w0*r0 + w1*r1 + w2*r2 + w3*r3;
      float r4 = bf2f(xbuf[(rb + 2*k2 + 4)*XLD + p_]);
      float o1 = bias + w0*r1 + w1*r2 + w2*r3 + w3*r4;
      float s0 = siluf(o0) * wjs[rb + 2*k2];
      float s1 = siluf(o1) * wjs[rb + 2*k2 + 1];
      pkx[k2] = (u32)f2bf(s0) | ((u32)f2bf(s1) << 16);
      r0 = r2; r1 = r3; r2 = r4;
    }
  }
  __syncthreads();   // raw x reads done
  #pragma unroll
  for (int q = 0; q < 4; q++) {
    u32x4 v; v[0] = pkx[q*4]; v[1] = pkx[q*4+1]; v[2] = pkx[q*4+2]; v[3] = pkx[q*4+3];
    *(u32x4*)&xbuf[p_*LDF + jq*32 + q*8] = v;
  }
  __syncthreads();

  // chunk_state[p][n] = sum_j xsT[p][j] * BTs[n][j]
  const int lane = t & 63, wave = t >> 6;
  const int r16 = lane & 15, kb = lane >> 4;
  const int n0 = wave*32;
  f32x4 acc[4][2] = {};
  #pragma unroll
  for (int kt = 0; kt < 4; kt++) {
    bf16x8 af[4], bfr[2];
    #pragma unroll
    for (int m = 0; m < 4; m++) af[m] = *(const bf16x8*)&xbuf[(m*16 + r16)*LDF + kt*32 + kb*8];
    #pragma unroll
    for (int nn = 0; nn < 2; nn++) bfr[nn] = *(const bf16x8*)&Bbuf[(n0 + nn*16 + r16)*LDF + kt*32 + kb*8];
    #pragma unroll
    for (int m = 0; m < 4; m++)
      #pragma unroll
      for (int nn = 0; nn < 2; nn++)
        acc[m][nn] = __builtin_amdgcn_mfma_f32_16x16x32_bf16(af[m], bfr[nn], acc[m][nn], 0, 0, 0);
  }
  u16* dst = cstat + (size_t)id*64*128;
  #pragma unroll
  for (int m = 0; m < 4; m++)
    #pragma unroll
    for (int nn = 0; nn < 2; nn++)
      #pragma unroll
      for (int e = 0; e < 4; e++) {
        int p = m*16 + kb*4 + e;
        int n = n0 + nn*16 + r16;
        dst[p*128 + n] = f2bf(acc[m][nn][e]);
      }
  if (t == 0) dtot[id] = __expf(cs[127]);
}

// ---- K2: inter-chunk scan (in-place: slot <- state BEFORE that chunk) ----
__global__ __launch_bounds__(256)
void state_scan_kernel(u16* __restrict__ cstat, const float* __restrict__ dtot)
{
  const int b = blockIdx.x / NH, h = blockIdx.x % NH;
  const int t = threadIdx.x;
  float run[32];
  #pragma unroll
  for (int k = 0; k < 32; k++) run[k] = 0.f;
  size_t id0 = (size_t)(b*NCH)*NH + h;
  short8 cur[4];
  {
    const u16* s0 = cstat + id0*8192 + t*32;
    #pragma unroll
    for (int q = 0; q < 4; q++) cur[q] = *(const short8*)(s0 + q*8);
  }
  float d = dtot[id0];
  for (int c = 0; c < NCH; ++c) {
    size_t id = (size_t)(b*NCH + c)*NH + h;
    u16* slab = cstat + id*8192 + t*32;
    short8 nxt[4] = {}; float nd = 0.f;
    if (c + 1 < NCH) {
      const u16* sn = slab + (size_t)NH*8192;
      #pragma unroll
      for (int q = 0; q < 4; q++) nxt[q] = *(const short8*)(sn + q*8);
      nd = dtot[id + NH];
    }
    short8 out[4];
    #pragma unroll
    for (int q = 0; q < 4; q++)
      #pragma unroll
      for (int k = 0; k < 8; k++) {
        int idx = q*8 + k;
        float csv = bf2f((u16)cur[q][k]);
        out[q][k] = (short)f2bf(run[idx]);
        run[idx] = run[idx]*d + csv;
      }
    #pragma unroll
    for (int q = 0; q < 4; q++) *(short8*)(slab + q*8) = out[q];
    #pragma unroll
    for (int q = 0; q < 4; q++) cur[q] = nxt[q];
    d = nd;
  }
}

// ---- K3: per-chunk output (512 threads / 8 waves); writes y*silu(z) over z-cols of zx ----
__global__ __launch_bounds__(512, 2)
void chunk_output_kernel(u16* __restrict__ zx, const float* __restrict__ dtb,
                         const float* __restrict__ alog, const float* __restrict__ cw,
                         const float* __restrict__ cb, const float* __restrict__ Dvec,
                         const u16* __restrict__ Bcv, const u16* __restrict__ Ccv,
                         const u16* __restrict__ cstat)
{
  const int id = blockIdx.x;
  const int h = id % NH; const int c = (id / NH) % NCH; const int b = id / (NH*NCH);
  const int t = threadIdx.x;                 // 0..511
  const int base = c*CHK;
  int rows = LTOT - base; if (rows > CHK) rows = CHK;

  __shared__ __align__(16) u16 Bc[128*LDF];       // conv'd B [j][n] -> P[i][j]
  __shared__ __align__(16) u16 Cc[128*LDF];       // conv'd C [i][n]
  __shared__ __align__(16) u16 stT[64*LDF];       // state_before [p][n]
  __shared__ __align__(16) u16 xbuf[131*XLD + 8]; // raw x -> xc[p][j]
  __shared__ float dtv[128];
  __shared__ float cs[128];

  const u16* zb = zx + (size_t)(b*LTOT)*ZLD;
  const float aexp = __expf(alog[h]);
  if (t < 128) {
    float dv = 0.f;
    if (t < rows) dv = dtb[(size_t)(b*LTOT + base + t)*NH + h];
    dtv[t] = dv; cs[t] = -dv * aexp;
  }
  // stage state_before
  {
    const u16* slab = cstat + (size_t)id*8192;
    int p = t >> 3, nb = (t & 7)*16;
    *(short8*)&stT[p*LDF + nb]     = *(const short8*)(slab + p*128 + nb);
    *(short8*)&stT[p*LDF + nb + 8] = *(const short8*)(slab + p*128 + nb + 8);
  }
  // stage conv'd B/C: 16 rows/round x 8 rounds
  #pragma unroll
  for (int rg = 0; rg < 8; rg++) {
    int r = rg*16 + (t >> 5);
    int seg = t & 31;
    int g = base + r;
    short8 v = {};
    if (g < LTOT) {
      size_t srow = (size_t)(b*LTOT + g)*128;
      v = (seg < 16) ? *(const short8*)(Bcv + srow + seg*8)
                     : *(const short8*)(Ccv + srow + (seg - 16)*8);
    }
    if (seg < 16) *(short8*)&Bc[r*LDF + seg*8] = v;
    else          *(short8*)&Cc[r*LDF + (seg - 16)*8] = v;
  }
  // stage raw x: 64 rows/round
  #pragma unroll
  for (int rg = 0; rg < 3; rg++) {
    int r = rg*64 + (t >> 3);
    int seg = t & 7;
    if (r < 131) {
      int g = base - 3 + r;
      short8 v = {};
      if (g >= 0 && g < LTOT) v = *(const short8*)(zb + (size_t)g*ZLD + 1536 + h*HD + seg*8);
      *(short8*)&xbuf[r*XLD + seg*8] = v;
    }
  }
  __syncthreads();
  // prefix sum of dtA
  for (int off = 1; off < 128; off <<= 1) {
    float add = 0.f;
    if (t < 128 && t >= off) add = cs[t - off];
    __syncthreads();
    if (t < 128) cs[t] += add;
    __syncthreads();
  }

  // x conv -> regs (8 j-groups of 16)
  const int p_ = t & 63, jq = t >> 6;
  u32 pkx[8];
  {
    const int ch = h*HD + p_;
    float w0 = cw[ch*4+0], w1 = cw[ch*4+1], w2 = cw[ch*4+2], w3 = cw[ch*4+3];
    float bias = cb[ch];
    const int rb = jq*16;
    float r0 = bf2f(xbuf[(rb+0)*XLD + p_]);
    float r1 = bf2f(xbuf[(rb+1)*XLD + p_]);
    float r2 = bf2f(xbuf[(rb+2)*XLD + p_]);
    #pragma unroll
    for (int k2 = 0; k2 < 8; k2++) {
      float r3 = bf2f(xbuf[(rb + 2*k2 + 3)*XLD + p_]);
      float o0 = bias + w0*r0 + w1*r1 + w2*r2 + w3*r3;
      float r4 = bf2f(xbuf[(rb + 2*k2 + 4)*XLD + p_]);
      float o1 = bias + w0*r1 + w1*r2 + w2*r3 + w3*r4;
      int j0 = rb + 2*k2;
      u32 lo = (j0     < rows) ? (u32)f2bf(siluf(o0)) : 0u;
      u32 hi = (j0 + 1 < rows) ? (u32)f2bf(siluf(o1)) : 0u;
      pkx[k2] = lo | (hi << 16);
      r0 = r2; r1 = r3; r2 = r4;
    }
  }
  __syncthreads();   // all raw x reads complete
  // write xc[p][j] over xbuf
  {
    u32x4 v0; v0[0] = pkx[0]; v0[1] = pkx[1]; v0[2] = pkx[2]; v0[3] = pkx[3];
    u32x4 v1; v1[0] = pkx[4]; v1[1] = pkx[5]; v1[2] = pkx[6]; v1[3] = pkx[7];
    *(u32x4*)&xbuf[p_*LDF + jq*16]     = v0;
    *(u32x4*)&xbuf[p_*LDF + jq*16 + 8] = v1;
  }
  __syncthreads();

  const int lane = t & 63, wave = t >> 6;
  const int r16 = lane & 15, kb = lane >> 4;

  // Phase A: S[i][j] = sum_n Cc[i][n]*Bc[j][n]; 8 waves -> 64x32 tiles; then P into Bc
  {
    const int wi = wave >> 2, wjn = wave & 3;
    f32x4 acc[4][2] = {};
    #pragma unroll
    for (int kt = 0; kt < 4; kt++) {
      bf16x8 af[4], bfr[2];
      #pragma unroll
      for (int m = 0; m < 4; m++) af[m] = *(const bf16x8*)&Cc[(wi*64 + m*16 + r16)*LDF + kt*32 + kb*8];
      #pragma unroll
      for (int nj = 0; nj < 2; nj++) bfr[nj] = *(const bf16x8*)&Bc[(wjn*32 + nj*16 + r16)*LDF + kt*32 + kb*8];
      #pragma unroll
      for (int m = 0; m < 4; m++)
        #pragma unroll
        for (int nj = 0; nj < 2; nj++)
          acc[m][nj] = __builtin_amdgcn_mfma_f32_16x16x32_bf16(af[m], bfr[nj], acc[m][nj], 0, 0, 0);
    }
    __syncthreads();   // all conv'd-B reads done -> safe to overwrite with P
    #pragma unroll
    for (int m = 0; m < 4; m++)
      #pragma unroll
      for (int nj = 0; nj < 2; nj++)
        #pragma unroll
        for (int e = 0; e < 4; e++) {
          int i = wi*64 + m*16 + kb*4 + e;
          int j = wjn*32 + nj*16 + r16;
          float f = 0.f;
          if (j <= i && i < rows) f = __expf(cs[i] - cs[j]) * dtv[j];
          Bc[i*LDF + j] = f2bf(acc[m][nj][e] * f);
        }
  }
  __syncthreads();

  // Phase B: Y1 = P @ xc^T ; Phase C: Y2 = Cc @ stT^T ; 8 waves -> 16 rows each
  {
    const int iq = wave;
    f32x4 accY[4] = {};
    #pragma unroll
    for (int kt = 0; kt < 4; kt++) {
      bf16x8 af = *(const bf16x8*)&Bc[(iq*16 + r16)*LDF + kt*32 + kb*8];
      #pragma unroll
      for (int n = 0; n < 4; n++) {
        bf16x8 bfr = *(const bf16x8*)&xbuf[(n*16 + r16)*LDF + kt*32 + kb*8];
        accY[n] = __builtin_amdgcn_mfma_f32_16x16x32_bf16(af, bfr, accY[n], 0, 0, 0);
      }
    }
    f32x4 accS[4] = {};
    #pragma unroll
    for (int kt = 0; kt < 4; kt++) {
      bf16x8 af = *(const bf16x8*)&Cc[(iq*16 + r16)*LDF + kt*32 + kb*8];
      #pragma unroll
      for (int n = 0; n < 4; n++) {
        bf16x8 bfr = *(const bf16x8*)&stT[(n*16 + r16)*LDF + kt*32 + kb*8];
        accS[n] = __builtin_amdgcn_mfma_f32_16x16x32_bf16(af, bfr, accS[n], 0, 0, 0);
      }
    }
    const float dcoef = Dvec[h];
    #pragma unroll
    for (int e = 0; e < 4; e++) {
      int i = iq*16 + kb*4 + e;
      if (i < rows) {
        float sc = __expf(cs[i]);
        size_t orow = (size_t)(b*LTOT + base + i)*ZLD + h*HD;
        #pragma unroll
        for (int n = 0; n < 4; n++) {
          int p = n*16 + r16;
          float xv = bf2f(xbuf[p*LDF + i]);
          float yv = accY[n][e] + sc*accS[n][e] + dcoef*xv;
          float zval = bf2f(zx[orow + p]);
          zx[orow + p] = f2bf(yv * siluf(zval));
        }
      }
    }
  }
}

// ---- rmsnorm in place on zx cols [0,1536) ----
__global__ __launch_bounds__(256)
void gate_rms_kernel(u16* __restrict__ zx, const float* __restrict__ gw)
{
  int row = blockIdx.x;
  int t = threadIdx.x;
  __shared__ float sh[4];
  float g[6]; float ss = 0.f;
  u16* zr = zx + (size_t)row*ZLD;
  #pragma unroll
  for (int i = 0; i < 6; i++) {
    int c = t + i*256;
    g[i] = bf2f(zr[c]);
    ss += g[i]*g[i];
  }
  ss = blockSum256(ss, sh);
  float rs = rsqrtf(ss * (1.f/1536.f) + EPSF);
  #pragma unroll
  for (int i = 0; i < 6; i++) {
    int c = t + i*256;
    zr[c] = f2bf(g[i]*rs*gw[c]);
  }
}

// ---- head ----
__global__ __launch_bounds__(256)
void head_kernel(const float* __restrict__ x, const float* __restrict__ tw,
                 const float* __restrict__ tb, const float* __restrict__ im64,
                 float* __restrict__ out, float* __restrict__ partial)
{
  int bj = blockIdx.x;
  int b = bj >> 12, j = bj & 4095;
  int row = b*LTOT + 65 + j;
  const float* xr = x + (size_t)row*DM;
  int t = threadIdx.x;
  float p0 = 0, p1 = 0, p2 = 0;
  for (int k = t; k < 768; k += 256) {
    float xv = xr[k];
    p0 += xv*tw[k*3 + 0]; p1 += xv*tw[k*3 + 1]; p2 += xv*tw[k*3 + 2];
  }
  __shared__ float sh[4];
  p0 = blockSum256(p0, sh);
  p1 = blockSum256(p1, sh);
  p2 = blockSum256(p2, sh);
  if (t == 0) {
    float y0 = p0 + tb[0], y1 = p1 + tb[1], y2 = p2 + tb[2];
    size_t o = (size_t)bj*3;
    out[o] = y0; out[o + 1] = y1; out[o + 2] = y2;
    float d0 = y0 - im64[o], d1 = y1 - im64[o + 1], d2 = y2 - im64[o + 2];
    partial[bj] = d0*d0 + d1*d1 + d2*d2;
  }
}

__global__ __launch_bounds__(256)
void loss_reduce(const float* __restrict__ partial, float* __restrict__ out)
{
  int t = threadIdx.x;
  float s = 0.f;
  for (int i = t; i < BATCH*4096; i += 256) s += partial[i];
  __shared__ float sh[4];
  s = blockSum256(s, sh);
  if (t == 0) out[49152] = s * (1.f/49152.f);
}

// ---- launcher ----
static inline size_t alignup(size_t v){ return (v + 255) & ~(size_t)255; }

extern "C" void kernel_launch(void* const* d_in, const int* in_sizes, int n_in,
                              void* d_out, int out_size, void* d_ws, size_t ws_size,
                              hipStream_t stream)
{
  const float* im8        = (const float*)d_in[0];
  const float* im64       = (const float*)d_in[1];
  const float* from_rgb_w = (const float*)d_in[2];
  const float* from_rgb_b = (const float*)d_in[3];
  const float* to_rgb_w   = (const float*)d_in[4];
  const float* to_rgb_b   = (const float*)d_in[5];
  const float* s0         = (const float*)d_in[6];
  const float* suffix     = (const float*)d_in[7];
  const float* norm0_w    = (const float*)d_in[8];
  const float* norm0_b    = (const float*)d_in[9];
  const float* ln_w       = (const float*)d_in[10];
  const float* ln_b       = (const float*)d_in[11];
  const float* in_proj_w  = (const float*)d_in[12];
  const float* conv_w     = (const float*)d_in[13];
  const float* conv_b     = (const float*)d_in[14];
  const float* dt_bias    = (const float*)d_in[15];
  const float* A_log      = (const float*)d_in[16];
  const float* Dvec       = (const float*)d_in[17];
  const float* gn_w       = (const float*)d_in[18];
  const float* out_proj_w = (const float*)d_in[19];

  char* w = (char*)d_ws;
  size_t off = 0;
  float* x     = (float*)(w + off); off = alignup(off + (size_t)NROWS*DM*4);        // 51.1 MB
  u16*   zx    = (u16*)  (w + off); off = alignup(off + (size_t)NROWS*ZLD*2);       // 110.8 MB
  u16*   scr   = (u16*)  (w + off); off = alignup(off + (size_t)BATCH*NCH*NH*64*128*2); // 51.9 MB (wT+xn | cstat)
  u16*   Bcv   = (u16*)  (w + off); off = alignup(off + (size_t)NROWS*128*2);       // 4.26 MB
  u16*   Ccv   = (u16*)  (w + off); off = alignup(off + (size_t)NROWS*128*2);       // 4.26 MB
  u16*   BcvT  = (u16*)  (w + off); off = alignup(off + (size_t)BATCH*NCH*16384*2); // 4.33 MB
  float* dt    = (float*)(w + off); off = alignup(off + (size_t)NROWS*NH*4);        // 1.6 MB
  float* dtot  = (float*)(w + off); off = alignup(off + (size_t)BATCH*NCH*NH*4);    // 12.7 KB
  float* lpart = (float*)(w + off); off = alignup(off + (size_t)BATCH*4096*4);      // 64 KB
  // total ~228.5 MB
  u16* wT    = scr;                                                     // 5.31 MB
  u16* xn    = (u16*)((char*)scr + alignup((size_t)NPAD1*DM*2));        // 25.6 MB (ends ~30.9 MB)
  u16* cstat = scr;                                                     // 51.9 MB (after gemm0)

  build_x_kernel<<<NROWS, 256, 0, stream>>>(im8, from_rgb_w, from_rgb_b, s0, suffix,
                                            norm0_w, norm0_b, x);

  const int NBLK = BATCH*NCH*NH;   // 3168
  for (int i = 0; i < 4; i++) {
    ln_bf16_kernel<<<NROWS, 256, 0, stream>>>(x, ln_w + i*DM, ln_b + i*DM, xn);
    transp_bf16<<<dim3(NPAD1/32, DM/32), 256, 0, stream>>>(in_proj_w + (size_t)i*DM*DIP, wT, DM, DIP);
    gemm0<<<dim3(NPAD1/128, MPAD/128), 256, 0, stream>>>(xn, wT, zx, dt_bias + i*NH, dt);
    convBC_kernel<<<BATCH*NCH, 256, 0, stream>>>(zx, conv_w + (size_t)i*(DI+2*DS)*4,
        conv_b + i*(DI+2*DS), Bcv, Ccv, BcvT);
    chunk_state_kernel<<<NBLK, 256, 0, stream>>>(zx, dt, A_log + i*NH,
        conv_w + (size_t)i*(DI+2*DS)*4, conv_b + i*(DI+2*DS), BcvT, cstat, dtot);
    state_scan_kernel<<<BATCH*NH, 256, 0, stream>>>(cstat, dtot);
    chunk_output_kernel<<<NBLK, 512, 0, stream>>>(zx, dt, A_log + i*NH,
        conv_w + (size_t)i*(DI+2*DS)*4, conv_b + i*(DI+2*DS), Dvec + i*NH, Bcv, Ccv, cstat);
    gate_rms_kernel<<<NROWS, 256, 0, stream>>>(zx, gn_w + i*DI);
    transp_bf16<<<dim3(DM/32, DI/32), 256, 0, stream>>>(out_proj_w + (size_t)i*DI*DM, wT, DI, DM);
    gemm_out<<<dim3(DM/128, MPAD/128), 256, 0, stream>>>(zx, wT, x);
  }

  head_kernel<<<BATCH*4096, 256, 0, stream>>>(x, to_rgb_w, to_rgb_b, im64, (float*)d_out, lpart);
  loss_reduce<<<1, 256, 0, stream>>>(lpart, (float*)d_out);
}

// Round 8
// 2433.804 us; speedup vs baseline: 6.3279x; 1.1186x over previous
//
#include <hip/hip_runtime.h>
#include <hip/hip_bf16.h>
#include <math.h>

// ---- problem constants ----
#define LTOT 4161
#define BATCH 4
#define NROWS (BATCH*LTOT)      // 16644
#define MPAD 16768              // rows padded for 128-tile GEMM grid
#define NPAD1 3456              // 3352 -> padded to 128 multiple
#define DM 768
#define DI 1536
#define DIP 3352
#define ZLD 3328                // stored columns of zx
#define NH 24
#define HD 64
#define DS 128
#define EPSF 1e-5f
#define CHK 128                 // SSD chunk length
#define NCH 33                  // ceil(4161/128)
#define LDF 136                 // LDS row stride (u16) for 128-wide tiles
#define XLD 72                  // LDS row stride (u16) for raw-x staging
#define RLD 264                 // LDS row stride (u16) for raw B/C staging in convBC

typedef __attribute__((ext_vector_type(8))) __bf16 bf16x8;
typedef __attribute__((ext_vector_type(4))) float f32x4;
typedef __attribute__((ext_vector_type(8))) short short8;
typedef __attribute__((ext_vector_type(4))) unsigned int u32x4;
typedef unsigned short u16;
typedef unsigned int u32;

static __device__ __forceinline__ u16 f2bf(float f){
  unsigned u = __builtin_bit_cast(unsigned, f);
  u += 0x7FFFu + ((u >> 16) & 1u);          // RNE
  return (u16)(u >> 16);
}
static __device__ __forceinline__ float bf2f(u16 v){
  return __builtin_bit_cast(float, ((unsigned)v) << 16);
}
static __device__ __forceinline__ float siluf(float v){ return v / (1.f + __expf(-v)); }

// bijective XCD-chunking remap (m204): consecutive new-ids land on the same XCD
static __device__ __forceinline__ int xcd_swz(int orig, int nwg){
  int xcd = orig & 7;
  int idx = orig >> 3;
  int q = nwg >> 3, r = nwg & 7;
  int base = (xcd < r) ? xcd*(q + 1) : r*(q + 1) + (xcd - r)*q;
  return base + idx;
}

__device__ __forceinline__ float blockSum256(float v, float* sh){
  #pragma unroll
  for (int o = 32; o > 0; o >>= 1) v += __shfl_down(v, o);
  int w = threadIdx.x >> 6;
  if ((threadIdx.x & 63) == 0) sh[w] = v;
  __syncthreads();
  v = sh[0] + sh[1] + sh[2] + sh[3];
  __syncthreads();
  return v;
}

// ---- build x = LN0(concat(s0, h8, zm)) ----
__global__ __launch_bounds__(256)
void build_x_kernel(const float* __restrict__ im8, const float* __restrict__ frw,
                    const float* __restrict__ frb, const float* __restrict__ s0,
                    const float* __restrict__ suffix, const float* __restrict__ w,
                    const float* __restrict__ bb, float* __restrict__ x)
{
  int row = blockIdx.x;
  int b = row / LTOT, l = row % LTOT;
  int t = threadIdx.x;
  __shared__ float sh[4];
  float v[3];
  if (l == 0) {
    #pragma unroll
    for (int i = 0; i < 3; i++) v[i] = s0[t + i*256];
  } else if (l <= 64) {
    int p = l - 1;
    float r0 = im8[(b*64 + p)*3 + 0], r1 = im8[(b*64 + p)*3 + 1], r2 = im8[(b*64 + p)*3 + 2];
    #pragma unroll
    for (int i = 0; i < 3; i++) {
      int d = t + i*256;
      v[i] = r0*frw[d] + r1*frw[768 + d] + r2*frw[1536 + d] + frb[d];
    }
  } else {
    int j = l - 65;
    int p = ((j >> 9) << 3) | ((j & 63) >> 3);
    float r0 = im8[(b*64 + p)*3 + 0], r1 = im8[(b*64 + p)*3 + 1], r2 = im8[(b*64 + p)*3 + 2];
    #pragma unroll
    for (int i = 0; i < 3; i++) {
      int d = t + i*256;
      v[i] = r0*frw[d] + r1*frw[768 + d] + r2*frw[1536 + d] + frb[d] + suffix[(size_t)j*768 + d];
    }
  }
  float s = v[0] + v[1] + v[2];
  s = blockSum256(s, sh);
  float mu = s * (1.f/768.f);
  float q = 0;
  #pragma unroll
  for (int i = 0; i < 3; i++) { float d = v[i] - mu; q += d*d; }
  q = blockSum256(q, sh);
  float rs = rsqrtf(q * (1.f/768.f) + EPSF);
  float* xr = x + (size_t)row*DM;
  #pragma unroll
  for (int i = 0; i < 3; i++) {
    int d = t + i*256;
    xr[d] = (v[i] - mu)*rs*w[d] + bb[d];
  }
}

// ---- per-layer LN -> bf16 ----
__global__ __launch_bounds__(256)
void ln_bf16_kernel(const float* __restrict__ x, const float* __restrict__ w,
                    const float* __restrict__ bb, u16* __restrict__ out)
{
  int row = blockIdx.x;
  int t = threadIdx.x;
  __shared__ float sh[4];
  const float* xr = x + (size_t)row*DM;
  float v[3];
  #pragma unroll
  for (int i = 0; i < 3; i++) v[i] = xr[t + i*256];
  float s = v[0] + v[1] + v[2];
  s = blockSum256(s, sh);
  float mu = s * (1.f/768.f);
  float q = 0;
  #pragma unroll
  for (int i = 0; i < 3; i++) { float d = v[i] - mu; q += d*d; }
  q = blockSum256(q, sh);
  float rs = rsqrtf(q * (1.f/768.f) + EPSF);
  u16* orow = out + (size_t)row*DM;
  #pragma unroll
  for (int i = 0; i < 3; i++) {
    int d = t + i*256;
    orow[d] = f2bf((v[i] - mu)*rs*w[d] + bb[d]);
  }
}

// ---- transpose + f32->bf16: in (K x N) -> out (Npad x K); grid(Npad/32, K/32) ----
__global__ __launch_bounds__(256)
void transp_bf16(const float* __restrict__ in, u16* __restrict__ out, int K, int N)
{
  __shared__ float tl[32][33];
  int tx = threadIdx.x & 31, ty = threadIdx.x >> 5;
  int n0 = blockIdx.x * 32, k0 = blockIdx.y * 32;
  #pragma unroll
  for (int r = 0; r < 4; r++) {
    int k = k0 + ty + r*8, n = n0 + tx;
    tl[ty + r*8][tx] = (n < N) ? in[(size_t)k*N + n] : 0.f;
  }
  __syncthreads();
  #pragma unroll
  for (int r = 0; r < 4; r++) {
    int n = n0 + ty + r*8, k = k0 + tx;
    out[(size_t)n*K + k] = f2bf(tl[tx][ty + r*8]);
  }
}

#define LD8(p) (*(const short8*)(p))

// ---- GEMM0: zx = xn @ Wi (bf16 A, lda DM); dt epilogue; XCD-swizzled; pipelined ----
__global__ __launch_bounds__(256)
void gemm0(const u16* __restrict__ A, const u16* __restrict__ BT,
           u16* __restrict__ zxO, const float* __restrict__ dtbias,
           float* __restrict__ dtO)
{
  __shared__ __align__(16) u16 As[128*40];
  __shared__ __align__(16) u16 Bs[128*40];
  const int t = threadIdx.x;
  const int nid = xcd_swz(blockIdx.y*27 + blockIdx.x, 27*131);
  const int bm = nid / 27, bn = nid % 27;
  const int lane = t & 63, wave = t >> 6;
  const int wr = wave >> 1, wc = wave & 1;
  const int r16 = lane & 15, kb = lane >> 4;

  const int m = t >> 1, half = t & 1;
  const int grow = bm*128 + m;
  const bool valid = grow < NROWS;
  const u16* gA = A + (size_t)(valid ? grow : 0)*DM + half*16;
  const u16* gB = BT + (size_t)(bn*128 + m)*DM + half*16;
  u16* wA = &As[m*40 + half*16];
  u16* wB = &Bs[m*40 + half*16];

  short8 a0 = {}, a1 = {}, b0, b1;
  b0 = LD8(gB); b1 = LD8(gB + 8);
  if (valid) { a0 = LD8(gA); a1 = LD8(gA + 8); }

  f32x4 acc[4][4] = {};
  for (int kt = 0; kt < DM; kt += 32) {
    *(short8*)(wA)     = a0; *(short8*)(wA + 8) = a1;
    *(short8*)(wB)     = b0; *(short8*)(wB + 8) = b1;
    __syncthreads();
    if (kt + 32 < DM) {            // prefetch next K-tile; latency hides under MFMA
      b0 = LD8(gB + kt + 32); b1 = LD8(gB + kt + 40);
      if (valid) { a0 = LD8(gA + kt + 32); a1 = LD8(gA + kt + 40); }
    }
    bf16x8 af[4], bfr[4];
    #pragma unroll
    for (int i = 0; i < 4; i++) af[i]  = *(const bf16x8*)&As[(wr*64 + i*16 + r16)*40 + kb*8];
    #pragma unroll
    for (int i = 0; i < 4; i++) bfr[i] = *(const bf16x8*)&Bs[(wc*64 + i*16 + r16)*40 + kb*8];
    #pragma unroll
    for (int i = 0; i < 4; i++)
      #pragma unroll
      for (int j = 0; j < 4; j++)
        acc[i][j] = __builtin_amdgcn_mfma_f32_16x16x32_bf16(af[i], bfr[j], acc[i][j], 0, 0, 0);
    __syncthreads();
  }
  const int rbase = bm*128 + wr*64, cbase = bn*128 + wc*64;
  #pragma unroll
  for (int i = 0; i < 4; i++) {
    #pragma unroll
    for (int j = 0; j < 4; j++) {
      int col = cbase + j*16 + r16;
      #pragma unroll
      for (int e = 0; e < 4; e++) {
        int row = rbase + i*16 + kb*4 + e;
        if (row < NROWS) {
          float v = acc[i][j][e];
          if (col < ZLD) {
            zxO[(size_t)row*ZLD + col] = f2bf(v);
          } else if (col < DIP) {
            int hh = col - ZLD;
            float d = v + dtbias[hh];
            d = (d > 20.f) ? d : log1pf(expf(d));
            dtO[(size_t)row*NH + hh] = d;
          }
        }
      }
    }
  }
}

// ---- GEMM1: x += rmsnorm-scaled gated zx @ Wo ; rs*gw fused into A-staging ----
__global__ __launch_bounds__(256)
void gemm_out(const u16* __restrict__ A, const float* __restrict__ rsb,
              const float* __restrict__ gw, const u16* __restrict__ BT,
              float* __restrict__ X)
{
  __shared__ __align__(16) u16 As[128*40];
  __shared__ __align__(16) u16 Bs[128*40];
  __shared__ float gwl[DI];
  const int t = threadIdx.x;
  const int nid = xcd_swz(blockIdx.y*6 + blockIdx.x, 6*131);
  const int bm = nid / 6, bn = nid % 6;
  const int lane = t & 63, wave = t >> 6;
  const int wr = wave >> 1, wc = wave & 1;
  const int r16 = lane & 15, kb = lane >> 4;

  for (int i = t; i < DI; i += 256) gwl[i] = gw[i];

  const int m = t >> 1, half = t & 1;
  const int grow = bm*128 + m;
  const bool valid = grow < NROWS;
  const float rs = valid ? rsb[grow] : 0.f;
  const u16* gA = A + (size_t)(valid ? grow : 0)*ZLD + half*16;
  const u16* gB = BT + (size_t)(bn*128 + m)*DI + half*16;
  u16* wA = &As[m*40 + half*16];
  u16* wB = &Bs[m*40 + half*16];

  short8 ra0 = {}, ra1 = {}, b0, b1;
  b0 = LD8(gB); b1 = LD8(gB + 8);
  if (valid) { ra0 = LD8(gA); ra1 = LD8(gA + 8); }
  __syncthreads();   // gwl visible

  f32x4 acc[4][4] = {};
  for (int kt = 0; kt < DI; kt += 32) {
    const int c0 = kt + half*16;
    short8 ta0, ta1;
    #pragma unroll
    for (int j = 0; j < 8; j++) ta0[j] = (short)f2bf(bf2f((u16)ra0[j]) * rs * gwl[c0 + j]);
    #pragma unroll
    for (int j = 0; j < 8; j++) ta1[j] = (short)f2bf(bf2f((u16)ra1[j]) * rs * gwl[c0 + 8 + j]);
    *(short8*)(wA)     = ta0; *(short8*)(wA + 8) = ta1;
    *(short8*)(wB)     = b0;  *(short8*)(wB + 8) = b1;
    __syncthreads();
    if (kt + 32 < DI) {
      b0 = LD8(gB + kt + 32); b1 = LD8(gB + kt + 40);
      if (valid) { ra0 = LD8(gA + kt + 32); ra1 = LD8(gA + kt + 40); }
    }
    bf16x8 af[4], bfr[4];
    #pragma unroll
    for (int i = 0; i < 4; i++) af[i]  = *(const bf16x8*)&As[(wr*64 + i*16 + r16)*40 + kb*8];
    #pragma unroll
    for (int i = 0; i < 4; i++) bfr[i] = *(const bf16x8*)&Bs[(wc*64 + i*16 + r16)*40 + kb*8];
    #pragma unroll
    for (int i = 0; i < 4; i++)
      #pragma unroll
      for (int j = 0; j < 4; j++)
        acc[i][j] = __builtin_amdgcn_mfma_f32_16x16x32_bf16(af[i], bfr[j], acc[i][j], 0, 0, 0);
    __syncthreads();
  }
  const int rbase = bm*128 + wr*64, cbase = bn*128 + wc*64;
  #pragma unroll
  for (int i = 0; i < 4; i++) {
    #pragma unroll
    for (int j = 0; j < 4; j++) {
      int col = cbase + j*16 + r16;
      #pragma unroll
      for (int e = 0; e < 4; e++) {
        int row = rbase + i*16 + kb*4 + e;
        if (row < NROWS) X[(size_t)row*DM + col] += acc[i][j][e];
      }
    }
  }
}

// ======================= chunked SSD =======================
// zx row layout (bf16, ld ZLD): [0,1536) z | [1536,3072) x raw | [3072,3200) B raw | [3200,3328) C raw
// Bcv/Ccv[(b*LTOT + l)*128 + n] : conv'd+silu'd B/C ; BcvT[(b*NCH + c)*16384 + n*128 + j]
// cstat[id][p][n] bf16, id = (b*NCH + c)*NH + h ; dtot[id] f32

// ---- conv B/C once per (b,chunk): 132 blocks ----
__global__ __launch_bounds__(256)
void convBC_kernel(const u16* __restrict__ zx, const float* __restrict__ cw,
                   const float* __restrict__ cb, u16* __restrict__ Bcv,
                   u16* __restrict__ Ccv, u16* __restrict__ BcvT)
{
  const int bc = xcd_swz(blockIdx.x, BATCH*NCH);
  const int b = bc / NCH, c = bc % NCH;
  const int t = threadIdx.x;
  const int base = c*CHK;
  __shared__ __align__(16) u16 raw[131*RLD + 8];
  __shared__ __align__(16) u16 Bt[128*LDF];
  __shared__ __align__(16) u16 Ct[128*LDF];
  const u16* zb = zx + (size_t)(b*LTOT)*ZLD;

  #pragma unroll
  for (int rg = 0; rg < 17; rg++) {
    int idx = rg*256 + t;
    int r = idx >> 5, seg = idx & 31;
    if (r < 131) {
      int g = base - 3 + r;
      short8 v = {};
      if (g >= 0 && g < LTOT) v = *(const short8*)(zb + (size_t)g*ZLD + 3072 + seg*8);
      *(short8*)&raw[r*RLD + seg*8] = v;
    }
  }
  __syncthreads();
  {
    const int isC = t >> 7, n = t & 127;
    const int ch = 1536 + t;
    float w0 = cw[ch*4+0], w1 = cw[ch*4+1], w2 = cw[ch*4+2], w3 = cw[ch*4+3];
    float bias = cb[ch];
    float r0 = bf2f(raw[0*RLD + t]);
    float r1 = bf2f(raw[1*RLD + t]);
    float r2 = bf2f(raw[2*RLD + t]);
    u16* dstT = isC ? Ct : Bt;
    #pragma unroll 4
    for (int j = 0; j < 128; j++) {
      float r3 = bf2f(raw[(j + 3)*RLD + t]);
      float o = bias + w0*r0 + w1*r1 + w2*r2 + w3*r3;
      dstT[j*LDF + n] = f2bf(siluf(o));
      r0 = r1; r1 = r2; r2 = r3;
    }
  }
  __syncthreads();
  #pragma unroll
  for (int rg = 0; rg < 16; rg++) {
    int idx = rg*256 + t;
    int r = idx >> 5, seg = idx & 31;
    int g = base + r;
    if (g < LTOT) {
      size_t orow = (size_t)(b*LTOT + g)*128;
      if (seg < 16) *(short8*)(Bcv + orow + seg*8)        = *(const short8*)&Bt[r*LDF + seg*8];
      else          *(short8*)(Ccv + orow + (seg - 16)*8) = *(const short8*)&Ct[r*LDF + (seg - 16)*8];
    }
  }
  u16* bT = BcvT + (size_t)bc*16384;
  #pragma unroll
  for (int rg = 0; rg < 8; rg++) {
    int idx = rg*256 + t;
    int n = idx >> 4, js = (idx & 15)*8;
    short8 v;
    #pragma unroll
    for (int k = 0; k < 8; k++) v[k] = (short)Bt[(js + k)*LDF + n];
    *(short8*)(bT + n*128 + js) = v;
  }
}

// ---- K1: per-chunk state ----
__global__ __launch_bounds__(256)
void chunk_state_kernel(const u16* __restrict__ zx, const float* __restrict__ dtb,
                        const float* __restrict__ alog, const float* __restrict__ cw,
                        const float* __restrict__ cb, const u16* __restrict__ BcvT,
                        u16* __restrict__ cstat, float* __restrict__ dtot)
{
  const int id = xcd_swz(blockIdx.x, BATCH*NCH*NH);
  const int h = id % NH; const int c = (id / NH) % NCH; const int b = id / (NH*NCH);
  const int t = threadIdx.x;
  const int base = c*CHK;
  int rows = LTOT - base; if (rows > CHK) rows = CHK;

  __shared__ __align__(16) u16 Bbuf[128*LDF];
  __shared__ __align__(16) u16 xbuf[131*XLD + 8];
  __shared__ float dtv[128];
  __shared__ float cs[128];
  __shared__ float wjs[128];

  const u16* zb = zx + (size_t)(b*LTOT)*ZLD;
  const float aexp = __expf(alog[h]);
  if (t < 128) {
    float dv = 0.f;
    if (t < rows) dv = dtb[(size_t)(b*LTOT + base + t)*NH + h];
    dtv[t] = dv; cs[t] = -dv * aexp;
  }
  {
    const u16* bT = BcvT + (size_t)(b*NCH + c)*16384;
    #pragma unroll
    for (int rg = 0; rg < 8; rg++) {
      int idx = rg*256 + t;
      int n = idx >> 4, js = (idx & 15)*8;
      *(short8*)&Bbuf[n*LDF + js] = *(const short8*)(bT + n*128 + js);
    }
  }
  #pragma unroll
  for (int rg = 0; rg < 5; rg++) {
    int r = rg*32 + (t >> 3);
    int seg = t & 7;
    if (r < 131) {
      int g = base - 3 + r;
      short8 v = {};
      if (g >= 0 && g < LTOT) v = *(const short8*)(zb + (size_t)g*ZLD + 1536 + h*HD + seg*8);
      *(short8*)&xbuf[r*XLD + seg*8] = v;
    }
  }
  __syncthreads();
  for (int off = 1; off < 128; off <<= 1) {
    float add = 0.f;
    if (t < 128 && t >= off) add = cs[t - off];
    __syncthreads();
    if (t < 128) cs[t] += add;
    __syncthreads();
  }
  if (t < 128) wjs[t] = __expf(cs[127] - cs[t]) * dtv[t];
  __syncthreads();

  const int p_ = t & 63, jq = t >> 6;
  u32 pkx[16];
  {
    const int ch = h*HD + p_;
    float w0 = cw[ch*4+0], w1 = cw[ch*4+1], w2 = cw[ch*4+2], w3 = cw[ch*4+3];
    float bias = cb[ch];
    const int rb = jq*32;
    float r0 = bf2f(xbuf[(rb+0)*XLD + p_]);
    float r1 = bf2f(xbuf[(rb+1)*XLD + p_]);
    float r2 = bf2f(xbuf[(rb+2)*XLD + p_]);
    #pragma unroll
    for (int k2 = 0; k2 < 16; k2++) {
      float r3 = bf2f(xbuf[(rb + 2*k2 + 3)*XLD + p_]);
      float o0 = bias + w0*r0 + w1*r1 + w2*r2 + w3*r3;
      float r4 = bf2f(xbuf[(rb + 2*k2 + 4)*XLD + p_]);
      float o1 = bias + w0*r1 + w1*r2 + w2*r3 + w3*r4;
      float s0 = siluf(o0) * wjs[rb + 2*k2];
      float s1 = siluf(o1) * wjs[rb + 2*k2 + 1];
      pkx[k2] = (u32)f2bf(s0) | ((u32)f2bf(s1) << 16);
      r0 = r2; r1 = r3; r2 = r4;
    }
  }
  __syncthreads();
  #pragma unroll
  for (int q = 0; q < 4; q++) {
    u32x4 v; v[0] = pkx[q*4]; v[1] = pkx[q*4+1]; v[2] = pkx[q*4+2]; v[3] = pkx[q*4+3];
    *(u32x4*)&xbuf[p_*LDF + jq*32 + q*8] = v;
  }
  __syncthreads();

  const int lane = t & 63, wave = t >> 6;
  const int r16 = lane & 15, kb = lane >> 4;
  const int n0 = wave*32;
  f32x4 acc[4][2] = {};
  #pragma unroll
  for (int kt = 0; kt < 4; kt++) {
    bf16x8 af[4], bfr[2];
    #pragma unroll
    for (int m = 0; m < 4; m++) af[m] = *(const bf16x8*)&xbuf[(m*16 + r16)*LDF + kt*32 + kb*8];
    #pragma unroll
    for (int nn = 0; nn < 2; nn++) bfr[nn] = *(const bf16x8*)&Bbuf[(n0 + nn*16 + r16)*LDF + kt*32 + kb*8];
    #pragma unroll
    for (int m = 0; m < 4; m++)
      #pragma unroll
      for (int nn = 0; nn < 2; nn++)
        acc[m][nn] = __builtin_amdgcn_mfma_f32_16x16x32_bf16(af[m], bfr[nn], acc[m][nn], 0, 0, 0);
  }
  u16* dst = cstat + (size_t)id*64*128;
  #pragma unroll
  for (int m = 0; m < 4; m++)
    #pragma unroll
    for (int nn = 0; nn < 2; nn++)
      #pragma unroll
      for (int e = 0; e < 4; e++) {
        int p = m*16 + kb*4 + e;
        int n = n0 + nn*16 + r16;
        dst[p*128 + n] = f2bf(acc[m][nn][e]);
      }
  if (t == 0) dtot[id] = __expf(cs[127]);
}

// ---- K2: inter-chunk scan ----
__global__ __launch_bounds__(256)
void state_scan_kernel(u16* __restrict__ cstat, const float* __restrict__ dtot)
{
  const int b = blockIdx.x / NH, h = blockIdx.x % NH;
  const int t = threadIdx.x;
  float run[32];
  #pragma unroll
  for (int k = 0; k < 32; k++) run[k] = 0.f;
  size_t id0 = (size_t)(b*NCH)*NH + h;
  short8 cur[4];
  {
    const u16* s0 = cstat + id0*8192 + t*32;
    #pragma unroll
    for (int q = 0; q < 4; q++) cur[q] = *(const short8*)(s0 + q*8);
  }
  float d = dtot[id0];
  for (int c = 0; c < NCH; ++c) {
    size_t id = (size_t)(b*NCH + c)*NH + h;
    u16* slab = cstat + id*8192 + t*32;
    short8 nxt[4] = {}; float nd = 0.f;
    if (c + 1 < NCH) {
      const u16* sn = slab + (size_t)NH*8192;
      #pragma unroll
      for (int q = 0; q < 4; q++) nxt[q] = *(const short8*)(sn + q*8);
      nd = dtot[id + NH];
    }
    short8 out[4];
    #pragma unroll
    for (int q = 0; q < 4; q++)
      #pragma unroll
      for (int k = 0; k < 8; k++) {
        int idx = q*8 + k;
        float csv = bf2f((u16)cur[q][k]);
        out[q][k] = (short)f2bf(run[idx]);
        run[idx] = run[idx]*d + csv;
      }
    #pragma unroll
    for (int q = 0; q < 4; q++) *(short8*)(slab + q*8) = out[q];
    #pragma unroll
    for (int q = 0; q < 4; q++) cur[q] = nxt[q];
    d = nd;
  }
}

// ---- K3: per-chunk output (512 threads / 8 waves); writes y*silu(z) over z-cols of zx ----
__global__ __launch_bounds__(512, 2)
void chunk_output_kernel(u16* __restrict__ zx, const float* __restrict__ dtb,
                         const float* __restrict__ alog, const float* __restrict__ cw,
                         const float* __restrict__ cb, const float* __restrict__ Dvec,
                         const u16* __restrict__ Bcv, const u16* __restrict__ Ccv,
                         const u16* __restrict__ cstat)
{
  const int id = xcd_swz(blockIdx.x, BATCH*NCH*NH);
  const int h = id % NH; const int c = (id / NH) % NCH; const int b = id / (NH*NCH);
  const int t = threadIdx.x;
  const int base = c*CHK;
  int rows = LTOT - base; if (rows > CHK) rows = CHK;

  __shared__ __align__(16) u16 Bc[128*LDF];
  __shared__ __align__(16) u16 Cc[128*LDF];
  __shared__ __align__(16) u16 stT[64*LDF];
  __shared__ __align__(16) u16 xbuf[131*XLD + 8];
  __shared__ float dtv[128];
  __shared__ float cs[128];

  const u16* zb = zx + (size_t)(b*LTOT)*ZLD;
  const float aexp = __expf(alog[h]);
  if (t < 128) {
    float dv = 0.f;
    if (t < rows) dv = dtb[(size_t)(b*LTOT + base + t)*NH + h];
    dtv[t] = dv; cs[t] = -dv * aexp;
  }
  {
    const u16* slab = cstat + (size_t)id*8192;
    int p = t >> 3, nb = (t & 7)*16;
    *(short8*)&stT[p*LDF + nb]     = *(const short8*)(slab + p*128 + nb);
    *(short8*)&stT[p*LDF + nb + 8] = *(const short8*)(slab + p*128 + nb + 8);
  }
  #pragma unroll
  for (int rg = 0; rg < 8; rg++) {
    int r = rg*16 + (t >> 5);
    int seg = t & 31;
    int g = base + r;
    short8 v = {};
    if (g < LTOT) {
      size_t srow = (size_t)(b*LTOT + g)*128;
      v = (seg < 16) ? *(const short8*)(Bcv + srow + seg*8)
                     : *(const short8*)(Ccv + srow + (seg - 16)*8);
    }
    if (seg < 16) *(short8*)&Bc[r*LDF + seg*8] = v;
    else          *(short8*)&Cc[r*LDF + (seg - 16)*8] = v;
  }
  #pragma unroll
  for (int rg = 0; rg < 3; rg++) {
    int r = rg*64 + (t >> 3);
    int seg = t & 7;
    if (r < 131) {
      int g = base - 3 + r;
      short8 v = {};
      if (g >= 0 && g < LTOT) v = *(const short8*)(zb + (size_t)g*ZLD + 1536 + h*HD + seg*8);
      *(short8*)&xbuf[r*XLD + seg*8] = v;
    }
  }
  __syncthreads();
  for (int off = 1; off < 128; off <<= 1) {
    float add = 0.f;
    if (t < 128 && t >= off) add = cs[t - off];
    __syncthreads();
    if (t < 128) cs[t] += add;
    __syncthreads();
  }

  const int p_ = t & 63, jq = t >> 6;
  u32 pkx[8];
  {
    const int ch = h*HD + p_;
    float w0 = cw[ch*4+0], w1 = cw[ch*4+1], w2 = cw[ch*4+2], w3 = cw[ch*4+3];
    float bias = cb[ch];
    const int rb = jq*16;
    float r0 = bf2f(xbuf[(rb+0)*XLD + p_]);
    float r1 = bf2f(xbuf[(rb+1)*XLD + p_]);
    float r2 = bf2f(xbuf[(rb+2)*XLD + p_]);
    #pragma unroll
    for (int k2 = 0; k2 < 8; k2++) {
      float r3 = bf2f(xbuf[(rb + 2*k2 + 3)*XLD + p_]);
      float o0 = bias + w0*r0 + w1*r1 + w2*r2 + w3*r3;
      float r4 = bf2f(xbuf[(rb + 2*k2 + 4)*XLD + p_]);
      float o1 = bias + w0*r1 + w1*r2 + w2*r3 + w3*r4;
      int j0 = rb + 2*k2;
      u32 lo = (j0     < rows) ? (u32)f2bf(siluf(o0)) : 0u;
      u32 hi = (j0 + 1 < rows) ? (u32)f2bf(siluf(o1)) : 0u;
      pkx[k2] = lo | (hi << 16);
      r0 = r2; r1 = r3; r2 = r4;
    }
  }
  __syncthreads();
  {
    u32x4 v0; v0[0] = pkx[0]; v0[1] = pkx[1]; v0[2] = pkx[2]; v0[3] = pkx[3];
    u32x4 v1; v1[0] = pkx[4]; v1[1] = pkx[5]; v1[2] = pkx[6]; v1[3] = pkx[7];
    *(u32x4*)&xbuf[p_*LDF + jq*16]     = v0;
    *(u32x4*)&xbuf[p_*LDF + jq*16 + 8] = v1;
  }
  __syncthreads();

  const int lane = t & 63, wave = t >> 6;
  const int r16 = lane & 15, kb = lane >> 4;

  {
    const int wi = wave >> 2, wjn = wave & 3;
    f32x4 acc[4][2] = {};
    #pragma unroll
    for (int kt = 0; kt < 4; kt++) {
      bf16x8 af[4], bfr[2];
      #pragma unroll
      for (int m = 0; m < 4; m++) af[m] = *(const bf16x8*)&Cc[(wi*64 + m*16 + r16)*LDF + kt*32 + kb*8];
      #pragma unroll
      for (int nj = 0; nj < 2; nj++) bfr[nj] = *(const bf16x8*)&Bc[(wjn*32 + nj*16 + r16)*LDF + kt*32 + kb*8];
      #pragma unroll
      for (int m = 0; m < 4; m++)
        #pragma unroll
        for (int nj = 0; nj < 2; nj++)
          acc[m][nj] = __builtin_amdgcn_mfma_f32_16x16x32_bf16(af[m], bfr[nj], acc[m][nj], 0, 0, 0);
    }
    __syncthreads();
    #pragma unroll
    for (int m = 0; m < 4; m++)
      #pragma unroll
      for (int nj = 0; nj < 2; nj++)
        #pragma unroll
        for (int e = 0; e < 4; e++) {
          int i = wi*64 + m*16 + kb*4 + e;
          int j = wjn*32 + nj*16 + r16;
          float f = 0.f;
          if (j <= i && i < rows) f = __expf(cs[i] - cs[j]) * dtv[j];
          Bc[i*LDF + j] = f2bf(acc[m][nj][e] * f);
        }
  }
  __syncthreads();

  {
    const int iq = wave;
    f32x4 accY[4] = {};
    #pragma unroll
    for (int kt = 0; kt < 4; kt++) {
      bf16x8 af = *(const bf16x8*)&Bc[(iq*16 + r16)*LDF + kt*32 + kb*8];
      #pragma unroll
      for (int n = 0; n < 4; n++) {
        bf16x8 bfr = *(const bf16x8*)&xbuf[(n*16 + r16)*LDF + kt*32 + kb*8];
        accY[n] = __builtin_amdgcn_mfma_f32_16x16x32_bf16(af, bfr, accY[n], 0, 0, 0);
      }
    }
    f32x4 accS[4] = {};
    #pragma unroll
    for (int kt = 0; kt < 4; kt++) {
      bf16x8 af = *(const bf16x8*)&Cc[(iq*16 + r16)*LDF + kt*32 + kb*8];
      #pragma unroll
      for (int n = 0; n < 4; n++) {
        bf16x8 bfr = *(const bf16x8*)&stT[(n*16 + r16)*LDF + kt*32 + kb*8];
        accS[n] = __builtin_amdgcn_mfma_f32_16x16x32_bf16(af, bfr, accS[n], 0, 0, 0);
      }
    }
    const float dcoef = Dvec[h];
    #pragma unroll
    for (int e = 0; e < 4; e++) {
      int i = iq*16 + kb*4 + e;
      if (i < rows) {
        float sc = __expf(cs[i]);
        size_t orow = (size_t)(b*LTOT + base + i)*ZLD + h*HD;
        #pragma unroll
        for (int n = 0; n < 4; n++) {
          int p = n*16 + r16;
          float xv = bf2f(xbuf[p*LDF + i]);
          float yv = accY[n][e] + sc*accS[n][e] + dcoef*xv;
          float zval = bf2f(zx[orow + p]);
          zx[orow + p] = f2bf(yv * siluf(zval));
        }
      }
    }
  }
}

// ---- rms stats only: rs per row of gated zx cols [0,1536) ----
__global__ __launch_bounds__(256)
void rms_stats_kernel(const u16* __restrict__ zx, float* __restrict__ rsb)
{
  int row = blockIdx.x;
  int t = threadIdx.x;
  __shared__ float sh[4];
  float ss = 0.f;
  const u16* zr = zx + (size_t)row*ZLD;
  if (t < 192) {
    short8 v = *(const short8*)(zr + t*8);
    #pragma unroll
    for (int j = 0; j < 8; j++) { float f = bf2f((u16)v[j]); ss += f*f; }
  }
  ss = blockSum256(ss, sh);
  if (t == 0) rsb[row] = rsqrtf(ss * (1.f/1536.f) + EPSF);
}

// ---- head ----
__global__ __launch_bounds__(256)
void head_kernel(const float* __restrict__ x, const float* __restrict__ tw,
                 const float* __restrict__ tb, const float* __restrict__ im64,
                 float* __restrict__ out, float* __restrict__ partial)
{
  int bj = blockIdx.x;
  int b = bj >> 12, j = bj & 4095;
  int row = b*LTOT + 65 + j;
  const float* xr = x + (size_t)row*DM;
  int t = threadIdx.x;
  float p0 = 0, p1 = 0, p2 = 0;
  for (int k = t; k < 768; k += 256) {
    float xv = xr[k];
    p0 += xv*tw[k*3 + 0]; p1 += xv*tw[k*3 + 1]; p2 += xv*tw[k*3 + 2];
  }
  __shared__ float sh[4];
  p0 = blockSum256(p0, sh);
  p1 = blockSum256(p1, sh);
  p2 = blockSum256(p2, sh);
  if (t == 0) {
    float y0 = p0 + tb[0], y1 = p1 + tb[1], y2 = p2 + tb[2];
    size_t o = (size_t)bj*3;
    out[o] = y0; out[o + 1] = y1; out[o + 2] = y2;
    float d0 = y0 - im64[o], d1 = y1 - im64[o + 1], d2 = y2 - im64[o + 2];
    partial[bj] = d0*d0 + d1*d1 + d2*d2;
  }
}

__global__ __launch_bounds__(256)
void loss_reduce(const float* __restrict__ partial, float* __restrict__ out)
{
  int t = threadIdx.x;
  float s = 0.f;
  for (int i = t; i < BATCH*4096; i += 256) s += partial[i];
  __shared__ float sh[4];
  s = blockSum256(s, sh);
  if (t == 0) out[49152] = s * (1.f/49152.f);
}

// ---- launcher ----
static inline size_t alignup(size_t v){ return (v + 255) & ~(size_t)255; }

extern "C" void kernel_launch(void* const* d_in, const int* in_sizes, int n_in,
                              void* d_out, int out_size, void* d_ws, size_t ws_size,
                              hipStream_t stream)
{
  const float* im8        = (const float*)d_in[0];
  const float* im64       = (const float*)d_in[1];
  const float* from_rgb_w = (const float*)d_in[2];
  const float* from_rgb_b = (const float*)d_in[3];
  const float* to_rgb_w   = (const float*)d_in[4];
  const float* to_rgb_b   = (const float*)d_in[5];
  const float* s0         = (const float*)d_in[6];
  const float* suffix     = (const float*)d_in[7];
  const float* norm0_w    = (const float*)d_in[8];
  const float* norm0_b    = (const float*)d_in[9];
  const float* ln_w       = (const float*)d_in[10];
  const float* ln_b       = (const float*)d_in[11];
  const float* in_proj_w  = (const float*)d_in[12];
  const float* conv_w     = (const float*)d_in[13];
  const float* conv_b     = (const float*)d_in[14];
  const float* dt_bias    = (const float*)d_in[15];
  const float* A_log      = (const float*)d_in[16];
  const float* Dvec       = (const float*)d_in[17];
  const float* gn_w       = (const float*)d_in[18];
  const float* out_proj_w = (const float*)d_in[19];

  char* w = (char*)d_ws;
  size_t off = 0;
  float* x     = (float*)(w + off); off = alignup(off + (size_t)NROWS*DM*4);        // 51.1 MB
  u16*   zx    = (u16*)  (w + off); off = alignup(off + (size_t)NROWS*ZLD*2);       // 110.8 MB
  u16*   scr   = (u16*)  (w + off); off = alignup(off + (size_t)BATCH*NCH*NH*64*128*2); // 51.9 MB (wT+xn | cstat)
  u16*   Bcv   = (u16*)  (w + off); off = alignup(off + (size_t)NROWS*128*2);       // 4.26 MB
  u16*   Ccv   = (u16*)  (w + off); off = alignup(off + (size_t)NROWS*128*2);       // 4.26 MB
  u16*   BcvT  = (u16*)  (w + off); off = alignup(off + (size_t)BATCH*NCH*16384*2); // 4.33 MB
  float* dt    = (float*)(w + off); off = alignup(off + (size_t)NROWS*NH*4);        // 1.6 MB
  float* rsb   = (float*)(w + off); off = alignup(off + (size_t)NROWS*4);           // 67 KB
  float* dtot  = (float*)(w + off); off = alignup(off + (size_t)BATCH*NCH*NH*4);    // 12.7 KB
  float* lpart = (float*)(w + off); off = alignup(off + (size_t)BATCH*4096*4);      // 64 KB
  // total ~228.6 MB
  u16* wT    = scr;                                                     // 5.31 MB
  u16* xn    = (u16*)((char*)scr + alignup((size_t)NPAD1*DM*2));        // 25.6 MB
  u16* cstat = scr;                                                     // 51.9 MB (after gemm0)

  build_x_kernel<<<NROWS, 256, 0, stream>>>(im8, from_rgb_w, from_rgb_b, s0, suffix,
                                            norm0_w, norm0_b, x);

  const int NBLK = BATCH*NCH*NH;   // 3168
  for (int i = 0; i < 4; i++) {
    ln_bf16_kernel<<<NROWS, 256, 0, stream>>>(x, ln_w + i*DM, ln_b + i*DM, xn);
    transp_bf16<<<dim3(NPAD1/32, DM/32), 256, 0, stream>>>(in_proj_w + (size_t)i*DM*DIP, wT, DM, DIP);
    gemm0<<<dim3(NPAD1/128, MPAD/128), 256, 0, stream>>>(xn, wT, zx, dt_bias + i*NH, dt);
    convBC_kernel<<<BATCH*NCH, 256, 0, stream>>>(zx, conv_w + (size_t)i*(DI+2*DS)*4,
        conv_b + i*(DI+2*DS), Bcv, Ccv, BcvT);
    chunk_state_kernel<<<NBLK, 256, 0, stream>>>(zx, dt, A_log + i*NH,
        conv_w + (size_t)i*(DI+2*DS)*4, conv_b + i*(DI+2*DS), BcvT, cstat, dtot);
    state_scan_kernel<<<BATCH*NH, 256, 0, stream>>>(cstat, dtot);
    chunk_output_kernel<<<NBLK, 512, 0, stream>>>(zx, dt, A_log + i*NH,
        conv_w + (size_t)i*(DI+2*DS)*4, conv_b + i*(DI+2*DS), Dvec + i*NH, Bcv, Ccv, cstat);
    rms_stats_kernel<<<NROWS, 256, 0, stream>>>(zx, rsb);
    transp_bf16<<<dim3(DM/32, DI/32), 256, 0, stream>>>(out_proj_w + (size_t)i*DI*DM, wT, DI, DM);
    gemm_out<<<dim3(DM/128, MPAD/128), 256, 0, stream>>>(zx, rsb, gn_w + i*DI, wT, x);
  }

  head_kernel<<<BATCH*4096, 256, 0, stream>>>(x, to_rgb_w, to_rgb_b, im64, (float*)d_out, lpart);
  loss_reduce<<<1, 256, 0, stream>>>(lpart, (float*)d_out);
}